// Round 21
// baseline (416.765 us; speedup 1.0000x reference)
//
#include <hip/hip_runtime.h>

typedef unsigned short u16;
typedef unsigned int u32;

using f32x4 = __attribute__((ext_vector_type(4))) float;
using bf16x8 = __attribute__((ext_vector_type(8))) __bf16;

// ---------- constants ----------
#define HN 2048
#define KVD 512
#define TOKENS 2048          // B*T
#define N1 3712              // GEMM1 N (3648 padded to 29*128)
#define K2W 576              // GEMM2 K
#define N2 7168              // GEMM2 N: w(2048) a(2048) g(2048) v(512) k(512)

// ---------- workspace layout (bytes) — lifetime-aliased, peak 213.4 MB ----------
#define OFF_Y1   0ull
#define OFF_OO   0ull
#define OFF_XG   16777216ull
#define OFF_Y2   30408704ull
#define OFF_OUTR 30408704ull
#define OFF_BT1  89128960ull
#define OFF_XB   104333312ull
#define OFF_W2T  89128960ull
#define OFF_X2   97386496ull
#define OFF_OT   89128960ull
#define OFF_RR   112721920ull
#define OFF_DEC  129499136ull
#define OFF_KR   146276352ull
#define OFF_VV   163053568ull
#define OFF_AA   179830784ull
#define OFF_BB   196608000ull
#define WS_NEED  213385216ull

// ---------- helpers ----------
__device__ __forceinline__ u16 f2bf(float f) {
    u32 u = __float_as_uint(f);
    u32 r = u + 0x7fffu + ((u >> 16) & 1u);
    return (u16)(r >> 16);
}
__device__ __forceinline__ float sigm(float x) { return 1.f / (1.f + expf(-x)); }
__device__ __forceinline__ float wsum(float v) {
#pragma unroll
    for (int m = 32; m > 0; m >>= 1) v += __shfl_xor(v, m, 64);
    return v;
}
// sum across each 16-lane DPP row via row_ror 1,2,4,8; result in all lanes of the row
__device__ __forceinline__ float rowsum16(float v) {
    float t;
    t = __uint_as_float(__builtin_amdgcn_update_dpp(0, __float_as_uint(v), 0x121, 0xf, 0xf, true));
    v += t;
    t = __uint_as_float(__builtin_amdgcn_update_dpp(0, __float_as_uint(v), 0x122, 0xf, 0xf, true));
    v += t;
    t = __uint_as_float(__builtin_amdgcn_update_dpp(0, __float_as_uint(v), 0x124, 0xf, 0xf, true));
    v += t;
    t = __uint_as_float(__builtin_amdgcn_update_dpp(0, __float_as_uint(v), 0x128, 0xf, 0xf, true));
    v += t;
    return v;
}

typedef __attribute__((address_space(1))) const void glob_t;
typedef __attribute__((address_space(3))) void lds_t;
__device__ __forceinline__ void gload_lds16(const void* g, void* l) {
    __builtin_amdgcn_global_load_lds((glob_t*)g, (lds_t*)l, 16, 0, 0);
}

// inline-asm LDS readers with literal offset (burst-issued, order preserved)
template<int OFF>
__device__ __forceinline__ float4 ds_read128(u32 a) {
    float4 r;
    asm volatile("ds_read_b128 %0, %1 offset:%2" : "=v"(r) : "v"(a), "i"(OFF));
    return r;
}
template<int OFF>
__device__ __forceinline__ float2 ds_read64(u32 a) {
    float2 r;
    asm volatile("ds_read_b64 %0, %1 offset:%2" : "=v"(r) : "v"(a), "i"(OFF));
    return r;
}

// ---------- weight prep: tiled transposes (coalesced read AND write) ----------
__global__ __launch_bounds__(256) void k_prep_bt1(const float* __restrict__ wavgk1,
                                                  const float* __restrict__ RKV,
                                                  u16* __restrict__ BT1) {
    __shared__ float tile[64][65];
    const int bn = blockIdx.x >> 5;        // 0..57
    const int bk = blockIdx.x & 31;        // 0..31
    const int n0 = bn << 6, k0 = bk << 6;
    const int c = threadIdx.x & 63, q = threadIdx.x >> 6;
#pragma unroll
    for (int i = 0; i < 16; ++i) {
        const int r = (q << 4) + i;
        float v = 0.f;
        if (bn < 9)       v = wavgk1[(size_t)(k0 + r) * 576 + n0 + c];
        else if (bn < 57) v = RKV[(size_t)(k0 + r) * 3072 + (n0 + c - 576)];
        tile[r][c] = v;
    }
    __syncthreads();
#pragma unroll
    for (int i = 0; i < 16; ++i) {
        const int rw = (q << 4) + i;
        BT1[(size_t)(n0 + rw) * 2048 + k0 + c] = f2bf(tile[c][rw]);
    }
}

__global__ __launch_bounds__(256) void k_prep_w2t(const float* __restrict__ w2, const float* __restrict__ a2,
                                                  const float* __restrict__ g2, const float* __restrict__ v2,
                                                  const float* __restrict__ k2, u16* __restrict__ W2T) {
    int idx = blockIdx.x * 256 + threadIdx.x;   // n*576 + c, n<7168
    int n = idx / 576, c = idx - n * 576;
    float v = 0.f;
    if (n < 2048)      { if (c < 96)              v = w2[(size_t)c * 2048 + n]; }
    else if (n < 4096) { if (c >= 96 && c < 192)  v = a2[(size_t)(c - 96) * 2048 + (n - 2048)]; }
    else if (n < 6144) { if (c >= 192 && c < 448) v = g2[(size_t)(c - 192) * 2048 + (n - 4096)]; }
    else if (n < 6656) { if (c >= 448 && c < 512) v = v2[(size_t)(c - 448) * 512 + (n - 6144)]; }
    else               { if (c >= 512)            v = k2[(size_t)(c - 512) * 512 + (n - 6656)]; }
    W2T[idx] = f2bf(v);
}

// OT[n][k] = O[k][n], 2048x2048, 64x64 tiles
__global__ __launch_bounds__(256) void k_prep_ot(const float* __restrict__ O, u16* __restrict__ OT) {
    __shared__ float tile[64][65];
    const int bn = blockIdx.x >> 5, bk = blockIdx.x & 31;
    const int n0 = bn << 6, k0 = bk << 6;
    const int c = threadIdx.x & 63, q = threadIdx.x >> 6;
#pragma unroll
    for (int i = 0; i < 16; ++i) {
        const int r = (q << 4) + i;
        tile[r][c] = O[(size_t)(k0 + r) * 2048 + n0 + c];
    }
    __syncthreads();
#pragma unroll
    for (int i = 0; i < 16; ++i) {
        const int rw = (q << 4) + i;
        OT[(size_t)(n0 + rw) * 2048 + k0 + c] = f2bf(tile[c][rw]);
    }
}

// ---------- rmsnorm(x_in, ln1) -> bf16 ----------
__global__ __launch_bounds__(256) void k_rms1(const float* __restrict__ X,
                                              const float* __restrict__ ln1,
                                              u16* __restrict__ XB) {
    const int t = blockIdx.x, tid = threadIdx.x;
    const float* row = X + ((size_t)t << 11);
    float4 v0 = *(const float4*)(row + tid * 8);
    float4 v1 = *(const float4*)(row + tid * 8 + 4);
    float ss = v0.x*v0.x + v0.y*v0.y + v0.z*v0.z + v0.w*v0.w
             + v1.x*v1.x + v1.y*v1.y + v1.z*v1.z + v1.w*v1.w;
    ss = wsum(ss);
    __shared__ float red[4];
    if ((tid & 63) == 0) red[tid >> 6] = ss;
    __syncthreads();
    float scale = rsqrtf((red[0] + red[1] + red[2] + red[3]) * (1.f / 2048.f) + 1e-6f);
    float4 w0_ = *(const float4*)(ln1 + tid * 8);
    float4 w1_ = *(const float4*)(ln1 + tid * 8 + 4);
    u16* o = XB + ((size_t)t << 11) + tid * 8;
    o[0] = f2bf(v0.x * scale * w0_.x); o[1] = f2bf(v0.y * scale * w0_.y);
    o[2] = f2bf(v0.z * scale * w0_.z); o[3] = f2bf(v0.w * scale * w0_.w);
    o[4] = f2bf(v1.x * scale * w1_.x); o[5] = f2bf(v1.y * scale * w1_.y);
    o[6] = f2bf(v1.z * scale * w1_.z); o[7] = f2bf(v1.w * scale * w1_.w);
}

// ---------- generic bf16 MFMA GEMM with LDS chunk swizzle ----------
__global__ __launch_bounds__(256) void k_gemm(const u16* __restrict__ A,
                                              const u16* __restrict__ Bt,
                                              float* __restrict__ C,
                                              int M, int N, int K) {
    __shared__ __align__(16) u16 tA[4096];  // [128 rows][32 k]
    __shared__ __align__(16) u16 tB[4096];
    const int tid = threadIdx.x;
    const int w = tid >> 6, l = tid & 63;
    const int bm = blockIdx.x << 7, bn = blockIdx.y << 7;
    const int wm = (w >> 1) << 6, wn = (w & 1) << 6;
    const int lrow = l >> 2;        // 0..15 (staged row within 16-row group)
    const int lk = (((l & 3) ^ ((l >> 3) & 3)) << 3);   // pre-swizzled global chunk
    f32x4 acc[4][4] = {};
    const size_t rA0 = (size_t)(bm + (w << 4) + lrow) * K;
    const size_t rA1 = (size_t)(bm + ((w + 4) << 4) + lrow) * K;
    const size_t rB0 = (size_t)(bn + (w << 4) + lrow) * K;
    const size_t rB1 = (size_t)(bn + ((w + 4) << 4) + lrow) * K;
    const int frow = l & 15;
    const int koff = (((l >> 4) ^ ((l >> 1) & 3)) << 3);  // swizzled read chunk
    for (int kt = 0; kt < K; kt += 32) {
        gload_lds16(A + rA0 + kt + lk, &tA[w << 9]);
        gload_lds16(A + rA1 + kt + lk, &tA[2048 + (w << 9)]);
        gload_lds16(Bt + rB0 + kt + lk, &tB[w << 9]);
        gload_lds16(Bt + rB1 + kt + lk, &tB[2048 + (w << 9)]);
        __syncthreads();
        bf16x8 av[4], bv[4];
#pragma unroll
        for (int i = 0; i < 4; ++i) {
            av[i] = *(const bf16x8*)&tA[((wm + (i << 4) + frow) << 5) + koff];
            bv[i] = *(const bf16x8*)&tB[((wn + (i << 4) + frow) << 5) + koff];
        }
#pragma unroll
        for (int i = 0; i < 4; ++i)
#pragma unroll
            for (int j = 0; j < 4; ++j)
                acc[i][j] = __builtin_amdgcn_mfma_f32_16x16x32_bf16(av[i], bv[j], acc[i][j], 0, 0, 0);
        __syncthreads();
    }
    const int crow = bm + wm + ((l >> 4) << 2);
    const int ccol = bn + wn + (l & 15);
#pragma unroll
    for (int i = 0; i < 4; ++i)
#pragma unroll
        for (int j = 0; j < 4; ++j)
#pragma unroll
            for (int jj = 0; jj < 4; ++jj)
                C[(size_t)(crow + (i << 4) + jj) * N + ccol + (j << 4)] = acc[i][j][jj];
}

// ---------- GEMM2 specialization: block-diagonal W2T, per-segment true K ----------
__global__ __launch_bounds__(256) void k_gemm2(const u16* __restrict__ A,
                                               const u16* __restrict__ Bt,
                                               float* __restrict__ C) {
    __shared__ __align__(16) u16 tA[4096];
    __shared__ __align__(16) u16 tB[4096];
    const int tid = threadIdx.x;
    const int w = tid >> 6, l = tid & 63;
    const int by = blockIdx.y;
    int c0, K;
    if (by < 16)      { c0 = 0;   K = 96; }
    else if (by < 32) { c0 = 96;  K = 96; }
    else if (by < 48) { c0 = 192; K = 256; }
    else if (by < 52) { c0 = 448; K = 64; }
    else              { c0 = 512; K = 64; }
    const int n0 = by << 7;
    const int bm = blockIdx.x << 7;
    const int wm = (w >> 1) << 6, wn = (w & 1) << 6;
    const int lrow = l >> 2;
    const int lk = (((l & 3) ^ ((l >> 3) & 3)) << 3);
    f32x4 acc[4][4] = {};
    const size_t rA0 = (size_t)(bm + (w << 4) + lrow) * 576 + c0;
    const size_t rA1 = (size_t)(bm + ((w + 4) << 4) + lrow) * 576 + c0;
    const size_t rB0 = (size_t)(n0 + (w << 4) + lrow) * 576 + c0;
    const size_t rB1 = (size_t)(n0 + ((w + 4) << 4) + lrow) * 576 + c0;
    const int frow = l & 15;
    const int koff = (((l >> 4) ^ ((l >> 1) & 3)) << 3);
    for (int kt = 0; kt < K; kt += 32) {
        gload_lds16(A + rA0 + kt + lk, &tA[w << 9]);
        gload_lds16(A + rA1 + kt + lk, &tA[2048 + (w << 9)]);
        gload_lds16(Bt + rB0 + kt + lk, &tB[w << 9]);
        gload_lds16(Bt + rB1 + kt + lk, &tB[2048 + (w << 9)]);
        __syncthreads();
        bf16x8 av[4], bv[4];
#pragma unroll
        for (int i = 0; i < 4; ++i) {
            av[i] = *(const bf16x8*)&tA[((wm + (i << 4) + frow) << 5) + koff];
            bv[i] = *(const bf16x8*)&tB[((wn + (i << 4) + frow) << 5) + koff];
        }
#pragma unroll
        for (int i = 0; i < 4; ++i)
#pragma unroll
            for (int j = 0; j < 4; ++j)
                acc[i][j] = __builtin_amdgcn_mfma_f32_16x16x32_bf16(av[i], bv[j], acc[i][j], 0, 0, 0);
        __syncthreads();
    }
    const int crow = bm + wm + ((l >> 4) << 2);
    const int ccol = n0 + wn + (l & 15);
#pragma unroll
    for (int i = 0; i < 4; ++i)
#pragma unroll
        for (int j = 0; j < 4; ++j)
#pragma unroll
            for (int jj = 0; jj < 4; ++jj)
                C[(size_t)(crow + (i << 4) + jj) * N2 + ccol + (j << 4)] = acc[i][j][jj];
}

// ---------- Y1 -> X2 (bf16): [tanh(xw) | xa | sigmoid(xg) | xv | xk] ----------
__global__ __launch_bounds__(256) void k_prep_x2(const float* __restrict__ Y1, u16* __restrict__ X2) {
    int idx = blockIdx.x * 256 + threadIdx.x;   // t*576 + c
    int t = idx / 576, c = idx - t * 576;
    const float* y1 = Y1 + (size_t)t * N1;
    float v;
    if (c < 96)       v = tanhf(y1[c]);
    else if (c < 192) v = y1[c];
    else if (c < 448) v = sigm(y1[c + 64]);
    else if (c < 512) v = y1[c - 256];
    else              v = y1[c];
    X2[idx] = f2bf(v);
}

// ---------- per-token recurrence prep ----------
__global__ __launch_bounds__(256) void k_prep_rec(
    const float* __restrict__ Y1, const float* __restrict__ Y2,
    const float* __restrict__ v_first, const float* __restrict__ k_first,
    const float* __restrict__ cosb, const float* __restrict__ sinb,
    const float* __restrict__ w0, const float* __restrict__ a0,
    const float* __restrict__ v0b, const float* __restrict__ k0b,
    const float* __restrict__ R_bias, const float* __restrict__ K_bias,
    const float* __restrict__ V_bias, const float* __restrict__ ln_r,
    const float* __restrict__ ln_k,
    float* __restrict__ RR, float* __restrict__ DEC, float* __restrict__ KR,
    float* __restrict__ VV, float* __restrict__ AA, float* __restrict__ BB) {
    const int t = blockIdx.x, tid = threadIdx.x;
    const int ww = tid >> 6, lane = tid & 63;
    const float* y1 = Y1 + (size_t)t * N1;
    const float* y2 = Y2 + (size_t)t * N2;
    const float cs = cosb[t * 64 + lane];
    const float sn = sinb[t * 64 + lane];
    const float sign = lane < 32 ? -1.f : 1.f;
    const size_t tb = (size_t)t << 11;
    __shared__ float kkv[512], vkv[512];
    // r: per-head rmsnorm + rope
#pragma unroll
    for (int i = 0; i < 8; ++i) {
        int h = ww * 8 + i, c = h * 64 + lane;
        float rr = y1[576 + c] + R_bias[c];
        float ssq = wsum(rr * rr);
        float rn = ln_r[lane] * rr * rsqrtf(ssq * (1.f / 64.f) + 1e-6f);
        float rot = sign * __shfl(rn, lane ^ 32, 64);
        RR[tb + c] = rn * cs + rot * sn;
    }
    // k,v kv-heads: rmsnorm+rope+mix
#pragma unroll
    for (int i = 0; i < 2; ++i) {
        int j = ww * 2 + i, c = j * 64 + lane;
        float kr = y1[2624 + c] + K_bias[c];
        float ssq = wsum(kr * kr);
        float kn = ln_k[lane] * kr * rsqrtf(ssq * (1.f / 64.f) + 1e-6f);
        float rot = sign * __shfl(kn, lane ^ 32, 64);
        float krope = kn * cs + rot * sn;
        float ksig = sigm(y2[6656 + c] + k0b[c]);
        kkv[c] = krope + (k_first[(size_t)t * 512 + c] - krope) * ksig;
        float vr = y1[3136 + c] + V_bias[c];
        float vsig = sigm(y2[6144 + c] + v0b[c]);
        vkv[c] = vr + (v_first[(size_t)t * 512 + c] - vr) * vsig;
    }
    __syncthreads();
    // per-head final recurrence operands
#pragma unroll
    for (int i = 0; i < 8; ++i) {
        int h = ww * 8 + i, c = h * 64 + lane;
        int ckv = (h >> 2) * 64 + lane;
        float kb = kkv[ckv], vb = vkv[ckv];
        float a_ = sigm(y2[2048 + c] + a0[c]);
        float wr = y2[c] + w0[c];
        float z = -wr;
        float sp = fmaxf(z, 0.f) + log1pf(expf(-fabsf(z)));
        float w_log = -sp - 0.5f;
        float ssq = wsum(kb * kb);
        float kk = kb / fmaxf(sqrtf(ssq), 1e-12f);
        DEC[tb + c] = expf(-expf(w_log));
        KR[tb + c] = kb * (1.f - w_log + a_);
        VV[tb + c] = vb;
        AA[tb + c] = -kk;
        BB[tb + c] = kk * a_;
    }
}

// ---------- sequential recurrence: 4 blocks/chain, 2 waves/block, asm bursts ----------
// r20 showed the wall is DS-pipe throughput per CU (4 waves x 66 cyc/step).
// This version: 128-thread blocks (2 waves), wave owns 8 v-cols (16-lane row =
// 2 cols, float2 state) -> per-CU DS halves to ~132 cyc/step while VALU issue
// rises to ~150/SIMD. Staging: wave wl stages 3 arrays (compile-time pointer
// select), 24 gload_lds16/chunk. Burst ds_read groups of 8 steps as in r20.
// cbuf[b][ar][s][x] byte offset = b*49152 + ar*8192 + s*256 + x*4.
__global__ __launch_bounds__(128, 1) void k_recv13(
    const float* __restrict__ RRp, const float* __restrict__ DECp,
    const float* __restrict__ KRp, const float* __restrict__ VVp,
    const float* __restrict__ AAp, const float* __restrict__ BBp,
    const float* __restrict__ S0, float* __restrict__ OO) {
    __shared__ __align__(16) float cbuf[2][6][32][64];   // [dbuf][arr][t][64] = 96 KB
    const int tid = threadIdx.x;
    const int wl = tid >> 6;           // wave 0..1
    const int lane = tid & 63;
    const int vl = lane >> 4;          // DPP row 0..3
    const int kq = lane & 15;          // k-quad 0..15
    const int quarter = blockIdx.x & 3;
    const int ch = blockIdx.x >> 2;          // chain 0..63 (b*32+h)
    const int vcol2 = (quarter << 4) + (wl << 3) + (vl << 1);  // this row's 2 cols
    const size_t cb = ((size_t)(ch >> 5) * 1024 * 2048) + ((size_t)(ch & 31) << 6);

    // state: Lj = {S[4kq+j][vcol2], S[4kq+j][vcol2+1]}
    const float* s0 = S0 + ((size_t)ch << 12);
    float2 L0 = *(const float2*)(s0 + ((kq << 2) + 0) * 64 + vcol2);
    float2 L1 = *(const float2*)(s0 + ((kq << 2) + 1) * 64 + vcol2);
    float2 L2 = *(const float2*)(s0 + ((kq << 2) + 2) * 64 + vcol2);
    float2 L3 = *(const float2*)(s0 + ((kq << 2) + 3) * 64 + vcol2);

    // staging: wave 0 -> {AA,DEC,KR} at arrays 0,1,2; wave 1 -> {BB,RR,VV} at 3,4,5
    const float* sA = wl ? BBp : AAp;
    const float* sB = wl ? RRp : DECp;
    const float* sC = wl ? VVp : KRp;

#define STG(B, T0)                                                             \
    {                                                                          \
        float* lb = &cbuf[B][0][0][0] + wl * 6144;                             \
        _Pragma("unroll") for (int r0 = 0; r0 < 32; r0 += 4) {                 \
            const size_t g = cb + (size_t)((T0) + r0 + (lane >> 4)) * 2048     \
                           + ((lane & 15) << 2);                               \
            gload_lds16(sA + g, lb + (r0 << 6));                               \
            gload_lds16(sB + g, lb + 2048 + (r0 << 6));                        \
            gload_lds16(sC + g, lb + 4096 + (r0 << 6));                        \
        }                                                                      \
    }

    // LDS byte address of cbuf base (generic->LDS offset: aperture 4GB-aligned)
    const u32 base0 = (u32)(size_t)(void*)&cbuf[0][0][0][0];
    const u32 aA0 = base0 + (kq << 4);             // coefficient chunk for lane
    const u32 aV0 = base0 + 40960 + (vcol2 << 2);  // V slot (float2)

#define LDSTEP(J)                                                              \
    cA[J] = ds_read128<(J) * 256>(aA);                                         \
    cD[J] = ds_read128<8192 + (J) * 256>(aA);                                  \
    cK[J] = ds_read128<16384 + (J) * 256>(aA);                                 \
    cB[J] = ds_read128<24576 + (J) * 256>(aA);                                 \
    cR[J] = ds_read128<32768 + (J) * 256>(aA);                                 \
    cV[J] = ds_read64<(J) * 256>(aV);

    STG(0, 0);
    __syncthreads();

    for (int c = 0; c < 32; ++c) {
        const int b = c & 1;
        if (c < 31) STG(b ^ 1, (c + 1) << 5);      // async prefetch next chunk
        u32 aA = aA0 + b * 49152;
        u32 aV = aV0 + b * 49152;
        int t = c << 5;
        for (int g = 0; g < 4; ++g) {              // 4 groups of 8 steps
            float4 cA[8], cD[8], cK[8], cB[8], cR[8];
            float2 cV[8];
            LDSTEP(0) LDSTEP(1) LDSTEP(2) LDSTEP(3)
            LDSTEP(4) LDSTEP(5) LDSTEP(6) LDSTEP(7)
            asm volatile("s_waitcnt lgkmcnt(0)" ::: "memory");
            __builtin_amdgcn_sched_barrier(0);
#pragma unroll
            for (int j = 0; j < 8; ++j) {
                const float4 A4 = cA[j], D4 = cD[j], K4 = cK[j], B4 = cB[j], R4 = cR[j];
                const float2 Vj = cV[j];
                float spx = fmaf(L1.x, A4.y, L0.x * A4.x) + fmaf(L3.x, A4.w, L2.x * A4.z);
                float spy = fmaf(L1.y, A4.y, L0.y * A4.x) + fmaf(L3.y, A4.w, L2.y * A4.z);
                const float sax = rowsum16(spx);
                const float say = rowsum16(spy);
                L0.x = fmaf(B4.x, sax, fmaf(K4.x, Vj.x, L0.x * D4.x));
                L0.y = fmaf(B4.x, say, fmaf(K4.x, Vj.y, L0.y * D4.x));
                L1.x = fmaf(B4.y, sax, fmaf(K4.y, Vj.x, L1.x * D4.y));
                L1.y = fmaf(B4.y, say, fmaf(K4.y, Vj.y, L1.y * D4.y));
                L2.x = fmaf(B4.z, sax, fmaf(K4.z, Vj.x, L2.x * D4.z));
                L2.y = fmaf(B4.z, say, fmaf(K4.z, Vj.y, L2.y * D4.z));
                L3.x = fmaf(B4.w, sax, fmaf(K4.w, Vj.x, L3.x * D4.w));
                L3.y = fmaf(B4.w, say, fmaf(K4.w, Vj.y, L3.y * D4.w));
                float opx = fmaf(L1.x, R4.y, L0.x * R4.x) + fmaf(L3.x, R4.w, L2.x * R4.z);
                float opy = fmaf(L1.y, R4.y, L0.y * R4.x) + fmaf(L3.y, R4.w, L2.y * R4.z);
                const float ox = rowsum16(opx);
                const float oy = rowsum16(opy);
                if (kq == 0)
                    *(float2*)&OO[cb + ((size_t)(t + j) << 11) + vcol2] = make_float2(ox, oy);
            }
            t += 8;
            aA += 2048;
            aV += 2048;
        }
        __syncthreads();   // drains staging vmcnt (1/32 steps); flips buffers
    }
#undef LDSTEP
#undef STG
}

// ---------- bonus + gate -> bf16 ----------
__global__ __launch_bounds__(256) void k_gate(
    const float* __restrict__ OOp, const float* __restrict__ RRp,
    const float* __restrict__ KRp, const float* __restrict__ VVp,
    const float* __restrict__ Y2, const float* __restrict__ r_k,
    u16* __restrict__ XG) {
    const int t = blockIdx.x, tid = threadIdx.x;
    const int ww = tid >> 6, lane = tid & 63;
    const size_t tb = (size_t)t << 11;
#pragma unroll
    for (int i = 0; i < 8; ++i) {
        int c = (ww * 8 + i) * 64 + lane;
        float pr = RRp[tb + c] * KRp[tb + c] * r_k[c];
        float dot = wsum(pr);
        float xx = OOp[tb + c] * 0.125f + dot * VVp[tb + c];
        float g = Y2[(size_t)t * N2 + 4096 + c];
        XG[tb + c] = f2bf(xx * g);
    }
}

// ---------- final residual + rmsnorm ----------
__global__ __launch_bounds__(256) void k_final(const float* __restrict__ x_in,
                                               const float* __restrict__ OUTR,
                                               const float* __restrict__ ln2,
                                               float* __restrict__ out) {
    const int t = blockIdx.x, tid = threadIdx.x;
    const float* xr = x_in + ((size_t)t << 11);
    const float* orow = OUTR + ((size_t)t << 11);
    float4 a0 = *(const float4*)(xr + tid * 8);
    float4 a1 = *(const float4*)(xr + tid * 8 + 4);
    float4 b0 = *(const float4*)(orow + tid * 8);
    float4 b1 = *(const float4*)(orow + tid * 8 + 4);
    float v[8] = {a0.x + b0.x, a0.y + b0.y, a0.z + b0.z, a0.w + b0.w,
                  a1.x + b1.x, a1.y + b1.y, a1.z + b1.z, a1.w + b1.w};
    float ss = 0.f;
#pragma unroll
    for (int i = 0; i < 8; ++i) ss = fmaf(v[i], v[i], ss);
    ss = wsum(ss);
    __shared__ float red[4];
    if ((tid & 63) == 0) red[tid >> 6] = ss;
    __syncthreads();
    float scale = rsqrtf((red[0] + red[1] + red[2] + red[3]) * (1.f / 2048.f) + 1e-6f);
    float* o = out + ((size_t)t << 11) + tid * 8;
#pragma unroll
    for (int i = 0; i < 8; ++i) o[i] = ln2[tid * 8 + i] * v[i] * scale;
}

extern "C" void kernel_launch(void* const* d_in, const int* in_sizes, int n_in,
                              void* d_out, int out_size, void* d_ws, size_t ws_size,
                              hipStream_t stream) {
    const float* x_in    = (const float*)d_in[0];
    const float* v_first = (const float*)d_in[1];
    const float* k_first = (const float*)d_in[2];
    const float* state   = (const float*)d_in[3];
    const float* cosb    = (const float*)d_in[4];
    const float* sinb    = (const float*)d_in[5];
    const float* wavgk1  = (const float*)d_in[6];
    const float* w0      = (const float*)d_in[7];
    const float* w2      = (const float*)d_in[8];
    const float* a0      = (const float*)d_in[9];
    const float* a2      = (const float*)d_in[10];
    const float* v0      = (const float*)d_in[11];
    const float* v2      = (const float*)d_in[12];
    const float* g2      = (const float*)d_in[13];
    const float* k0      = (const float*)d_in[14];
    const float* k2      = (const float*)d_in[15];
    const float* r_k     = (const float*)d_in[16];
    const float* RKV     = (const float*)d_in[17];
    const float* O       = (const float*)d_in[18];
    const float* R_bias  = (const float*)d_in[19];
    const float* K_bias  = (const float*)d_in[20];
    const float* V_bias  = (const float*)d_in[21];
    const float* ln_r    = (const float*)d_in[22];
    const float* ln_k    = (const float*)d_in[23];
    const float* ln1     = (const float*)d_in[24];
    const float* ln2     = (const float*)d_in[25];

    if (ws_size < WS_NEED) return;  // need 213.4 MB (fits 256 MiB)

    char* ws = (char*)d_ws;
    u16*   BT1  = (u16*)(ws + OFF_BT1);
    u16*   W2T  = (u16*)(ws + OFF_W2T);
    u16*   OT   = (u16*)(ws + OFF_OT);
    u16*   XB   = (u16*)(ws + OFF_XB);
    float* Y1   = (float*)(ws + OFF_Y1);
    u16*   X2   = (u16*)(ws + OFF_X2);
    float* Y2   = (float*)(ws + OFF_Y2);
    float* RR   = (float*)(ws + OFF_RR);
    float* DEC  = (float*)(ws + OFF_DEC);
    float* KR   = (float*)(ws + OFF_KR);
    float* VV   = (float*)(ws + OFF_VV);
    float* AA   = (float*)(ws + OFF_AA);
    float* BB   = (float*)(ws + OFF_BB);
    float* OO   = (float*)(ws + OFF_OO);
    u16*   XG   = (u16*)(ws + OFF_XG);
    float* OUTR = (float*)(ws + OFF_OUTR);

    // P0: BT1 + XB (region C)
    k_prep_bt1<<<1856, 256, 0, stream>>>(wavgk1, RKV, BT1);
    k_rms1<<<2048, 256, 0, stream>>>(x_in, ln1, XB);
    // P1: GEMM1 -> Y1  (region A)
    k_gemm<<<dim3(16, 29), 256, 0, stream>>>(XB, BT1, Y1, 2048, N1, 2048);
    // P2: W2T + X2 overwrite BT1/XB (dead); GEMM2 (block-diagonal) -> Y2 (region B)
    k_prep_w2t<<<16128, 256, 0, stream>>>(w2, a2, g2, v2, k2, W2T);
    k_prep_x2<<<4608, 256, 0, stream>>>(Y1, X2);
    k_gemm2<<<dim3(16, 56), 256, 0, stream>>>(X2, W2T, Y2);
    // P3: recurrence operands (region D); Y1 dead after this
    k_prep_rec<<<2048, 256, 0, stream>>>(Y1, Y2, v_first, k_first, cosb, sinb,
                                         w0, a0, v0, k0, R_bias, K_bias, V_bias,
                                         ln_r, ln_k, RR, DEC, KR, VV, AA, BB);
    // P4: OT overwrites W2T/X2 (dead); recurrence -> OO (in old Y1 space)
    k_prep_ot<<<1024, 256, 0, stream>>>(O, OT);
    k_recv13<<<256, 128, 0, stream>>>(RR, DEC, KR, VV, AA, BB, state, OO);
    // P5: gate -> XG (in old Y1 space); Y2 dead after this
    k_gate<<<2048, 256, 0, stream>>>(OO, RR, KR, VV, Y2, r_k, XG);
    // P6: GEMM3 -> OUTR (in old Y2 space); final norm
    k_gemm<<<dim3(16, 16), 256, 0, stream>>>(XG, OT, OUTR, 2048, 2048, 2048);
    k_final<<<2048, 256, 0, stream>>>(x_in, OUTR, ln2, (float*)d_out);
}

// Round 22
// 385.988 us; speedup vs baseline: 1.0797x; 1.0797x over previous
//
#include <hip/hip_runtime.h>

typedef unsigned short u16;
typedef unsigned int u32;

using f32x4 = __attribute__((ext_vector_type(4))) float;
using bf16x8 = __attribute__((ext_vector_type(8))) __bf16;

// ---------- constants ----------
#define HN 2048
#define KVD 512
#define TOKENS 2048          // B*T
#define N1 3712              // GEMM1 N (3648 padded to 29*128)
#define K2W 576              // GEMM2 K
#define N2 7168              // GEMM2 N: w(2048) a(2048) g(2048) v(512) k(512)

// ---------- workspace layout (bytes) — lifetime-aliased, peak 235.5 MB ----------
#define OFF_Y1   0ull
#define OFF_OO   0ull
#define OFF_XG   16777216ull
#define OFF_Y2   30408704ull
#define OFF_OUTR 30408704ull
#define OFF_BT1  89128960ull
#define OFF_XB   104333312ull
#define OFF_W2T  89128960ull
#define OFF_X2   97386496ull
#define OFF_OT   89128960ull
#define OFF_RR   112721920ull
#define OFF_DEC  129499136ull
#define OFF_KR   146276352ull
#define OFF_VV   163053568ull
#define OFF_AA   179830784ull
#define OFF_BB   196608000ull
#define OFF_PAB  213385216ull            // u32 [2048][2048]: bf16(A) | bf16(B)<<16
#define OFF_PKR  230162432ull            // u32 [2048][2048]: bf16(K) | bf16(R)<<16
#define WS_NEED  246939648ull

// ---------- helpers ----------
__device__ __forceinline__ u16 f2bf(float f) {
    u32 u = __float_as_uint(f);
    u32 r = u + 0x7fffu + ((u >> 16) & 1u);
    return (u16)(r >> 16);
}
__device__ __forceinline__ float sigm(float x) { return 1.f / (1.f + expf(-x)); }
__device__ __forceinline__ float wsum(float v) {
#pragma unroll
    for (int m = 32; m > 0; m >>= 1) v += __shfl_xor(v, m, 64);
    return v;
}
// sum across each 16-lane DPP row via row_ror 1,2,4,8; result in all lanes of the row
__device__ __forceinline__ float rowsum16(float v) {
    float t;
    t = __uint_as_float(__builtin_amdgcn_update_dpp(0, __float_as_uint(v), 0x121, 0xf, 0xf, true));
    v += t;
    t = __uint_as_float(__builtin_amdgcn_update_dpp(0, __float_as_uint(v), 0x122, 0xf, 0xf, true));
    v += t;
    t = __uint_as_float(__builtin_amdgcn_update_dpp(0, __float_as_uint(v), 0x124, 0xf, 0xf, true));
    v += t;
    t = __uint_as_float(__builtin_amdgcn_update_dpp(0, __float_as_uint(v), 0x128, 0xf, 0xf, true));
    v += t;
    return v;
}

typedef __attribute__((address_space(1))) const void glob_t;
typedef __attribute__((address_space(3))) void lds_t;
__device__ __forceinline__ void gload_lds16(const void* g, void* l) {
    __builtin_amdgcn_global_load_lds((glob_t*)g, (lds_t*)l, 16, 0, 0);
}

// inline-asm LDS readers with literal offset (burst-issued, order preserved)
template<int OFF>
__device__ __forceinline__ float4 ds_read128(u32 a) {
    float4 r;
    asm volatile("ds_read_b128 %0, %1 offset:%2" : "=v"(r) : "v"(a), "i"(OFF));
    return r;
}
template<int OFF>
__device__ __forceinline__ uint4 ds_read128u(u32 a) {
    uint4 r;
    asm volatile("ds_read_b128 %0, %1 offset:%2" : "=v"(r) : "v"(a), "i"(OFF));
    return r;
}
template<int OFF>
__device__ __forceinline__ float ds_read32(u32 a) {
    float r;
    asm volatile("ds_read_b32 %0, %1 offset:%2" : "=v"(r) : "v"(a), "i"(OFF));
    return r;
}

// ---------- weight prep: tiled transposes (coalesced read AND write) ----------
__global__ __launch_bounds__(256) void k_prep_bt1(const float* __restrict__ wavgk1,
                                                  const float* __restrict__ RKV,
                                                  u16* __restrict__ BT1) {
    __shared__ float tile[64][65];
    const int bn = blockIdx.x >> 5;        // 0..57
    const int bk = blockIdx.x & 31;        // 0..31
    const int n0 = bn << 6, k0 = bk << 6;
    const int c = threadIdx.x & 63, q = threadIdx.x >> 6;
#pragma unroll
    for (int i = 0; i < 16; ++i) {
        const int r = (q << 4) + i;
        float v = 0.f;
        if (bn < 9)       v = wavgk1[(size_t)(k0 + r) * 576 + n0 + c];
        else if (bn < 57) v = RKV[(size_t)(k0 + r) * 3072 + (n0 + c - 576)];
        tile[r][c] = v;
    }
    __syncthreads();
#pragma unroll
    for (int i = 0; i < 16; ++i) {
        const int rw = (q << 4) + i;
        BT1[(size_t)(n0 + rw) * 2048 + k0 + c] = f2bf(tile[c][rw]);
    }
}

__global__ __launch_bounds__(256) void k_prep_w2t(const float* __restrict__ w2, const float* __restrict__ a2,
                                                  const float* __restrict__ g2, const float* __restrict__ v2,
                                                  const float* __restrict__ k2, u16* __restrict__ W2T) {
    int idx = blockIdx.x * 256 + threadIdx.x;   // n*576 + c, n<7168
    int n = idx / 576, c = idx - n * 576;
    float v = 0.f;
    if (n < 2048)      { if (c < 96)              v = w2[(size_t)c * 2048 + n]; }
    else if (n < 4096) { if (c >= 96 && c < 192)  v = a2[(size_t)(c - 96) * 2048 + (n - 2048)]; }
    else if (n < 6144) { if (c >= 192 && c < 448) v = g2[(size_t)(c - 192) * 2048 + (n - 4096)]; }
    else if (n < 6656) { if (c >= 448 && c < 512) v = v2[(size_t)(c - 448) * 512 + (n - 6144)]; }
    else               { if (c >= 512)            v = k2[(size_t)(c - 512) * 512 + (n - 6656)]; }
    W2T[idx] = f2bf(v);
}

// OT[n][k] = O[k][n], 2048x2048, 64x64 tiles
__global__ __launch_bounds__(256) void k_prep_ot(const float* __restrict__ O, u16* __restrict__ OT) {
    __shared__ float tile[64][65];
    const int bn = blockIdx.x >> 5, bk = blockIdx.x & 31;
    const int n0 = bn << 6, k0 = bk << 6;
    const int c = threadIdx.x & 63, q = threadIdx.x >> 6;
#pragma unroll
    for (int i = 0; i < 16; ++i) {
        const int r = (q << 4) + i;
        tile[r][c] = O[(size_t)(k0 + r) * 2048 + n0 + c];
    }
    __syncthreads();
#pragma unroll
    for (int i = 0; i < 16; ++i) {
        const int rw = (q << 4) + i;
        OT[(size_t)(n0 + rw) * 2048 + k0 + c] = f2bf(tile[c][rw]);
    }
}

// ---------- rmsnorm(x_in, ln1) -> bf16 ----------
__global__ __launch_bounds__(256) void k_rms1(const float* __restrict__ X,
                                              const float* __restrict__ ln1,
                                              u16* __restrict__ XB) {
    const int t = blockIdx.x, tid = threadIdx.x;
    const float* row = X + ((size_t)t << 11);
    float4 v0 = *(const float4*)(row + tid * 8);
    float4 v1 = *(const float4*)(row + tid * 8 + 4);
    float ss = v0.x*v0.x + v0.y*v0.y + v0.z*v0.z + v0.w*v0.w
             + v1.x*v1.x + v1.y*v1.y + v1.z*v1.z + v1.w*v1.w;
    ss = wsum(ss);
    __shared__ float red[4];
    if ((tid & 63) == 0) red[tid >> 6] = ss;
    __syncthreads();
    float scale = rsqrtf((red[0] + red[1] + red[2] + red[3]) * (1.f / 2048.f) + 1e-6f);
    float4 w0_ = *(const float4*)(ln1 + tid * 8);
    float4 w1_ = *(const float4*)(ln1 + tid * 8 + 4);
    u16* o = XB + ((size_t)t << 11) + tid * 8;
    o[0] = f2bf(v0.x * scale * w0_.x); o[1] = f2bf(v0.y * scale * w0_.y);
    o[2] = f2bf(v0.z * scale * w0_.z); o[3] = f2bf(v0.w * scale * w0_.w);
    o[4] = f2bf(v1.x * scale * w1_.x); o[5] = f2bf(v1.y * scale * w1_.y);
    o[6] = f2bf(v1.z * scale * w1_.z); o[7] = f2bf(v1.w * scale * w1_.w);
}

// ---------- generic bf16 MFMA GEMM with LDS chunk swizzle ----------
__global__ __launch_bounds__(256) void k_gemm(const u16* __restrict__ A,
                                              const u16* __restrict__ Bt,
                                              float* __restrict__ C,
                                              int M, int N, int K) {
    __shared__ __align__(16) u16 tA[4096];  // [128 rows][32 k]
    __shared__ __align__(16) u16 tB[4096];
    const int tid = threadIdx.x;
    const int w = tid >> 6, l = tid & 63;
    const int bm = blockIdx.x << 7, bn = blockIdx.y << 7;
    const int wm = (w >> 1) << 6, wn = (w & 1) << 6;
    const int lrow = l >> 2;        // 0..15 (staged row within 16-row group)
    const int lk = (((l & 3) ^ ((l >> 3) & 3)) << 3);   // pre-swizzled global chunk
    f32x4 acc[4][4] = {};
    const size_t rA0 = (size_t)(bm + (w << 4) + lrow) * K;
    const size_t rA1 = (size_t)(bm + ((w + 4) << 4) + lrow) * K;
    const size_t rB0 = (size_t)(bn + (w << 4) + lrow) * K;
    const size_t rB1 = (size_t)(bn + ((w + 4) << 4) + lrow) * K;
    const int frow = l & 15;
    const int koff = (((l >> 4) ^ ((l >> 1) & 3)) << 3);  // swizzled read chunk
    for (int kt = 0; kt < K; kt += 32) {
        gload_lds16(A + rA0 + kt + lk, &tA[w << 9]);
        gload_lds16(A + rA1 + kt + lk, &tA[2048 + (w << 9)]);
        gload_lds16(Bt + rB0 + kt + lk, &tB[w << 9]);
        gload_lds16(Bt + rB1 + kt + lk, &tB[2048 + (w << 9)]);
        __syncthreads();
        bf16x8 av[4], bv[4];
#pragma unroll
        for (int i = 0; i < 4; ++i) {
            av[i] = *(const bf16x8*)&tA[((wm + (i << 4) + frow) << 5) + koff];
            bv[i] = *(const bf16x8*)&tB[((wn + (i << 4) + frow) << 5) + koff];
        }
#pragma unroll
        for (int i = 0; i < 4; ++i)
#pragma unroll
            for (int j = 0; j < 4; ++j)
                acc[i][j] = __builtin_amdgcn_mfma_f32_16x16x32_bf16(av[i], bv[j], acc[i][j], 0, 0, 0);
        __syncthreads();
    }
    const int crow = bm + wm + ((l >> 4) << 2);
    const int ccol = bn + wn + (l & 15);
#pragma unroll
    for (int i = 0; i < 4; ++i)
#pragma unroll
        for (int j = 0; j < 4; ++j)
#pragma unroll
            for (int jj = 0; jj < 4; ++jj)
                C[(size_t)(crow + (i << 4) + jj) * N + ccol + (j << 4)] = acc[i][j][jj];
}

// ---------- GEMM2 specialization: block-diagonal W2T, per-segment true K ----------
__global__ __launch_bounds__(256) void k_gemm2(const u16* __restrict__ A,
                                               const u16* __restrict__ Bt,
                                               float* __restrict__ C) {
    __shared__ __align__(16) u16 tA[4096];
    __shared__ __align__(16) u16 tB[4096];
    const int tid = threadIdx.x;
    const int w = tid >> 6, l = tid & 63;
    const int by = blockIdx.y;
    int c0, K;
    if (by < 16)      { c0 = 0;   K = 96; }
    else if (by < 32) { c0 = 96;  K = 96; }
    else if (by < 48) { c0 = 192; K = 256; }
    else if (by < 52) { c0 = 448; K = 64; }
    else              { c0 = 512; K = 64; }
    const int n0 = by << 7;
    const int bm = blockIdx.x << 7;
    const int wm = (w >> 1) << 6, wn = (w & 1) << 6;
    const int lrow = l >> 2;
    const int lk = (((l & 3) ^ ((l >> 3) & 3)) << 3);
    f32x4 acc[4][4] = {};
    const size_t rA0 = (size_t)(bm + (w << 4) + lrow) * 576 + c0;
    const size_t rA1 = (size_t)(bm + ((w + 4) << 4) + lrow) * 576 + c0;
    const size_t rB0 = (size_t)(n0 + (w << 4) + lrow) * 576 + c0;
    const size_t rB1 = (size_t)(n0 + ((w + 4) << 4) + lrow) * 576 + c0;
    const int frow = l & 15;
    const int koff = (((l >> 4) ^ ((l >> 1) & 3)) << 3);
    for (int kt = 0; kt < K; kt += 32) {
        gload_lds16(A + rA0 + kt + lk, &tA[w << 9]);
        gload_lds16(A + rA1 + kt + lk, &tA[2048 + (w << 9)]);
        gload_lds16(Bt + rB0 + kt + lk, &tB[w << 9]);
        gload_lds16(Bt + rB1 + kt + lk, &tB[2048 + (w << 9)]);
        __syncthreads();
        bf16x8 av[4], bv[4];
#pragma unroll
        for (int i = 0; i < 4; ++i) {
            av[i] = *(const bf16x8*)&tA[((wm + (i << 4) + frow) << 5) + koff];
            bv[i] = *(const bf16x8*)&tB[((wn + (i << 4) + frow) << 5) + koff];
        }
#pragma unroll
        for (int i = 0; i < 4; ++i)
#pragma unroll
            for (int j = 0; j < 4; ++j)
                acc[i][j] = __builtin_amdgcn_mfma_f32_16x16x32_bf16(av[i], bv[j], acc[i][j], 0, 0, 0);
        __syncthreads();
    }
    const int crow = bm + wm + ((l >> 4) << 2);
    const int ccol = n0 + wn + (l & 15);
#pragma unroll
    for (int i = 0; i < 4; ++i)
#pragma unroll
        for (int j = 0; j < 4; ++j)
#pragma unroll
            for (int jj = 0; jj < 4; ++jj)
                C[(size_t)(crow + (i << 4) + jj) * N2 + ccol + (j << 4)] = acc[i][j][jj];
}

// ---------- Y1 -> X2 (bf16): [tanh(xw) | xa | sigmoid(xg) | xv | xk] ----------
__global__ __launch_bounds__(256) void k_prep_x2(const float* __restrict__ Y1, u16* __restrict__ X2) {
    int idx = blockIdx.x * 256 + threadIdx.x;   // t*576 + c
    int t = idx / 576, c = idx - t * 576;
    const float* y1 = Y1 + (size_t)t * N1;
    float v;
    if (c < 96)       v = tanhf(y1[c]);
    else if (c < 192) v = y1[c];
    else if (c < 448) v = sigm(y1[c + 64]);
    else if (c < 512) v = y1[c - 256];
    else              v = y1[c];
    X2[idx] = f2bf(v);
}

// ---------- per-token recurrence prep (+ packed bf16 coefficient pairs) ----------
__global__ __launch_bounds__(256) void k_prep_rec(
    const float* __restrict__ Y1, const float* __restrict__ Y2,
    const float* __restrict__ v_first, const float* __restrict__ k_first,
    const float* __restrict__ cosb, const float* __restrict__ sinb,
    const float* __restrict__ w0, const float* __restrict__ a0,
    const float* __restrict__ v0b, const float* __restrict__ k0b,
    const float* __restrict__ R_bias, const float* __restrict__ K_bias,
    const float* __restrict__ V_bias, const float* __restrict__ ln_r,
    const float* __restrict__ ln_k,
    float* __restrict__ RR, float* __restrict__ DEC, float* __restrict__ KR,
    float* __restrict__ VV, u32* __restrict__ PAB, u32* __restrict__ PKR) {
    const int t = blockIdx.x, tid = threadIdx.x;
    const int ww = tid >> 6, lane = tid & 63;
    const float* y1 = Y1 + (size_t)t * N1;
    const float* y2 = Y2 + (size_t)t * N2;
    const float cs = cosb[t * 64 + lane];
    const float sn = sinb[t * 64 + lane];
    const float sign = lane < 32 ? -1.f : 1.f;
    const size_t tb = (size_t)t << 11;
    __shared__ float kkv[512], vkv[512];
    float rsave[8];
    // r: per-head rmsnorm + rope
#pragma unroll
    for (int i = 0; i < 8; ++i) {
        int h = ww * 8 + i, c = h * 64 + lane;
        float rr = y1[576 + c] + R_bias[c];
        float ssq = wsum(rr * rr);
        float rn = ln_r[lane] * rr * rsqrtf(ssq * (1.f / 64.f) + 1e-6f);
        float rot = sign * __shfl(rn, lane ^ 32, 64);
        rsave[i] = rn * cs + rot * sn;
        RR[tb + c] = rsave[i];
    }
    // k,v kv-heads: rmsnorm+rope+mix
#pragma unroll
    for (int i = 0; i < 2; ++i) {
        int j = ww * 2 + i, c = j * 64 + lane;
        float kr = y1[2624 + c] + K_bias[c];
        float ssq = wsum(kr * kr);
        float kn = ln_k[lane] * kr * rsqrtf(ssq * (1.f / 64.f) + 1e-6f);
        float rot = sign * __shfl(kn, lane ^ 32, 64);
        float krope = kn * cs + rot * sn;
        float ksig = sigm(y2[6656 + c] + k0b[c]);
        kkv[c] = krope + (k_first[(size_t)t * 512 + c] - krope) * ksig;
        float vr = y1[3136 + c] + V_bias[c];
        float vsig = sigm(y2[6144 + c] + v0b[c]);
        vkv[c] = vr + (v_first[(size_t)t * 512 + c] - vr) * vsig;
    }
    __syncthreads();
    // per-head final recurrence operands
#pragma unroll
    for (int i = 0; i < 8; ++i) {
        int h = ww * 8 + i, c = h * 64 + lane;
        int ckv = (h >> 2) * 64 + lane;
        float kb = kkv[ckv], vb = vkv[ckv];
        float a_ = sigm(y2[2048 + c] + a0[c]);
        float wr = y2[c] + w0[c];
        float z = -wr;
        float sp = fmaxf(z, 0.f) + log1pf(expf(-fabsf(z)));
        float w_log = -sp - 0.5f;
        float ssq = wsum(kb * kb);
        float kk = kb / fmaxf(sqrtf(ssq), 1e-12f);
        const float kr2 = kb * (1.f - w_log + a_);
        DEC[tb + c] = expf(-expf(w_log));
        KR[tb + c] = kr2;
        VV[tb + c] = vb;
        PAB[tb + c] = (u32)f2bf(-kk) | ((u32)f2bf(kk * a_) << 16);
        PKR[tb + c] = (u32)f2bf(kr2) | ((u32)f2bf(rsave[i]) << 16);
    }
}

// ---------- sequential recurrence: 4 blocks/chain, asm bursts, bf16-packed coeffs ----------
// r20 structure (best: 170.6us). DS bytes per step per lane cut 88->52 via bf16
// pairs: PAB = bf16(A)|bf16(B)<<16, PKR = bf16(K)|bf16(R)<<16 (DEC & V stay f32
// — DEC compounds multiplicatively; state f32). DS/CU ~160 cyc/step vs 264.
// cbuf[b][ar][s][x]: buffer stride 32768B, arr stride 8192B, step stride 256B.
// arrays: 0=DEC(f32) 1=PAB(u32) 2=PKR(u32) 3=VV(f32).
__global__ __launch_bounds__(256, 1) void k_recv14(
    const float* __restrict__ DECp, const u32* __restrict__ PABp,
    const u32* __restrict__ PKRp, const float* __restrict__ VVp,
    const float* __restrict__ S0, float* __restrict__ OO) {
    __shared__ __align__(16) float cbuf[2][4][32][64];   // 64 KB
    const int tid = threadIdx.x;
    const int wl = tid >> 6;           // wave 0..3
    const int lane = tid & 63;
    const int vl = lane >> 4;          // DPP row 0..3
    const int kq = lane & 15;          // k-quad 0..15
    const int quarter = blockIdx.x & 3;
    const int ch = blockIdx.x >> 2;          // chain 0..63 (b*32+h)
    const int vcol = (quarter << 4) + (wl << 2) + vl;   // this row's v-column
    const size_t cb = ((size_t)(ch >> 5) * 1024 * 2048) + ((size_t)(ch & 31) << 6);

    // state: Lj = S[4kq+j][vcol]
    const float* s0 = S0 + ((size_t)ch << 12);
    float L0 = s0[((kq << 2) + 0) * 64 + vcol];
    float L1 = s0[((kq << 2) + 1) * 64 + vcol];
    float L2 = s0[((kq << 2) + 2) * 64 + vcol];
    float L3 = s0[((kq << 2) + 3) * 64 + vcol];

    const int trow = (wl << 2) + vl;   // 0..15; rows trow and trow+16 staged

#define STG(B, T0)                                                             \
    {                                                                          \
        const size_t g0 = cb + (size_t)((T0) + trow) * 2048 + (kq << 2);       \
        const size_t g1 = cb + (size_t)((T0) + 16 + trow) * 2048 + (kq << 2);  \
        float* lb = &cbuf[B][0][0][0] + (wl << 8);                             \
        gload_lds16(DECp + g0, lb);                                            \
        gload_lds16(DECp + g1, lb + 1024);                                     \
        gload_lds16(PABp + g0, lb + 2048);                                     \
        gload_lds16(PABp + g1, lb + 3072);                                     \
        gload_lds16(PKRp + g0, lb + 4096);                                     \
        gload_lds16(PKRp + g1, lb + 5120);                                     \
        gload_lds16(VVp + g0, lb + 6144);                                      \
        gload_lds16(VVp + g1, lb + 7168);                                      \
    }

    // LDS byte address of cbuf base (generic->LDS offset: aperture 4GB-aligned)
    const u32 base0 = (u32)(size_t)(void*)&cbuf[0][0][0][0];
    const u32 aA0 = base0 + (kq << 4);             // coefficient chunk for lane
    const u32 aV0 = base0 + 24576 + (vcol << 2);   // V broadcast slot

#define LDSTEP(J)                                                              \
    cD[J] = ds_read128<(J) * 256>(aA);                                         \
    cPA[J] = ds_read128u<8192 + (J) * 256>(aA);                                \
    cPK[J] = ds_read128u<16384 + (J) * 256>(aA);                               \
    cV[J] = ds_read32<(J) * 256>(aV);

#define UNP_LO(u) __uint_as_float((u) << 16)
#define UNP_HI(u) __uint_as_float((u) & 0xffff0000u)

    STG(0, 0);
    __syncthreads();

    for (int c = 0; c < 32; ++c) {
        const int b = c & 1;
        if (c < 31) STG(b ^ 1, (c + 1) << 5);      // async prefetch next chunk
        u32 aA = aA0 + b * 32768;
        u32 aV = aV0 + b * 32768;
        int t = c << 5;
        for (int g = 0; g < 4; ++g) {              // 4 groups of 8 steps
            float4 cD[8];
            uint4 cPA[8], cPK[8];
            float cV[8];
            LDSTEP(0) LDSTEP(1) LDSTEP(2) LDSTEP(3)
            LDSTEP(4) LDSTEP(5) LDSTEP(6) LDSTEP(7)
            asm volatile("s_waitcnt lgkmcnt(0)" ::: "memory");
            __builtin_amdgcn_sched_barrier(0);
#pragma unroll
            for (int j = 0; j < 8; ++j) {
                const float4 D4 = cD[j];
                const uint4 pa = cPA[j], pk = cPK[j];
                const float Vsj = cV[j];
                const float Ax = UNP_LO(pa.x), Ay = UNP_LO(pa.y),
                            Az = UNP_LO(pa.z), Aw = UNP_LO(pa.w);
                const float Bx = UNP_HI(pa.x), By = UNP_HI(pa.y),
                            Bz = UNP_HI(pa.z), Bw = UNP_HI(pa.w);
                const float Kx = UNP_LO(pk.x), Ky = UNP_LO(pk.y),
                            Kz = UNP_LO(pk.z), Kw = UNP_LO(pk.w);
                const float Rx = UNP_HI(pk.x), Ry = UNP_HI(pk.y),
                            Rz = UNP_HI(pk.z), Rw = UNP_HI(pk.w);
                float sp = fmaf(L1, Ay, L0 * Ax) + fmaf(L3, Aw, L2 * Az);
                const float sa = rowsum16(sp);
                L0 = fmaf(Bx, sa, fmaf(Kx, Vsj, L0 * D4.x));
                L1 = fmaf(By, sa, fmaf(Ky, Vsj, L1 * D4.y));
                L2 = fmaf(Bz, sa, fmaf(Kz, Vsj, L2 * D4.z));
                L3 = fmaf(Bw, sa, fmaf(Kw, Vsj, L3 * D4.w));
                float op = fmaf(L1, Ry, L0 * Rx) + fmaf(L3, Rw, L2 * Rz);
                const float o = rowsum16(op);
                if (kq == 0) OO[cb + ((size_t)(t + j) << 11) + vcol] = o;
            }
            t += 8;
            aA += 2048;
            aV += 2048;
        }
        __syncthreads();   // drains staging vmcnt (1/32 steps); flips buffers
    }
#undef UNP_LO
#undef UNP_HI
#undef LDSTEP
#undef STG
}

// ---------- bonus + gate -> bf16 ----------
__global__ __launch_bounds__(256) void k_gate(
    const float* __restrict__ OOp, const float* __restrict__ RRp,
    const float* __restrict__ KRp, const float* __restrict__ VVp,
    const float* __restrict__ Y2, const float* __restrict__ r_k,
    u16* __restrict__ XG) {
    const int t = blockIdx.x, tid = threadIdx.x;
    const int ww = tid >> 6, lane = tid & 63;
    const size_t tb = (size_t)t << 11;
#pragma unroll
    for (int i = 0; i < 8; ++i) {
        int c = (ww * 8 + i) * 64 + lane;
        float pr = RRp[tb + c] * KRp[tb + c] * r_k[c];
        float dot = wsum(pr);
        float xx = OOp[tb + c] * 0.125f + dot * VVp[tb + c];
        float g = Y2[(size_t)t * N2 + 4096 + c];
        XG[tb + c] = f2bf(xx * g);
    }
}

// ---------- final residual + rmsnorm ----------
__global__ __launch_bounds__(256) void k_final(const float* __restrict__ x_in,
                                               const float* __restrict__ OUTR,
                                               const float* __restrict__ ln2,
                                               float* __restrict__ out) {
    const int t = blockIdx.x, tid = threadIdx.x;
    const float* xr = x_in + ((size_t)t << 11);
    const float* orow = OUTR + ((size_t)t << 11);
    float4 a0 = *(const float4*)(xr + tid * 8);
    float4 a1 = *(const float4*)(xr + tid * 8 + 4);
    float4 b0 = *(const float4*)(orow + tid * 8);
    float4 b1 = *(const float4*)(orow + tid * 8 + 4);
    float v[8] = {a0.x + b0.x, a0.y + b0.y, a0.z + b0.z, a0.w + b0.w,
                  a1.x + b1.x, a1.y + b1.y, a1.z + b1.z, a1.w + b1.w};
    float ss = 0.f;
#pragma unroll
    for (int i = 0; i < 8; ++i) ss = fmaf(v[i], v[i], ss);
    ss = wsum(ss);
    __shared__ float red[4];
    if ((tid & 63) == 0) red[tid >> 6] = ss;
    __syncthreads();
    float scale = rsqrtf((red[0] + red[1] + red[2] + red[3]) * (1.f / 2048.f) + 1e-6f);
    float* o = out + ((size_t)t << 11) + tid * 8;
#pragma unroll
    for (int i = 0; i < 8; ++i) o[i] = ln2[tid * 8 + i] * v[i] * scale;
}

extern "C" void kernel_launch(void* const* d_in, const int* in_sizes, int n_in,
                              void* d_out, int out_size, void* d_ws, size_t ws_size,
                              hipStream_t stream) {
    const float* x_in    = (const float*)d_in[0];
    const float* v_first = (const float*)d_in[1];
    const float* k_first = (const float*)d_in[2];
    const float* state   = (const float*)d_in[3];
    const float* cosb    = (const float*)d_in[4];
    const float* sinb    = (const float*)d_in[5];
    const float* wavgk1  = (const float*)d_in[6];
    const float* w0      = (const float*)d_in[7];
    const float* w2      = (const float*)d_in[8];
    const float* a0      = (const float*)d_in[9];
    const float* a2      = (const float*)d_in[10];
    const float* v0      = (const float*)d_in[11];
    const float* v2      = (const float*)d_in[12];
    const float* g2      = (const float*)d_in[13];
    const float* k0      = (const float*)d_in[14];
    const float* k2      = (const float*)d_in[15];
    const float* r_k     = (const float*)d_in[16];
    const float* RKV     = (const float*)d_in[17];
    const float* O       = (const float*)d_in[18];
    const float* R_bias  = (const float*)d_in[19];
    const float* K_bias  = (const float*)d_in[20];
    const float* V_bias  = (const float*)d_in[21];
    const float* ln_r    = (const float*)d_in[22];
    const float* ln_k    = (const float*)d_in[23];
    const float* ln1     = (const float*)d_in[24];
    const float* ln2     = (const float*)d_in[25];

    if (ws_size < WS_NEED) return;  // need 235.5 MB (fits 256 MiB)

    char* ws = (char*)d_ws;
    u16*   BT1  = (u16*)(ws + OFF_BT1);
    u16*   W2T  = (u16*)(ws + OFF_W2T);
    u16*   OT   = (u16*)(ws + OFF_OT);
    u16*   XB   = (u16*)(ws + OFF_XB);
    float* Y1   = (float*)(ws + OFF_Y1);
    u16*   X2   = (u16*)(ws + OFF_X2);
    float* Y2   = (float*)(ws + OFF_Y2);
    float* RR   = (float*)(ws + OFF_RR);
    float* DEC  = (float*)(ws + OFF_DEC);
    float* KR   = (float*)(ws + OFF_KR);
    float* VV   = (float*)(ws + OFF_VV);
    u32*   PAB  = (u32*)(ws + OFF_PAB);
    u32*   PKR  = (u32*)(ws + OFF_PKR);
    float* OO   = (float*)(ws + OFF_OO);
    u16*   XG   = (u16*)(ws + OFF_XG);
    float* OUTR = (float*)(ws + OFF_OUTR);

    // P0: BT1 + XB (region C)
    k_prep_bt1<<<1856, 256, 0, stream>>>(wavgk1, RKV, BT1);
    k_rms1<<<2048, 256, 0, stream>>>(x_in, ln1, XB);
    // P1: GEMM1 -> Y1  (region A)
    k_gemm<<<dim3(16, 29), 256, 0, stream>>>(XB, BT1, Y1, 2048, N1, 2048);
    // P2: W2T + X2 overwrite BT1/XB (dead); GEMM2 (block-diagonal) -> Y2 (region B)
    k_prep_w2t<<<16128, 256, 0, stream>>>(w2, a2, g2, v2, k2, W2T);
    k_prep_x2<<<4608, 256, 0, stream>>>(Y1, X2);
    k_gemm2<<<dim3(16, 56), 256, 0, stream>>>(X2, W2T, Y2);
    // P3: recurrence operands (region D); Y1 dead after this
    k_prep_rec<<<2048, 256, 0, stream>>>(Y1, Y2, v_first, k_first, cosb, sinb,
                                         w0, a0, v0, k0, R_bias, K_bias, V_bias,
                                         ln_r, ln_k, RR, DEC, KR, VV, PAB, PKR);
    // P4: OT overwrites W2T/X2 (dead); recurrence -> OO (in old Y1 space)
    k_prep_ot<<<1024, 256, 0, stream>>>(O, OT);
    k_recv14<<<256, 256, 0, stream>>>(DEC, PAB, PKR, VV, state, OO);
    // P5: gate -> XG (in old Y1 space); Y2 dead after this
    k_gate<<<2048, 256, 0, stream>>>(OO, RR, KR, VV, Y2, r_k, XG);
    // P6: GEMM3 -> OUTR (in old Y2 space); final norm
    k_gemm<<<dim3(16, 16), 256, 0, stream>>>(XG, OT, OUTR, 2048, 2048, 2048);
    k_final<<<2048, 256, 0, stream>>>(x_in, OUTR, ln2, (float*)d_out);
}

// Round 24
// 376.904 us; speedup vs baseline: 1.1058x; 1.0241x over previous
//
#include <hip/hip_runtime.h>

typedef unsigned short u16;
typedef unsigned int u32;

using f32x4 = __attribute__((ext_vector_type(4))) float;
using bf16x8 = __attribute__((ext_vector_type(8))) __bf16;

// ---------- constants ----------
#define HN 2048
#define KVD 512
#define TOKENS 2048          // B*T
#define N1 3712              // GEMM1 N (3648 padded to 29*128)
#define K2W 576              // GEMM2 K
#define N2 7168              // GEMM2 N: w(2048) a(2048) g(2048) v(512) k(512)

// ---------- workspace layout (bytes) — lifetime-aliased, peak 235.5 MB ----------
#define OFF_Y1   0ull
#define OFF_OO   0ull
#define OFF_XG   16777216ull
#define OFF_Y2   30408704ull
#define OFF_OUTR 30408704ull
#define OFF_BT1  89128960ull
#define OFF_XB   104333312ull
#define OFF_W2T  89128960ull
#define OFF_X2   97386496ull
#define OFF_OT   89128960ull
#define OFF_RR   112721920ull
#define OFF_DEC  129499136ull
#define OFF_KR   146276352ull
#define OFF_VV   163053568ull
#define OFF_AA   179830784ull
#define OFF_BB   196608000ull
#define OFF_PAB  213385216ull            // u32 [2048][2048]: bf16(A) | bf16(B)<<16
#define OFF_PKR  230162432ull            // u32 [2048][2048]: bf16(K) | bf16(R)<<16
#define WS_NEED  246939648ull

// ---------- helpers ----------
__device__ __forceinline__ u16 f2bf(float f) {
    u32 u = __float_as_uint(f);
    u32 r = u + 0x7fffu + ((u >> 16) & 1u);
    return (u16)(r >> 16);
}
__device__ __forceinline__ float sigm(float x) { return 1.f / (1.f + expf(-x)); }
__device__ __forceinline__ float wsum(float v) {
#pragma unroll
    for (int m = 32; m > 0; m >>= 1) v += __shfl_xor(v, m, 64);
    return v;
}
// sum across each 16-lane DPP row via row_ror 1,2,4,8; result in all lanes of the row
__device__ __forceinline__ float rowsum16(float v) {
    float t;
    t = __uint_as_float(__builtin_amdgcn_update_dpp(0, __float_as_uint(v), 0x121, 0xf, 0xf, true));
    v += t;
    t = __uint_as_float(__builtin_amdgcn_update_dpp(0, __float_as_uint(v), 0x122, 0xf, 0xf, true));
    v += t;
    t = __uint_as_float(__builtin_amdgcn_update_dpp(0, __float_as_uint(v), 0x124, 0xf, 0xf, true));
    v += t;
    t = __uint_as_float(__builtin_amdgcn_update_dpp(0, __float_as_uint(v), 0x128, 0xf, 0xf, true));
    v += t;
    return v;
}

typedef __attribute__((address_space(1))) const void glob_t;
typedef __attribute__((address_space(3))) void lds_t;
__device__ __forceinline__ void gload_lds16(const void* g, void* l) {
    __builtin_amdgcn_global_load_lds((glob_t*)g, (lds_t*)l, 16, 0, 0);
}

// inline-asm LDS readers with literal offset (burst-issued, order preserved)
template<int OFF>
__device__ __forceinline__ float4 ds_read128(u32 a) {
    float4 r;
    asm volatile("ds_read_b128 %0, %1 offset:%2" : "=v"(r) : "v"(a), "i"(OFF));
    return r;
}
template<int OFF>
__device__ __forceinline__ uint4 ds_read128u(u32 a) {
    uint4 r;
    asm volatile("ds_read_b128 %0, %1 offset:%2" : "=v"(r) : "v"(a), "i"(OFF));
    return r;
}
template<int OFF>
__device__ __forceinline__ float ds_read32(u32 a) {
    float r;
    asm volatile("ds_read_b32 %0, %1 offset:%2" : "=v"(r) : "v"(a), "i"(OFF));
    return r;
}

// ---------- weight prep: tiled transposes (coalesced read AND write) ----------
__global__ __launch_bounds__(256) void k_prep_bt1(const float* __restrict__ wavgk1,
                                                  const float* __restrict__ RKV,
                                                  u16* __restrict__ BT1) {
    __shared__ float tile[64][65];
    const int bn = blockIdx.x >> 5;        // 0..57
    const int bk = blockIdx.x & 31;        // 0..31
    const int n0 = bn << 6, k0 = bk << 6;
    const int c = threadIdx.x & 63, q = threadIdx.x >> 6;
#pragma unroll
    for (int i = 0; i < 16; ++i) {
        const int r = (q << 4) + i;
        float v = 0.f;
        if (bn < 9)       v = wavgk1[(size_t)(k0 + r) * 576 + n0 + c];
        else if (bn < 57) v = RKV[(size_t)(k0 + r) * 3072 + (n0 + c - 576)];
        tile[r][c] = v;
    }
    __syncthreads();
#pragma unroll
    for (int i = 0; i < 16; ++i) {
        const int rw = (q << 4) + i;
        BT1[(size_t)(n0 + rw) * 2048 + k0 + c] = f2bf(tile[c][rw]);
    }
}

// W2T[n][c] = blockdiag src[c][n]; 64x64 tiles, both sides coalesced.
// grid: 112 n-tiles x 9 c-tiles = 1008 blocks.
__global__ __launch_bounds__(256) void k_prep_w2t(const float* __restrict__ w2, const float* __restrict__ a2,
                                                  const float* __restrict__ g2, const float* __restrict__ v2,
                                                  const float* __restrict__ k2, u16* __restrict__ W2T) {
    __shared__ float tile[64][65];
    const int bx = blockIdx.x;
    const int bn = bx / 9, bc = bx - bn * 9;
    const int n0 = bn << 6, c0 = bc << 6;
    const int cc = threadIdx.x & 63, q = threadIdx.x >> 6;
#pragma unroll
    for (int i = 0; i < 16; ++i) {
        const int r = (q << 4) + i;        // c-offset within tile
        const int c = c0 + r;
        const int n = n0 + cc;
        float v = 0.f;
        if (n0 < 2048)      { if (c < 96)              v = w2[(size_t)c * 2048 + n]; }
        else if (n0 < 4096) { if (c >= 96 && c < 192)  v = a2[(size_t)(c - 96) * 2048 + (n - 2048)]; }
        else if (n0 < 6144) { if (c >= 192 && c < 448) v = g2[(size_t)(c - 192) * 2048 + (n - 4096)]; }
        else if (n0 < 6656) { if (c >= 448 && c < 512) v = v2[(size_t)(c - 448) * 512 + (n - 6144)]; }
        else                { if (c >= 512)            v = k2[(size_t)(c - 512) * 512 + (n - 6656)]; }
        tile[r][cc] = v;
    }
    __syncthreads();
#pragma unroll
    for (int i = 0; i < 16; ++i) {
        const int rw = (q << 4) + i;       // n-offset within tile
        W2T[(size_t)(n0 + rw) * 576 + c0 + cc] = f2bf(tile[cc][rw]);
    }
}

// OT[n][k] = O[k][n], 2048x2048, 64x64 tiles
__global__ __launch_bounds__(256) void k_prep_ot(const float* __restrict__ O, u16* __restrict__ OT) {
    __shared__ float tile[64][65];
    const int bn = blockIdx.x >> 5, bk = blockIdx.x & 31;
    const int n0 = bn << 6, k0 = bk << 6;
    const int c = threadIdx.x & 63, q = threadIdx.x >> 6;
#pragma unroll
    for (int i = 0; i < 16; ++i) {
        const int r = (q << 4) + i;
        tile[r][c] = O[(size_t)(k0 + r) * 2048 + n0 + c];
    }
    __syncthreads();
#pragma unroll
    for (int i = 0; i < 16; ++i) {
        const int rw = (q << 4) + i;
        OT[(size_t)(n0 + rw) * 2048 + k0 + c] = f2bf(tile[c][rw]);
    }
}

// ---------- rmsnorm(x_in, ln1) -> bf16 ----------
__global__ __launch_bounds__(256) void k_rms1(const float* __restrict__ X,
                                              const float* __restrict__ ln1,
                                              u16* __restrict__ XB) {
    const int t = blockIdx.x, tid = threadIdx.x;
    const float* row = X + ((size_t)t << 11);
    float4 v0 = *(const float4*)(row + tid * 8);
    float4 v1 = *(const float4*)(row + tid * 8 + 4);
    float ss = v0.x*v0.x + v0.y*v0.y + v0.z*v0.z + v0.w*v0.w
             + v1.x*v1.x + v1.y*v1.y + v1.z*v1.z + v1.w*v1.w;
    ss = wsum(ss);
    __shared__ float red[4];
    if ((tid & 63) == 0) red[tid >> 6] = ss;
    __syncthreads();
    float scale = rsqrtf((red[0] + red[1] + red[2] + red[3]) * (1.f / 2048.f) + 1e-6f);
    float4 w0_ = *(const float4*)(ln1 + tid * 8);
    float4 w1_ = *(const float4*)(ln1 + tid * 8 + 4);
    u16* o = XB + ((size_t)t << 11) + tid * 8;
    o[0] = f2bf(v0.x * scale * w0_.x); o[1] = f2bf(v0.y * scale * w0_.y);
    o[2] = f2bf(v0.z * scale * w0_.z); o[3] = f2bf(v0.w * scale * w0_.w);
    o[4] = f2bf(v1.x * scale * w1_.x); o[5] = f2bf(v1.y * scale * w1_.y);
    o[6] = f2bf(v1.z * scale * w1_.z); o[7] = f2bf(v1.w * scale * w1_.w);
}

// ---------- generic bf16 MFMA GEMM with LDS chunk swizzle ----------
__global__ __launch_bounds__(256) void k_gemm(const u16* __restrict__ A,
                                              const u16* __restrict__ Bt,
                                              float* __restrict__ C,
                                              int M, int N, int K) {
    __shared__ __align__(16) u16 tA[4096];  // [128 rows][32 k]
    __shared__ __align__(16) u16 tB[4096];
    const int tid = threadIdx.x;
    const int w = tid >> 6, l = tid & 63;
    const int bm = blockIdx.x << 7, bn = blockIdx.y << 7;
    const int wm = (w >> 1) << 6, wn = (w & 1) << 6;
    const int lrow = l >> 2;        // 0..15 (staged row within 16-row group)
    const int lk = (((l & 3) ^ ((l >> 3) & 3)) << 3);   // pre-swizzled global chunk
    f32x4 acc[4][4] = {};
    const size_t rA0 = (size_t)(bm + (w << 4) + lrow) * K;
    const size_t rA1 = (size_t)(bm + ((w + 4) << 4) + lrow) * K;
    const size_t rB0 = (size_t)(bn + (w << 4) + lrow) * K;
    const size_t rB1 = (size_t)(bn + ((w + 4) << 4) + lrow) * K;
    const int frow = l & 15;
    const int koff = (((l >> 4) ^ ((l >> 1) & 3)) << 3);  // swizzled read chunk
    for (int kt = 0; kt < K; kt += 32) {
        gload_lds16(A + rA0 + kt + lk, &tA[w << 9]);
        gload_lds16(A + rA1 + kt + lk, &tA[2048 + (w << 9)]);
        gload_lds16(Bt + rB0 + kt + lk, &tB[w << 9]);
        gload_lds16(Bt + rB1 + kt + lk, &tB[2048 + (w << 9)]);
        __syncthreads();
        bf16x8 av[4], bv[4];
#pragma unroll
        for (int i = 0; i < 4; ++i) {
            av[i] = *(const bf16x8*)&tA[((wm + (i << 4) + frow) << 5) + koff];
            bv[i] = *(const bf16x8*)&tB[((wn + (i << 4) + frow) << 5) + koff];
        }
#pragma unroll
        for (int i = 0; i < 4; ++i)
#pragma unroll
            for (int j = 0; j < 4; ++j)
                acc[i][j] = __builtin_amdgcn_mfma_f32_16x16x32_bf16(av[i], bv[j], acc[i][j], 0, 0, 0);
        __syncthreads();
    }
    const int crow = bm + wm + ((l >> 4) << 2);
    const int ccol = bn + wn + (l & 15);
#pragma unroll
    for (int i = 0; i < 4; ++i)
#pragma unroll
        for (int j = 0; j < 4; ++j)
#pragma unroll
            for (int jj = 0; jj < 4; ++jj)
                C[(size_t)(crow + (i << 4) + jj) * N + ccol + (j << 4)] = acc[i][j][jj];
}

// ---------- GEMM2 specialization: block-diagonal W2T, per-segment true K ----------
__global__ __launch_bounds__(256) void k_gemm2(const u16* __restrict__ A,
                                               const u16* __restrict__ Bt,
                                               float* __restrict__ C) {
    __shared__ __align__(16) u16 tA[4096];
    __shared__ __align__(16) u16 tB[4096];
    const int tid = threadIdx.x;
    const int w = tid >> 6, l = tid & 63;
    const int by = blockIdx.y;
    int c0, K;
    if (by < 16)      { c0 = 0;   K = 96; }
    else if (by < 32) { c0 = 96;  K = 96; }
    else if (by < 48) { c0 = 192; K = 256; }
    else if (by < 52) { c0 = 448; K = 64; }
    else              { c0 = 512; K = 64; }
    const int n0 = by << 7;
    const int bm = blockIdx.x << 7;
    const int wm = (w >> 1) << 6, wn = (w & 1) << 6;
    const int lrow = l >> 2;
    const int lk = (((l & 3) ^ ((l >> 3) & 3)) << 3);
    f32x4 acc[4][4] = {};
    const size_t rA0 = (size_t)(bm + (w << 4) + lrow) * 576 + c0;
    const size_t rA1 = (size_t)(bm + ((w + 4) << 4) + lrow) * 576 + c0;
    const size_t rB0 = (size_t)(n0 + (w << 4) + lrow) * 576 + c0;
    const size_t rB1 = (size_t)(n0 + ((w + 4) << 4) + lrow) * 576 + c0;
    const int frow = l & 15;
    const int koff = (((l >> 4) ^ ((l >> 1) & 3)) << 3);
    for (int kt = 0; kt < K; kt += 32) {
        gload_lds16(A + rA0 + kt + lk, &tA[w << 9]);
        gload_lds16(A + rA1 + kt + lk, &tA[2048 + (w << 9)]);
        gload_lds16(Bt + rB0 + kt + lk, &tB[w << 9]);
        gload_lds16(Bt + rB1 + kt + lk, &tB[2048 + (w << 9)]);
        __syncthreads();
        bf16x8 av[4], bv[4];
#pragma unroll
        for (int i = 0; i < 4; ++i) {
            av[i] = *(const bf16x8*)&tA[((wm + (i << 4) + frow) << 5) + koff];
            bv[i] = *(const bf16x8*)&tB[((wn + (i << 4) + frow) << 5) + koff];
        }
#pragma unroll
        for (int i = 0; i < 4; ++i)
#pragma unroll
            for (int j = 0; j < 4; ++j)
                acc[i][j] = __builtin_amdgcn_mfma_f32_16x16x32_bf16(av[i], bv[j], acc[i][j], 0, 0, 0);
        __syncthreads();
    }
    const int crow = bm + wm + ((l >> 4) << 2);
    const int ccol = n0 + wn + (l & 15);
#pragma unroll
    for (int i = 0; i < 4; ++i)
#pragma unroll
        for (int j = 0; j < 4; ++j)
#pragma unroll
            for (int jj = 0; jj < 4; ++jj)
                C[(size_t)(crow + (i << 4) + jj) * N2 + ccol + (j << 4)] = acc[i][j][jj];
}

// ---------- Y1 -> X2 (bf16): [tanh(xw) | xa | sigmoid(xg) | xv | xk] ----------
__global__ __launch_bounds__(256) void k_prep_x2(const float* __restrict__ Y1, u16* __restrict__ X2) {
    int idx = blockIdx.x * 256 + threadIdx.x;   // t*576 + c
    int t = idx / 576, c = idx - t * 576;
    const float* y1 = Y1 + (size_t)t * N1;
    float v;
    if (c < 96)       v = tanhf(y1[c]);
    else if (c < 192) v = y1[c];
    else if (c < 448) v = sigm(y1[c + 64]);
    else if (c < 512) v = y1[c - 256];
    else              v = y1[c];
    X2[idx] = f2bf(v);
}

// ---------- per-token recurrence prep (+ packed bf16 coefficient pairs) ----------
__global__ __launch_bounds__(256) void k_prep_rec(
    const float* __restrict__ Y1, const float* __restrict__ Y2,
    const float* __restrict__ v_first, const float* __restrict__ k_first,
    const float* __restrict__ cosb, const float* __restrict__ sinb,
    const float* __restrict__ w0, const float* __restrict__ a0,
    const float* __restrict__ v0b, const float* __restrict__ k0b,
    const float* __restrict__ R_bias, const float* __restrict__ K_bias,
    const float* __restrict__ V_bias, const float* __restrict__ ln_r,
    const float* __restrict__ ln_k,
    float* __restrict__ RR, float* __restrict__ DEC, float* __restrict__ KR,
    float* __restrict__ VV, u32* __restrict__ PAB, u32* __restrict__ PKR) {
    const int t = blockIdx.x, tid = threadIdx.x;
    const int ww = tid >> 6, lane = tid & 63;
    const float* y1 = Y1 + (size_t)t * N1;
    const float* y2 = Y2 + (size_t)t * N2;
    const float cs = cosb[t * 64 + lane];
    const float sn = sinb[t * 64 + lane];
    const float sign = lane < 32 ? -1.f : 1.f;
    const size_t tb = (size_t)t << 11;
    __shared__ float kkv[512], vkv[512];
    float rsave[8];
    // r: per-head rmsnorm + rope
#pragma unroll
    for (int i = 0; i < 8; ++i) {
        int h = ww * 8 + i, c = h * 64 + lane;
        float rr = y1[576 + c] + R_bias[c];
        float ssq = wsum(rr * rr);
        float rn = ln_r[lane] * rr * rsqrtf(ssq * (1.f / 64.f) + 1e-6f);
        float rot = sign * __shfl(rn, lane ^ 32, 64);
        rsave[i] = rn * cs + rot * sn;
        RR[tb + c] = rsave[i];
    }
    // k,v kv-heads: rmsnorm+rope+mix
#pragma unroll
    for (int i = 0; i < 2; ++i) {
        int j = ww * 2 + i, c = j * 64 + lane;
        float kr = y1[2624 + c] + K_bias[c];
        float ssq = wsum(kr * kr);
        float kn = ln_k[lane] * kr * rsqrtf(ssq * (1.f / 64.f) + 1e-6f);
        float rot = sign * __shfl(kn, lane ^ 32, 64);
        float krope = kn * cs + rot * sn;
        float ksig = sigm(y2[6656 + c] + k0b[c]);
        kkv[c] = krope + (k_first[(size_t)t * 512 + c] - krope) * ksig;
        float vr = y1[3136 + c] + V_bias[c];
        float vsig = sigm(y2[6144 + c] + v0b[c]);
        vkv[c] = vr + (v_first[(size_t)t * 512 + c] - vr) * vsig;
    }
    __syncthreads();
    // per-head final recurrence operands
#pragma unroll
    for (int i = 0; i < 8; ++i) {
        int h = ww * 8 + i, c = h * 64 + lane;
        int ckv = (h >> 2) * 64 + lane;
        float kb = kkv[ckv], vb = vkv[ckv];
        float a_ = sigm(y2[2048 + c] + a0[c]);
        float wr = y2[c] + w0[c];
        float z = -wr;
        float sp = fmaxf(z, 0.f) + log1pf(expf(-fabsf(z)));
        float w_log = -sp - 0.5f;
        float ssq = wsum(kb * kb);
        float kk = kb / fmaxf(sqrtf(ssq), 1e-12f);
        const float kr2 = kb * (1.f - w_log + a_);
        DEC[tb + c] = expf(-expf(w_log));
        KR[tb + c] = kr2;
        VV[tb + c] = vb;
        PAB[tb + c] = (u32)f2bf(-kk) | ((u32)f2bf(kk * a_) << 16);
        PKR[tb + c] = (u32)f2bf(kr2) | ((u32)f2bf(rsave[i]) << 16);
    }
}

// ---------- sequential recurrence: homogeneous-b128 pipelined DS, V hoisted ----------
// r23's mixed b128/b32 counted-wait raced (stale V). Fix per m201-verified recipe:
// counted lgkmcnt over HOMOGENEOUS b128 only. All 32 V b32 reads hoisted to chunk
// start into cV[32] regs (static indices) + lgkmcnt(0) drain. Pipeline: 2-step
// groups of 6 b128, 2 groups in flight, s_waitcnt lgkmcnt(6)+sched_barrier(0).
__global__ __launch_bounds__(256, 1) void k_recv16(
    const float* __restrict__ DECp, const u32* __restrict__ PABp,
    const u32* __restrict__ PKRp, const float* __restrict__ VVp,
    const float* __restrict__ S0, float* __restrict__ OO) {
    __shared__ __align__(16) float cbuf[2][4][32][64];   // 64 KB
    const int tid = threadIdx.x;
    const int wl = tid >> 6;           // wave 0..3
    const int lane = tid & 63;
    const int vl = lane >> 4;          // DPP row 0..3
    const int kq = lane & 15;          // k-quad 0..15
    const int quarter = blockIdx.x & 3;
    const int ch = blockIdx.x >> 2;          // chain 0..63 (b*32+h)
    const int vcol = (quarter << 4) + (wl << 2) + vl;   // this row's v-column
    const size_t cb = ((size_t)(ch >> 5) * 1024 * 2048) + ((size_t)(ch & 31) << 6);

    // state: Lj = S[4kq+j][vcol]
    const float* s0 = S0 + ((size_t)ch << 12);
    float L0 = s0[((kq << 2) + 0) * 64 + vcol];
    float L1 = s0[((kq << 2) + 1) * 64 + vcol];
    float L2 = s0[((kq << 2) + 2) * 64 + vcol];
    float L3 = s0[((kq << 2) + 3) * 64 + vcol];

    const int trow = (wl << 2) + vl;   // 0..15; rows trow and trow+16 staged

#define STG(B, T0)                                                             \
    {                                                                          \
        const size_t g0 = cb + (size_t)((T0) + trow) * 2048 + (kq << 2);       \
        const size_t g1 = cb + (size_t)((T0) + 16 + trow) * 2048 + (kq << 2);  \
        float* lb = &cbuf[B][0][0][0] + (wl << 8);                             \
        gload_lds16(DECp + g0, lb);                                            \
        gload_lds16(DECp + g1, lb + 1024);                                     \
        gload_lds16(PABp + g0, lb + 2048);                                     \
        gload_lds16(PABp + g1, lb + 3072);                                     \
        gload_lds16(PKRp + g0, lb + 4096);                                     \
        gload_lds16(PKRp + g1, lb + 5120);                                     \
        gload_lds16(VVp + g0, lb + 6144);                                      \
        gload_lds16(VVp + g1, lb + 7168);                                      \
    }

    // LDS byte address of cbuf base (generic->LDS offset: aperture 4GB-aligned)
    const u32 base0 = (u32)(size_t)(void*)&cbuf[0][0][0][0];
    const u32 aA0 = base0 + (kq << 4);             // coefficient chunk for lane
    const u32 aV0 = base0 + 24576 + (vcol << 2);   // V broadcast slot

    float4 cDa0, cDa1, cDb0, cDb1;
    uint4 cPAa0, cPAa1, cPAb0, cPAb1, cPKa0, cPKa1, cPKb0, cPKb1;
    float cV[32];

// homogeneous b128 group load (6 ops); G literal -> template offsets
#define LD2(S_, G)                                                             \
    cD##S_##0 = ds_read128<(G) * 512>(aAb);                                    \
    cD##S_##1 = ds_read128<(G) * 512 + 256>(aAb);                              \
    cPA##S_##0 = ds_read128u<8192 + (G) * 512>(aAb);                           \
    cPA##S_##1 = ds_read128u<8192 + (G) * 512 + 256>(aAb);                     \
    cPK##S_##0 = ds_read128u<16384 + (G) * 512>(aAb);                          \
    cPK##S_##1 = ds_read128u<16384 + (G) * 512 + 256>(aAb);

#define VRD(J) cV[J] = ds_read32<(J) * 256>(aVb);
#define VRD8(J) VRD(J) VRD((J)+1) VRD((J)+2) VRD((J)+3) VRD((J)+4) VRD((J)+5) VRD((J)+6) VRD((J)+7)

#define WAIT6 asm volatile("s_waitcnt lgkmcnt(6)" ::: "memory");               \
    __builtin_amdgcn_sched_barrier(0);
#define WAIT0 asm volatile("s_waitcnt lgkmcnt(0)" ::: "memory");               \
    __builtin_amdgcn_sched_barrier(0);

#define UNP_LO(u) __uint_as_float((u) << 16)
#define UNP_HI(u) __uint_as_float((u) & 0xffff0000u)

#define STEP1(D4, pa, pk, Vsj, T)                                              \
    {                                                                          \
        const float Ax = UNP_LO(pa.x), Ay = UNP_LO(pa.y),                      \
                    Az = UNP_LO(pa.z), Aw = UNP_LO(pa.w);                      \
        const float Bx = UNP_HI(pa.x), By = UNP_HI(pa.y),                      \
                    Bz = UNP_HI(pa.z), Bw = UNP_HI(pa.w);                      \
        const float Kx = UNP_LO(pk.x), Ky = UNP_LO(pk.y),                      \
                    Kz = UNP_LO(pk.z), Kw = UNP_LO(pk.w);                      \
        const float Rx = UNP_HI(pk.x), Ry = UNP_HI(pk.y),                      \
                    Rz = UNP_HI(pk.z), Rw = UNP_HI(pk.w);                      \
        float sp = fmaf(L1, Ay, L0 * Ax) + fmaf(L3, Aw, L2 * Az);              \
        const float sa = rowsum16(sp);                                         \
        L0 = fmaf(Bx, sa, fmaf(Kx, Vsj, L0 * D4.x));                           \
        L1 = fmaf(By, sa, fmaf(Ky, Vsj, L1 * D4.y));                           \
        L2 = fmaf(Bz, sa, fmaf(Kz, Vsj, L2 * D4.z));                           \
        L3 = fmaf(Bw, sa, fmaf(Kw, Vsj, L3 * D4.w));                           \
        float op = fmaf(L1, Ry, L0 * Rx) + fmaf(L3, Rw, L2 * Rz);              \
        const float o = rowsum16(op);                                          \
        if (kq == 0) OO[cb + ((size_t)(T) << 11) + vcol] = o;                  \
    }

#define STEP2(S_, G)                                                           \
    STEP1(cD##S_##0, cPA##S_##0, cPK##S_##0, cV[2 * (G)], tbase + 2 * (G));    \
    STEP1(cD##S_##1, cPA##S_##1, cPK##S_##1, cV[2 * (G) + 1], tbase + 2 * (G) + 1);

#define PAIR(G)                                                                \
    LD2(b, (G) + 1) WAIT6 STEP2(a, G) LD2(a, (G) + 2) WAIT6 STEP2(b, (G) + 1)

    STG(0, 0);
    __syncthreads();

    for (int c = 0; c < 32; ++c) {
        const int b = c & 1;
        if (c < 31) STG(b ^ 1, (c + 1) << 5);      // async prefetch next chunk (vmcnt)
        const u32 aAb = aA0 + b * 32768;
        const u32 aVb = aV0 + b * 32768;
        const int tbase = c << 5;
        VRD8(0) VRD8(8) VRD8(16) VRD8(24)          // all 32 V values (b32 burst)
        WAIT0                                      // V in regs; lgkm queue empty
        LD2(a, 0)
        PAIR(0) PAIR(2) PAIR(4) PAIR(6) PAIR(8) PAIR(10) PAIR(12)
        LD2(b, 15) WAIT6 STEP2(a, 14) WAIT0 STEP2(b, 15)
        __syncthreads();   // drains staging vmcnt (1/32 steps); flips buffers
    }
#undef PAIR
#undef STEP2
#undef STEP1
#undef UNP_LO
#undef UNP_HI
#undef WAIT0
#undef WAIT6
#undef VRD8
#undef VRD
#undef LD2
#undef STG
}

// ---------- bonus + gate -> bf16 ----------
__global__ __launch_bounds__(256) void k_gate(
    const float* __restrict__ OOp, const float* __restrict__ RRp,
    const float* __restrict__ KRp, const float* __restrict__ VVp,
    const float* __restrict__ Y2, const float* __restrict__ r_k,
    u16* __restrict__ XG) {
    const int t = blockIdx.x, tid = threadIdx.x;
    const int ww = tid >> 6, lane = tid & 63;
    const size_t tb = (size_t)t << 11;
#pragma unroll
    for (int i = 0; i < 8; ++i) {
        int c = (ww * 8 + i) * 64 + lane;
        float pr = RRp[tb + c] * KRp[tb + c] * r_k[c];
        float dot = wsum(pr);
        float xx = OOp[tb + c] * 0.125f + dot * VVp[tb + c];
        float g = Y2[(size_t)t * N2 + 4096 + c];
        XG[tb + c] = f2bf(xx * g);
    }
}

// ---------- final residual + rmsnorm ----------
__global__ __launch_bounds__(256) void k_final(const float* __restrict__ x_in,
                                               const float* __restrict__ OUTR,
                                               const float* __restrict__ ln2,
                                               float* __restrict__ out) {
    const int t = blockIdx.x, tid = threadIdx.x;
    const float* xr = x_in + ((size_t)t << 11);
    const float* orow = OUTR + ((size_t)t << 11);
    float4 a0 = *(const float4*)(xr + tid * 8);
    float4 a1 = *(const float4*)(xr + tid * 8 + 4);
    float4 b0 = *(const float4*)(orow + tid * 8);
    float4 b1 = *(const float4*)(orow + tid * 8 + 4);
    float v[8] = {a0.x + b0.x, a0.y + b0.y, a0.z + b0.z, a0.w + b0.w,
                  a1.x + b1.x, a1.y + b1.y, a1.z + b1.z, a1.w + b1.w};
    float ss = 0.f;
#pragma unroll
    for (int i = 0; i < 8; ++i) ss = fmaf(v[i], v[i], ss);
    ss = wsum(ss);
    __shared__ float red[4];
    if ((tid & 63) == 0) red[tid >> 6] = ss;
    __syncthreads();
    float scale = rsqrtf((red[0] + red[1] + red[2] + red[3]) * (1.f / 2048.f) + 1e-6f);
    float* o = out + ((size_t)t << 11) + tid * 8;
#pragma unroll
    for (int i = 0; i < 8; ++i) o[i] = ln2[tid * 8 + i] * v[i] * scale;
}

extern "C" void kernel_launch(void* const* d_in, const int* in_sizes, int n_in,
                              void* d_out, int out_size, void* d_ws, size_t ws_size,
                              hipStream_t stream) {
    const float* x_in    = (const float*)d_in[0];
    const float* v_first = (const float*)d_in[1];
    const float* k_first = (const float*)d_in[2];
    const float* state   = (const float*)d_in[3];
    const float* cosb    = (const float*)d_in[4];
    const float* sinb    = (const float*)d_in[5];
    const float* wavgk1  = (const float*)d_in[6];
    const float* w0      = (const float*)d_in[7];
    const float* w2      = (const float*)d_in[8];
    const float* a0      = (const float*)d_in[9];
    const float* a2      = (const float*)d_in[10];
    const float* v0      = (const float*)d_in[11];
    const float* v2      = (const float*)d_in[12];
    const float* g2      = (const float*)d_in[13];
    const float* k0      = (const float*)d_in[14];
    const float* k2      = (const float*)d_in[15];
    const float* r_k     = (const float*)d_in[16];
    const float* RKV     = (const float*)d_in[17];
    const float* O       = (const float*)d_in[18];
    const float* R_bias  = (const float*)d_in[19];
    const float* K_bias  = (const float*)d_in[20];
    const float* V_bias  = (const float*)d_in[21];
    const float* ln_r    = (const float*)d_in[22];
    const float* ln_k    = (const float*)d_in[23];
    const float* ln1     = (const float*)d_in[24];
    const float* ln2     = (const float*)d_in[25];

    if (ws_size < WS_NEED) return;  // need 235.5 MB (fits 256 MiB)

    char* ws = (char*)d_ws;
    u16*   BT1  = (u16*)(ws + OFF_BT1);
    u16*   W2T  = (u16*)(ws + OFF_W2T);
    u16*   OT   = (u16*)(ws + OFF_OT);
    u16*   XB   = (u16*)(ws + OFF_XB);
    float* Y1   = (float*)(ws + OFF_Y1);
    u16*   X2   = (u16*)(ws + OFF_X2);
    float* Y2   = (float*)(ws + OFF_Y2);
    float* RR   = (float*)(ws + OFF_RR);
    float* DEC  = (float*)(ws + OFF_DEC);
    float* KR   = (float*)(ws + OFF_KR);
    float* VV   = (float*)(ws + OFF_VV);
    u32*   PAB  = (u32*)(ws + OFF_PAB);
    u32*   PKR  = (u32*)(ws + OFF_PKR);
    float* OO   = (float*)(ws + OFF_OO);
    u16*   XG   = (u16*)(ws + OFF_XG);
    float* OUTR = (float*)(ws + OFF_OUTR);

    // P0: BT1 + XB (region C)
    k_prep_bt1<<<1856, 256, 0, stream>>>(wavgk1, RKV, BT1);
    k_rms1<<<2048, 256, 0, stream>>>(x_in, ln1, XB);
    // P1: GEMM1 -> Y1  (region A)
    k_gemm<<<dim3(16, 29), 256, 0, stream>>>(XB, BT1, Y1, 2048, N1, 2048);
    // P2: W2T + X2 overwrite BT1/XB (dead); GEMM2 (block-diagonal) -> Y2 (region B)
    k_prep_w2t<<<1008, 256, 0, stream>>>(w2, a2, g2, v2, k2, W2T);
    k_prep_x2<<<4608, 256, 0, stream>>>(Y1, X2);
    k_gemm2<<<dim3(16, 56), 256, 0, stream>>>(X2, W2T, Y2);
    // P3: recurrence operands (region D); Y1 dead after this
    k_prep_rec<<<2048, 256, 0, stream>>>(Y1, Y2, v_first, k_first, cosb, sinb,
                                         w0, a0, v0, k0, R_bias, K_bias, V_bias,
                                         ln_r, ln_k, RR, DEC, KR, VV, PAB, PKR);
    // P4: OT overwrites W2T/X2 (dead); recurrence -> OO (in old Y1 space)
    k_prep_ot<<<1024, 256, 0, stream>>>(O, OT);
    k_recv16<<<256, 256, 0, stream>>>(DEC, PAB, PKR, VV, state, OO);
    // P5: gate -> XG (in old Y1 space); Y2 dead after this
    k_gate<<<2048, 256, 0, stream>>>(OO, RR, KR, VV, Y2, r_k, XG);
    // P6: GEMM3 -> OUTR (in old Y2 space); final norm
    k_gemm<<<dim3(16, 16), 256, 0, stream>>>(XG, OT, OUTR, 2048, 2048, 2048);
    k_final<<<2048, 256, 0, stream>>>(x_in, OUTR, ln2, (float*)d_out);
}

// Round 25
// 376.619 us; speedup vs baseline: 1.1066x; 1.0008x over previous
//
#include <hip/hip_runtime.h>

typedef unsigned short u16;
typedef unsigned int u32;

using f32x4 = __attribute__((ext_vector_type(4))) float;
using bf16x8 = __attribute__((ext_vector_type(8))) __bf16;

// ---------- constants ----------
#define HN 2048
#define KVD 512
#define TOKENS 2048          // B*T
#define N1 3712              // GEMM1 N (3648 padded to 29*128)
#define K2W 576              // GEMM2 K
#define N2 7168              // GEMM2 N: w(2048) a(2048) g(2048) v(512) k(512)

// ---------- workspace layout (bytes) — lifetime-aliased, peak 235.5 MB ----------
#define OFF_Y1   0ull
#define OFF_OO   0ull
#define OFF_XG   16777216ull
#define OFF_Y2   30408704ull
#define OFF_OUTR 30408704ull
#define OFF_BT1  89128960ull
#define OFF_XB   104333312ull
#define OFF_W2T  89128960ull
#define OFF_X2   97386496ull
#define OFF_OT   89128960ull
#define OFF_RR   112721920ull
#define OFF_DEC  129499136ull
#define OFF_KR   146276352ull
#define OFF_VV   163053568ull
#define OFF_AA   179830784ull
#define OFF_BB   196608000ull
#define OFF_PAB  213385216ull            // u32 [2048][2048]: bf16(A) | bf16(B)<<16
#define OFF_PKR  230162432ull            // u32 [2048][2048]: bf16(K) | bf16(R)<<16
#define WS_NEED  246939648ull

// ---------- helpers ----------
__device__ __forceinline__ u16 f2bf(float f) {
    u32 u = __float_as_uint(f);
    u32 r = u + 0x7fffu + ((u >> 16) & 1u);
    return (u16)(r >> 16);
}
__device__ __forceinline__ float sigm(float x) { return 1.f / (1.f + expf(-x)); }
__device__ __forceinline__ float wsum(float v) {
#pragma unroll
    for (int m = 32; m > 0; m >>= 1) v += __shfl_xor(v, m, 64);
    return v;
}
// sum across each 16-lane DPP row via row_ror 1,2,4,8; result in all lanes of the row
__device__ __forceinline__ float rowsum16(float v) {
    float t;
    t = __uint_as_float(__builtin_amdgcn_update_dpp(0, __float_as_uint(v), 0x121, 0xf, 0xf, true));
    v += t;
    t = __uint_as_float(__builtin_amdgcn_update_dpp(0, __float_as_uint(v), 0x122, 0xf, 0xf, true));
    v += t;
    t = __uint_as_float(__builtin_amdgcn_update_dpp(0, __float_as_uint(v), 0x124, 0xf, 0xf, true));
    v += t;
    t = __uint_as_float(__builtin_amdgcn_update_dpp(0, __float_as_uint(v), 0x128, 0xf, 0xf, true));
    v += t;
    return v;
}

typedef __attribute__((address_space(1))) const void glob_t;
typedef __attribute__((address_space(3))) void lds_t;
__device__ __forceinline__ void gload_lds16(const void* g, void* l) {
    __builtin_amdgcn_global_load_lds((glob_t*)g, (lds_t*)l, 16, 0, 0);
}

// inline-asm LDS readers with literal offset (burst-issued, order preserved)
template<int OFF>
__device__ __forceinline__ float4 ds_read128(u32 a) {
    float4 r;
    asm volatile("ds_read_b128 %0, %1 offset:%2" : "=v"(r) : "v"(a), "i"(OFF));
    return r;
}
template<int OFF>
__device__ __forceinline__ uint4 ds_read128u(u32 a) {
    uint4 r;
    asm volatile("ds_read_b128 %0, %1 offset:%2" : "=v"(r) : "v"(a), "i"(OFF));
    return r;
}
template<int OFF>
__device__ __forceinline__ float ds_read32(u32 a) {
    float r;
    asm volatile("ds_read_b32 %0, %1 offset:%2" : "=v"(r) : "v"(a), "i"(OFF));
    return r;
}

// ---------- weight prep: tiled transposes (coalesced read AND write) ----------
__global__ __launch_bounds__(256) void k_prep_bt1(const float* __restrict__ wavgk1,
                                                  const float* __restrict__ RKV,
                                                  u16* __restrict__ BT1) {
    __shared__ float tile[64][65];
    const int bn = blockIdx.x >> 5;        // 0..57
    const int bk = blockIdx.x & 31;        // 0..31
    const int n0 = bn << 6, k0 = bk << 6;
    const int c = threadIdx.x & 63, q = threadIdx.x >> 6;
#pragma unroll
    for (int i = 0; i < 16; ++i) {
        const int r = (q << 4) + i;
        float v = 0.f;
        if (bn < 9)       v = wavgk1[(size_t)(k0 + r) * 576 + n0 + c];
        else if (bn < 57) v = RKV[(size_t)(k0 + r) * 3072 + (n0 + c - 576)];
        tile[r][c] = v;
    }
    __syncthreads();
#pragma unroll
    for (int i = 0; i < 16; ++i) {
        const int rw = (q << 4) + i;
        BT1[(size_t)(n0 + rw) * 2048 + k0 + c] = f2bf(tile[c][rw]);
    }
}

// W2T[n][c] = blockdiag src[c][n]; 64x64 tiles, both sides coalesced.
__global__ __launch_bounds__(256) void k_prep_w2t(const float* __restrict__ w2, const float* __restrict__ a2,
                                                  const float* __restrict__ g2, const float* __restrict__ v2,
                                                  const float* __restrict__ k2, u16* __restrict__ W2T) {
    __shared__ float tile[64][65];
    const int bx = blockIdx.x;
    const int bn = bx / 9, bc = bx - bn * 9;
    const int n0 = bn << 6, c0 = bc << 6;
    const int cc = threadIdx.x & 63, q = threadIdx.x >> 6;
#pragma unroll
    for (int i = 0; i < 16; ++i) {
        const int r = (q << 4) + i;        // c-offset within tile
        const int c = c0 + r;
        const int n = n0 + cc;
        float v = 0.f;
        if (n0 < 2048)      { if (c < 96)              v = w2[(size_t)c * 2048 + n]; }
        else if (n0 < 4096) { if (c >= 96 && c < 192)  v = a2[(size_t)(c - 96) * 2048 + (n - 2048)]; }
        else if (n0 < 6144) { if (c >= 192 && c < 448) v = g2[(size_t)(c - 192) * 2048 + (n - 4096)]; }
        else if (n0 < 6656) { if (c >= 448 && c < 512) v = v2[(size_t)(c - 448) * 512 + (n - 6144)]; }
        else                { if (c >= 512)            v = k2[(size_t)(c - 512) * 512 + (n - 6656)]; }
        tile[r][cc] = v;
    }
    __syncthreads();
#pragma unroll
    for (int i = 0; i < 16; ++i) {
        const int rw = (q << 4) + i;       // n-offset within tile
        W2T[(size_t)(n0 + rw) * 576 + c0 + cc] = f2bf(tile[cc][rw]);
    }
}

// OT[n][k] = O[k][n], 2048x2048, 64x64 tiles
__global__ __launch_bounds__(256) void k_prep_ot(const float* __restrict__ O, u16* __restrict__ OT) {
    __shared__ float tile[64][65];
    const int bn = blockIdx.x >> 5, bk = blockIdx.x & 31;
    const int n0 = bn << 6, k0 = bk << 6;
    const int c = threadIdx.x & 63, q = threadIdx.x >> 6;
#pragma unroll
    for (int i = 0; i < 16; ++i) {
        const int r = (q << 4) + i;
        tile[r][c] = O[(size_t)(k0 + r) * 2048 + n0 + c];
    }
    __syncthreads();
#pragma unroll
    for (int i = 0; i < 16; ++i) {
        const int rw = (q << 4) + i;
        OT[(size_t)(n0 + rw) * 2048 + k0 + c] = f2bf(tile[c][rw]);
    }
}

// ---------- rmsnorm(x_in, ln1) -> bf16 ----------
__global__ __launch_bounds__(256) void k_rms1(const float* __restrict__ X,
                                              const float* __restrict__ ln1,
                                              u16* __restrict__ XB) {
    const int t = blockIdx.x, tid = threadIdx.x;
    const float* row = X + ((size_t)t << 11);
    float4 v0 = *(const float4*)(row + tid * 8);
    float4 v1 = *(const float4*)(row + tid * 8 + 4);
    float ss = v0.x*v0.x + v0.y*v0.y + v0.z*v0.z + v0.w*v0.w
             + v1.x*v1.x + v1.y*v1.y + v1.z*v1.z + v1.w*v1.w;
    ss = wsum(ss);
    __shared__ float red[4];
    if ((tid & 63) == 0) red[tid >> 6] = ss;
    __syncthreads();
    float scale = rsqrtf((red[0] + red[1] + red[2] + red[3]) * (1.f / 2048.f) + 1e-6f);
    float4 w0_ = *(const float4*)(ln1 + tid * 8);
    float4 w1_ = *(const float4*)(ln1 + tid * 8 + 4);
    u16* o = XB + ((size_t)t << 11) + tid * 8;
    o[0] = f2bf(v0.x * scale * w0_.x); o[1] = f2bf(v0.y * scale * w0_.y);
    o[2] = f2bf(v0.z * scale * w0_.z); o[3] = f2bf(v0.w * scale * w0_.w);
    o[4] = f2bf(v1.x * scale * w1_.x); o[5] = f2bf(v1.y * scale * w1_.y);
    o[6] = f2bf(v1.z * scale * w1_.z); o[7] = f2bf(v1.w * scale * w1_.w);
}

// ---------- generic bf16 MFMA GEMM with LDS chunk swizzle ----------
__global__ __launch_bounds__(256) void k_gemm(const u16* __restrict__ A,
                                              const u16* __restrict__ Bt,
                                              float* __restrict__ C,
                                              int M, int N, int K) {
    __shared__ __align__(16) u16 tA[4096];  // [128 rows][32 k]
    __shared__ __align__(16) u16 tB[4096];
    const int tid = threadIdx.x;
    const int w = tid >> 6, l = tid & 63;
    const int bm = blockIdx.x << 7, bn = blockIdx.y << 7;
    const int wm = (w >> 1) << 6, wn = (w & 1) << 6;
    const int lrow = l >> 2;        // 0..15 (staged row within 16-row group)
    const int lk = (((l & 3) ^ ((l >> 3) & 3)) << 3);   // pre-swizzled global chunk
    f32x4 acc[4][4] = {};
    const size_t rA0 = (size_t)(bm + (w << 4) + lrow) * K;
    const size_t rA1 = (size_t)(bm + ((w + 4) << 4) + lrow) * K;
    const size_t rB0 = (size_t)(bn + (w << 4) + lrow) * K;
    const size_t rB1 = (size_t)(bn + ((w + 4) << 4) + lrow) * K;
    const int frow = l & 15;
    const int koff = (((l >> 4) ^ ((l >> 1) & 3)) << 3);  // swizzled read chunk
    for (int kt = 0; kt < K; kt += 32) {
        gload_lds16(A + rA0 + kt + lk, &tA[w << 9]);
        gload_lds16(A + rA1 + kt + lk, &tA[2048 + (w << 9)]);
        gload_lds16(Bt + rB0 + kt + lk, &tB[w << 9]);
        gload_lds16(Bt + rB1 + kt + lk, &tB[2048 + (w << 9)]);
        __syncthreads();
        bf16x8 av[4], bv[4];
#pragma unroll
        for (int i = 0; i < 4; ++i) {
            av[i] = *(const bf16x8*)&tA[((wm + (i << 4) + frow) << 5) + koff];
            bv[i] = *(const bf16x8*)&tB[((wn + (i << 4) + frow) << 5) + koff];
        }
#pragma unroll
        for (int i = 0; i < 4; ++i)
#pragma unroll
            for (int j = 0; j < 4; ++j)
                acc[i][j] = __builtin_amdgcn_mfma_f32_16x16x32_bf16(av[i], bv[j], acc[i][j], 0, 0, 0);
        __syncthreads();
    }
    const int crow = bm + wm + ((l >> 4) << 2);
    const int ccol = bn + wn + (l & 15);
#pragma unroll
    for (int i = 0; i < 4; ++i)
#pragma unroll
        for (int j = 0; j < 4; ++j)
#pragma unroll
            for (int jj = 0; jj < 4; ++jj)
                C[(size_t)(crow + (i << 4) + jj) * N + ccol + (j << 4)] = acc[i][j][jj];
}

// ---------- GEMM2 specialization: block-diagonal W2T, per-segment true K ----------
__global__ __launch_bounds__(256) void k_gemm2(const u16* __restrict__ A,
                                               const u16* __restrict__ Bt,
                                               float* __restrict__ C) {
    __shared__ __align__(16) u16 tA[4096];
    __shared__ __align__(16) u16 tB[4096];
    const int tid = threadIdx.x;
    const int w = tid >> 6, l = tid & 63;
    const int by = blockIdx.y;
    int c0, K;
    if (by < 16)      { c0 = 0;   K = 96; }
    else if (by < 32) { c0 = 96;  K = 96; }
    else if (by < 48) { c0 = 192; K = 256; }
    else if (by < 52) { c0 = 448; K = 64; }
    else              { c0 = 512; K = 64; }
    const int n0 = by << 7;
    const int bm = blockIdx.x << 7;
    const int wm = (w >> 1) << 6, wn = (w & 1) << 6;
    const int lrow = l >> 2;
    const int lk = (((l & 3) ^ ((l >> 3) & 3)) << 3);
    f32x4 acc[4][4] = {};
    const size_t rA0 = (size_t)(bm + (w << 4) + lrow) * 576 + c0;
    const size_t rA1 = (size_t)(bm + ((w + 4) << 4) + lrow) * 576 + c0;
    const size_t rB0 = (size_t)(n0 + (w << 4) + lrow) * 576 + c0;
    const size_t rB1 = (size_t)(n0 + ((w + 4) << 4) + lrow) * 576 + c0;
    const int frow = l & 15;
    const int koff = (((l >> 4) ^ ((l >> 1) & 3)) << 3);
    for (int kt = 0; kt < K; kt += 32) {
        gload_lds16(A + rA0 + kt + lk, &tA[w << 9]);
        gload_lds16(A + rA1 + kt + lk, &tA[2048 + (w << 9)]);
        gload_lds16(Bt + rB0 + kt + lk, &tB[w << 9]);
        gload_lds16(Bt + rB1 + kt + lk, &tB[2048 + (w << 9)]);
        __syncthreads();
        bf16x8 av[4], bv[4];
#pragma unroll
        for (int i = 0; i < 4; ++i) {
            av[i] = *(const bf16x8*)&tA[((wm + (i << 4) + frow) << 5) + koff];
            bv[i] = *(const bf16x8*)&tB[((wn + (i << 4) + frow) << 5) + koff];
        }
#pragma unroll
        for (int i = 0; i < 4; ++i)
#pragma unroll
            for (int j = 0; j < 4; ++j)
                acc[i][j] = __builtin_amdgcn_mfma_f32_16x16x32_bf16(av[i], bv[j], acc[i][j], 0, 0, 0);
        __syncthreads();
    }
    const int crow = bm + wm + ((l >> 4) << 2);
    const int ccol = n0 + wn + (l & 15);
#pragma unroll
    for (int i = 0; i < 4; ++i)
#pragma unroll
        for (int j = 0; j < 4; ++j)
#pragma unroll
            for (int jj = 0; jj < 4; ++jj)
                C[(size_t)(crow + (i << 4) + jj) * N2 + ccol + (j << 4)] = acc[i][j][jj];
}

// ---------- Y1 -> X2 (bf16): [tanh(xw) | xa | sigmoid(xg) | xv | xk] ----------
__global__ __launch_bounds__(256) void k_prep_x2(const float* __restrict__ Y1, u16* __restrict__ X2) {
    int idx = blockIdx.x * 256 + threadIdx.x;   // t*576 + c
    int t = idx / 576, c = idx - t * 576;
    const float* y1 = Y1 + (size_t)t * N1;
    float v;
    if (c < 96)       v = tanhf(y1[c]);
    else if (c < 192) v = y1[c];
    else if (c < 448) v = sigm(y1[c + 64]);
    else if (c < 512) v = y1[c - 256];
    else              v = y1[c];
    X2[idx] = f2bf(v);
}

// ---------- per-token recurrence prep (+ packed bf16 coefficient pairs) ----------
__global__ __launch_bounds__(256) void k_prep_rec(
    const float* __restrict__ Y1, const float* __restrict__ Y2,
    const float* __restrict__ v_first, const float* __restrict__ k_first,
    const float* __restrict__ cosb, const float* __restrict__ sinb,
    const float* __restrict__ w0, const float* __restrict__ a0,
    const float* __restrict__ v0b, const float* __restrict__ k0b,
    const float* __restrict__ R_bias, const float* __restrict__ K_bias,
    const float* __restrict__ V_bias, const float* __restrict__ ln_r,
    const float* __restrict__ ln_k,
    float* __restrict__ RR, float* __restrict__ DEC, float* __restrict__ KR,
    float* __restrict__ VV, u32* __restrict__ PAB, u32* __restrict__ PKR) {
    const int t = blockIdx.x, tid = threadIdx.x;
    const int ww = tid >> 6, lane = tid & 63;
    const float* y1 = Y1 + (size_t)t * N1;
    const float* y2 = Y2 + (size_t)t * N2;
    const float cs = cosb[t * 64 + lane];
    const float sn = sinb[t * 64 + lane];
    const float sign = lane < 32 ? -1.f : 1.f;
    const size_t tb = (size_t)t << 11;
    __shared__ float kkv[512], vkv[512];
    float rsave[8];
    // r: per-head rmsnorm + rope
#pragma unroll
    for (int i = 0; i < 8; ++i) {
        int h = ww * 8 + i, c = h * 64 + lane;
        float rr = y1[576 + c] + R_bias[c];
        float ssq = wsum(rr * rr);
        float rn = ln_r[lane] * rr * rsqrtf(ssq * (1.f / 64.f) + 1e-6f);
        float rot = sign * __shfl(rn, lane ^ 32, 64);
        rsave[i] = rn * cs + rot * sn;
        RR[tb + c] = rsave[i];
    }
    // k,v kv-heads: rmsnorm+rope+mix
#pragma unroll
    for (int i = 0; i < 2; ++i) {
        int j = ww * 2 + i, c = j * 64 + lane;
        float kr = y1[2624 + c] + K_bias[c];
        float ssq = wsum(kr * kr);
        float kn = ln_k[lane] * kr * rsqrtf(ssq * (1.f / 64.f) + 1e-6f);
        float rot = sign * __shfl(kn, lane ^ 32, 64);
        float krope = kn * cs + rot * sn;
        float ksig = sigm(y2[6656 + c] + k0b[c]);
        kkv[c] = krope + (k_first[(size_t)t * 512 + c] - krope) * ksig;
        float vr = y1[3136 + c] + V_bias[c];
        float vsig = sigm(y2[6144 + c] + v0b[c]);
        vkv[c] = vr + (v_first[(size_t)t * 512 + c] - vr) * vsig;
    }
    __syncthreads();
    // per-head final recurrence operands
#pragma unroll
    for (int i = 0; i < 8; ++i) {
        int h = ww * 8 + i, c = h * 64 + lane;
        int ckv = (h >> 2) * 64 + lane;
        float kb = kkv[ckv], vb = vkv[ckv];
        float a_ = sigm(y2[2048 + c] + a0[c]);
        float wr = y2[c] + w0[c];
        float z = -wr;
        float sp = fmaxf(z, 0.f) + log1pf(expf(-fabsf(z)));
        float w_log = -sp - 0.5f;
        float ssq = wsum(kb * kb);
        float kk = kb / fmaxf(sqrtf(ssq), 1e-12f);
        const float kr2 = kb * (1.f - w_log + a_);
        DEC[tb + c] = expf(-expf(w_log));
        KR[tb + c] = kr2;
        VV[tb + c] = vb;
        PAB[tb + c] = (u32)f2bf(-kk) | ((u32)f2bf(kk * a_) << 16);
        PKR[tb + c] = (u32)f2bf(kr2) | ((u32)f2bf(rsave[i]) << 16);
    }
}

// ---------- sequential recurrence: homogeneous-b128, 3 groups in flight ----------
// r24 (2 groups, lgkmcnt(6)) passed but waits still exposed ~100 cyc (DS latency
// > one compute phase). 3 sets a/b/c rotating, 18 b128 outstanding, wait at
// lgkmcnt(12) -> each group has TWO compute phases (~160 cyc) to land. V b32
// reads hoisted per chunk (homogeneous-width queue only; r23's mixed-width race).
__global__ __launch_bounds__(256, 1) void k_recv17(
    const float* __restrict__ DECp, const u32* __restrict__ PABp,
    const u32* __restrict__ PKRp, const float* __restrict__ VVp,
    const float* __restrict__ S0, float* __restrict__ OO) {
    __shared__ __align__(16) float cbuf[2][4][32][64];   // 64 KB
    const int tid = threadIdx.x;
    const int wl = tid >> 6;           // wave 0..3
    const int lane = tid & 63;
    const int vl = lane >> 4;          // DPP row 0..3
    const int kq = lane & 15;          // k-quad 0..15
    const int quarter = blockIdx.x & 3;
    const int ch = blockIdx.x >> 2;          // chain 0..63 (b*32+h)
    const int vcol = (quarter << 4) + (wl << 2) + vl;   // this row's v-column
    const size_t cb = ((size_t)(ch >> 5) * 1024 * 2048) + ((size_t)(ch & 31) << 6);

    // state: Lj = S[4kq+j][vcol]
    const float* s0 = S0 + ((size_t)ch << 12);
    float L0 = s0[((kq << 2) + 0) * 64 + vcol];
    float L1 = s0[((kq << 2) + 1) * 64 + vcol];
    float L2 = s0[((kq << 2) + 2) * 64 + vcol];
    float L3 = s0[((kq << 2) + 3) * 64 + vcol];

    const int trow = (wl << 2) + vl;   // 0..15; rows trow and trow+16 staged

#define STG(B, T0)                                                             \
    {                                                                          \
        const size_t g0 = cb + (size_t)((T0) + trow) * 2048 + (kq << 2);       \
        const size_t g1 = cb + (size_t)((T0) + 16 + trow) * 2048 + (kq << 2);  \
        float* lb = &cbuf[B][0][0][0] + (wl << 8);                             \
        gload_lds16(DECp + g0, lb);                                            \
        gload_lds16(DECp + g1, lb + 1024);                                     \
        gload_lds16(PABp + g0, lb + 2048);                                     \
        gload_lds16(PABp + g1, lb + 3072);                                     \
        gload_lds16(PKRp + g0, lb + 4096);                                     \
        gload_lds16(PKRp + g1, lb + 5120);                                     \
        gload_lds16(VVp + g0, lb + 6144);                                      \
        gload_lds16(VVp + g1, lb + 7168);                                      \
    }

    // LDS byte address of cbuf base (generic->LDS offset: aperture 4GB-aligned)
    const u32 base0 = (u32)(size_t)(void*)&cbuf[0][0][0][0];
    const u32 aA0 = base0 + (kq << 4);             // coefficient chunk for lane
    const u32 aV0 = base0 + 24576 + (vcol << 2);   // V broadcast slot

    float4 cDa0, cDa1, cDb0, cDb1, cDc0, cDc1;
    uint4 cPAa0, cPAa1, cPAb0, cPAb1, cPAc0, cPAc1;
    uint4 cPKa0, cPKa1, cPKb0, cPKb1, cPKc0, cPKc1;
    float cV[32];

// homogeneous b128 group load (6 ops); G literal -> template offsets
#define LD2(S_, G)                                                             \
    cD##S_##0 = ds_read128<(G) * 512>(aAb);                                    \
    cD##S_##1 = ds_read128<(G) * 512 + 256>(aAb);                              \
    cPA##S_##0 = ds_read128u<8192 + (G) * 512>(aAb);                           \
    cPA##S_##1 = ds_read128u<8192 + (G) * 512 + 256>(aAb);                     \
    cPK##S_##0 = ds_read128u<16384 + (G) * 512>(aAb);                          \
    cPK##S_##1 = ds_read128u<16384 + (G) * 512 + 256>(aAb);

#define VRD(J) cV[J] = ds_read32<(J) * 256>(aVb);
#define VRD8(J) VRD(J) VRD((J)+1) VRD((J)+2) VRD((J)+3) VRD((J)+4) VRD((J)+5) VRD((J)+6) VRD((J)+7)

#define WAIT12 asm volatile("s_waitcnt lgkmcnt(12)" ::: "memory");             \
    __builtin_amdgcn_sched_barrier(0);
#define WAIT6 asm volatile("s_waitcnt lgkmcnt(6)" ::: "memory");               \
    __builtin_amdgcn_sched_barrier(0);
#define WAIT0 asm volatile("s_waitcnt lgkmcnt(0)" ::: "memory");               \
    __builtin_amdgcn_sched_barrier(0);

#define UNP_LO(u) __uint_as_float((u) << 16)
#define UNP_HI(u) __uint_as_float((u) & 0xffff0000u)

#define STEP1(D4, pa, pk, Vsj, T)                                              \
    {                                                                          \
        const float Ax = UNP_LO(pa.x), Ay = UNP_LO(pa.y),                      \
                    Az = UNP_LO(pa.z), Aw = UNP_LO(pa.w);                      \
        const float Bx = UNP_HI(pa.x), By = UNP_HI(pa.y),                      \
                    Bz = UNP_HI(pa.z), Bw = UNP_HI(pa.w);                      \
        const float Kx = UNP_LO(pk.x), Ky = UNP_LO(pk.y),                      \
                    Kz = UNP_LO(pk.z), Kw = UNP_LO(pk.w);                      \
        const float Rx = UNP_HI(pk.x), Ry = UNP_HI(pk.y),                      \
                    Rz = UNP_HI(pk.z), Rw = UNP_HI(pk.w);                      \
        float sp = fmaf(L1, Ay, L0 * Ax) + fmaf(L3, Aw, L2 * Az);              \
        const float sa = rowsum16(sp);                                         \
        L0 = fmaf(Bx, sa, fmaf(Kx, Vsj, L0 * D4.x));                           \
        L1 = fmaf(By, sa, fmaf(Ky, Vsj, L1 * D4.y));                           \
        L2 = fmaf(Bz, sa, fmaf(Kz, Vsj, L2 * D4.z));                           \
        L3 = fmaf(Bw, sa, fmaf(Kw, Vsj, L3 * D4.w));                           \
        float op = fmaf(L1, Ry, L0 * Rx) + fmaf(L3, Rw, L2 * Rz);              \
        const float o = rowsum16(op);                                          \
        if (kq == 0) OO[cb + ((size_t)(T) << 11) + vcol] = o;                  \
    }

#define STEP2(S_, G)                                                           \
    STEP1(cD##S_##0, cPA##S_##0, cPK##S_##0, cV[2 * (G)], tbase + 2 * (G));    \
    STEP1(cD##S_##1, cPA##S_##1, cPK##S_##1, cV[2 * (G) + 1], tbase + 2 * (G) + 1);

    STG(0, 0);
    __syncthreads();

    for (int c = 0; c < 32; ++c) {
        const int b = c & 1;
        if (c < 31) STG(b ^ 1, (c + 1) << 5);      // async prefetch next chunk (vmcnt)
        const u32 aAb = aA0 + b * 32768;
        const u32 aVb = aV0 + b * 32768;
        const int tbase = c << 5;
        VRD8(0) VRD8(8) VRD8(16) VRD8(24)          // all 32 V values (b32 burst)
        WAIT0                                      // V in regs; lgkm queue empty
        LD2(a, 0) LD2(b, 1)
        LD2(c, 2)  WAIT12 STEP2(a, 0)
        LD2(a, 3)  WAIT12 STEP2(b, 1)
        LD2(b, 4)  WAIT12 STEP2(c, 2)
        LD2(c, 5)  WAIT12 STEP2(a, 3)
        LD2(a, 6)  WAIT12 STEP2(b, 4)
        LD2(b, 7)  WAIT12 STEP2(c, 5)
        LD2(c, 8)  WAIT12 STEP2(a, 6)
        LD2(a, 9)  WAIT12 STEP2(b, 7)
        LD2(b, 10) WAIT12 STEP2(c, 8)
        LD2(c, 11) WAIT12 STEP2(a, 9)
        LD2(a, 12) WAIT12 STEP2(b, 10)
        LD2(b, 13) WAIT12 STEP2(c, 11)
        LD2(c, 14) WAIT12 STEP2(a, 12)
        LD2(a, 15) WAIT12 STEP2(b, 13)
        WAIT6 STEP2(c, 14)
        WAIT0 STEP2(a, 15)
        __syncthreads();   // drains staging vmcnt (1/32 steps); flips buffers
    }
#undef STEP2
#undef STEP1
#undef UNP_LO
#undef UNP_HI
#undef WAIT0
#undef WAIT6
#undef WAIT12
#undef VRD8
#undef VRD
#undef LD2
#undef STG
}

// ---------- bonus + gate -> bf16 ----------
__global__ __launch_bounds__(256) void k_gate(
    const float* __restrict__ OOp, const float* __restrict__ RRp,
    const float* __restrict__ KRp, const float* __restrict__ VVp,
    const float* __restrict__ Y2, const float* __restrict__ r_k,
    u16* __restrict__ XG) {
    const int t = blockIdx.x, tid = threadIdx.x;
    const int ww = tid >> 6, lane = tid & 63;
    const size_t tb = (size_t)t << 11;
#pragma unroll
    for (int i = 0; i < 8; ++i) {
        int c = (ww * 8 + i) * 64 + lane;
        float pr = RRp[tb + c] * KRp[tb + c] * r_k[c];
        float dot = wsum(pr);
        float xx = OOp[tb + c] * 0.125f + dot * VVp[tb + c];
        float g = Y2[(size_t)t * N2 + 4096 + c];
        XG[tb + c] = f2bf(xx * g);
    }
}

// ---------- final residual + rmsnorm ----------
__global__ __launch_bounds__(256) void k_final(const float* __restrict__ x_in,
                                               const float* __restrict__ OUTR,
                                               const float* __restrict__ ln2,
                                               float* __restrict__ out) {
    const int t = blockIdx.x, tid = threadIdx.x;
    const float* xr = x_in + ((size_t)t << 11);
    const float* orow = OUTR + ((size_t)t << 11);
    float4 a0 = *(const float4*)(xr + tid * 8);
    float4 a1 = *(const float4*)(xr + tid * 8 + 4);
    float4 b0 = *(const float4*)(orow + tid * 8);
    float4 b1 = *(const float4*)(orow + tid * 8 + 4);
    float v[8] = {a0.x + b0.x, a0.y + b0.y, a0.z + b0.z, a0.w + b0.w,
                  a1.x + b1.x, a1.y + b1.y, a1.z + b1.z, a1.w + b1.w};
    float ss = 0.f;
#pragma unroll
    for (int i = 0; i < 8; ++i) ss = fmaf(v[i], v[i], ss);
    ss = wsum(ss);
    __shared__ float red[4];
    if ((tid & 63) == 0) red[tid >> 6] = ss;
    __syncthreads();
    float scale = rsqrtf((red[0] + red[1] + red[2] + red[3]) * (1.f / 2048.f) + 1e-6f);
    float* o = out + ((size_t)t << 11) + tid * 8;
#pragma unroll
    for (int i = 0; i < 8; ++i) o[i] = ln2[tid * 8 + i] * v[i] * scale;
}

extern "C" void kernel_launch(void* const* d_in, const int* in_sizes, int n_in,
                              void* d_out, int out_size, void* d_ws, size_t ws_size,
                              hipStream_t stream) {
    const float* x_in    = (const float*)d_in[0];
    const float* v_first = (const float*)d_in[1];
    const float* k_first = (const float*)d_in[2];
    const float* state   = (const float*)d_in[3];
    const float* cosb    = (const float*)d_in[4];
    const float* sinb    = (const float*)d_in[5];
    const float* wavgk1  = (const float*)d_in[6];
    const float* w0      = (const float*)d_in[7];
    const float* w2      = (const float*)d_in[8];
    const float* a0      = (const float*)d_in[9];
    const float* a2      = (const float*)d_in[10];
    const float* v0      = (const float*)d_in[11];
    const float* v2      = (const float*)d_in[12];
    const float* g2      = (const float*)d_in[13];
    const float* k0      = (const float*)d_in[14];
    const float* k2      = (const float*)d_in[15];
    const float* r_k     = (const float*)d_in[16];
    const float* RKV     = (const float*)d_in[17];
    const float* O       = (const float*)d_in[18];
    const float* R_bias  = (const float*)d_in[19];
    const float* K_bias  = (const float*)d_in[20];
    const float* V_bias  = (const float*)d_in[21];
    const float* ln_r    = (const float*)d_in[22];
    const float* ln_k    = (const float*)d_in[23];
    const float* ln1     = (const float*)d_in[24];
    const float* ln2     = (const float*)d_in[25];

    if (ws_size < WS_NEED) return;  // need 235.5 MB (fits 256 MiB)

    char* ws = (char*)d_ws;
    u16*   BT1  = (u16*)(ws + OFF_BT1);
    u16*   W2T  = (u16*)(ws + OFF_W2T);
    u16*   OT   = (u16*)(ws + OFF_OT);
    u16*   XB   = (u16*)(ws + OFF_XB);
    float* Y1   = (float*)(ws + OFF_Y1);
    u16*   X2   = (u16*)(ws + OFF_X2);
    float* Y2   = (float*)(ws + OFF_Y2);
    float* RR   = (float*)(ws + OFF_RR);
    float* DEC  = (float*)(ws + OFF_DEC);
    float* KR   = (float*)(ws + OFF_KR);
    float* VV   = (float*)(ws + OFF_VV);
    u32*   PAB  = (u32*)(ws + OFF_PAB);
    u32*   PKR  = (u32*)(ws + OFF_PKR);
    float* OO   = (float*)(ws + OFF_OO);
    u16*   XG   = (u16*)(ws + OFF_XG);
    float* OUTR = (float*)(ws + OFF_OUTR);

    // P0: BT1 + XB (region C)
    k_prep_bt1<<<1856, 256, 0, stream>>>(wavgk1, RKV, BT1);
    k_rms1<<<2048, 256, 0, stream>>>(x_in, ln1, XB);
    // P1: GEMM1 -> Y1  (region A)
    k_gemm<<<dim3(16, 29), 256, 0, stream>>>(XB, BT1, Y1, 2048, N1, 2048);
    // P2: W2T + X2 overwrite BT1/XB (dead); GEMM2 (block-diagonal) -> Y2 (region B)
    k_prep_w2t<<<1008, 256, 0, stream>>>(w2, a2, g2, v2, k2, W2T);
    k_prep_x2<<<4608, 256, 0, stream>>>(Y1, X2);
    k_gemm2<<<dim3(16, 56), 256, 0, stream>>>(X2, W2T, Y2);
    // P3: recurrence operands (region D); Y1 dead after this
    k_prep_rec<<<2048, 256, 0, stream>>>(Y1, Y2, v_first, k_first, cosb, sinb,
                                         w0, a0, v0, k0, R_bias, K_bias, V_bias,
                                         ln_r, ln_k, RR, DEC, KR, VV, PAB, PKR);
    // P4: OT overwrites W2T/X2 (dead); recurrence -> OO (in old Y1 space)
    k_prep_ot<<<1024, 256, 0, stream>>>(O, OT);
    k_recv17<<<256, 256, 0, stream>>>(DEC, PAB, PKR, VV, state, OO);
    // P5: gate -> XG (in old Y1 space); Y2 dead after this
    k_gate<<<2048, 256, 0, stream>>>(OO, RR, KR, VV, Y2, r_k, XG);
    // P6: GEMM3 -> OUTR (in old Y2 space); final norm
    k_gemm<<<dim3(16, 16), 256, 0, stream>>>(XG, OT, OUTR, 2048, 2048, 2048);
    k_final<<<2048, 256, 0, stream>>>(x_in, OUTR, ln2, (float*)d_out);
}

// Round 26
// 361.114 us; speedup vs baseline: 1.1541x; 1.0429x over previous
//
#include <hip/hip_runtime.h>

typedef unsigned short u16;
typedef unsigned int u32;

using f32x4 = __attribute__((ext_vector_type(4))) float;
using bf16x8 = __attribute__((ext_vector_type(8))) __bf16;

// ---------- constants ----------
#define HN 2048
#define KVD 512
#define TOKENS 2048          // B*T
#define N1 3712              // GEMM1 N (3648 padded to 29*128)
#define K2W 576              // GEMM2 K
#define N2 7168              // GEMM2 N: w(2048) a(2048) g(2048) v(512) k(512)

// ---------- workspace layout (bytes) — lifetime-aliased ----------
#define OFF_Y1   0ull                    // bf16 [2048][3712] = 15.2MB (dead after prep_rec)
#define OFF_OO   0ull                    // f32 [2048][2048] (after Y1 dead)
#define OFF_XG   16777216ull
#define OFF_Y2   30408704ull             // f32 [2048][7168]
#define OFF_OUTR 30408704ull             // after Y2 dead
#define OFF_BT1  89128960ull
#define OFF_XB   104333312ull
#define OFF_W2T  89128960ull
#define OFF_X2   97386496ull
#define OFF_OT   89128960ull
#define OFF_RR   112721920ull            // (unused region, kept for layout stability)
#define OFF_DEC  129499136ull
#define OFF_KR   146276352ull            // (unused)
#define OFF_VV   163053568ull
#define OFF_AA   179830784ull            // (unused)
#define OFF_BB   196608000ull            // (unused)
#define OFF_PAB  213385216ull            // u32 [2048][2048]: bf16(A) | bf16(B)<<16
#define OFF_PKR  230162432ull            // u32 [2048][2048]: bf16(K) | bf16(R)<<16
#define OFF_DOT  246939648ull            // f32 [2048][32] = 256KB
#define WS_NEED  247201792ull

// ---------- helpers ----------
__device__ __forceinline__ u16 f2bf(float f) {
    u32 u = __float_as_uint(f);
    u32 r = u + 0x7fffu + ((u >> 16) & 1u);
    return (u16)(r >> 16);
}
__device__ __forceinline__ float bf2f(u16 b) {
    return __uint_as_float(((u32)b) << 16);
}
__device__ __forceinline__ float sigm(float x) { return 1.f / (1.f + expf(-x)); }
__device__ __forceinline__ float wsum(float v) {
#pragma unroll
    for (int m = 32; m > 0; m >>= 1) v += __shfl_xor(v, m, 64);
    return v;
}
// sum across each 16-lane DPP row via row_ror 1,2,4,8; result in all lanes of the row
__device__ __forceinline__ float rowsum16(float v) {
    float t;
    t = __uint_as_float(__builtin_amdgcn_update_dpp(0, __float_as_uint(v), 0x121, 0xf, 0xf, true));
    v += t;
    t = __uint_as_float(__builtin_amdgcn_update_dpp(0, __float_as_uint(v), 0x122, 0xf, 0xf, true));
    v += t;
    t = __uint_as_float(__builtin_amdgcn_update_dpp(0, __float_as_uint(v), 0x124, 0xf, 0xf, true));
    v += t;
    t = __uint_as_float(__builtin_amdgcn_update_dpp(0, __float_as_uint(v), 0x128, 0xf, 0xf, true));
    v += t;
    return v;
}

typedef __attribute__((address_space(1))) const void glob_t;
typedef __attribute__((address_space(3))) void lds_t;
__device__ __forceinline__ void gload_lds16(const void* g, void* l) {
    __builtin_amdgcn_global_load_lds((glob_t*)g, (lds_t*)l, 16, 0, 0);
}

// inline-asm LDS readers with literal offset (burst-issued, order preserved)
template<int OFF>
__device__ __forceinline__ float4 ds_read128(u32 a) {
    float4 r;
    asm volatile("ds_read_b128 %0, %1 offset:%2" : "=v"(r) : "v"(a), "i"(OFF));
    return r;
}
template<int OFF>
__device__ __forceinline__ uint4 ds_read128u(u32 a) {
    uint4 r;
    asm volatile("ds_read_b128 %0, %1 offset:%2" : "=v"(r) : "v"(a), "i"(OFF));
    return r;
}
template<int OFF>
__device__ __forceinline__ float ds_read32(u32 a) {
    float r;
    asm volatile("ds_read_b32 %0, %1 offset:%2" : "=v"(r) : "v"(a), "i"(OFF));
    return r;
}

// ---------- weight prep: tiled transposes (coalesced read AND write) ----------
__global__ __launch_bounds__(256) void k_prep_bt1(const float* __restrict__ wavgk1,
                                                  const float* __restrict__ RKV,
                                                  u16* __restrict__ BT1) {
    __shared__ float tile[64][65];
    const int bn = blockIdx.x >> 5;        // 0..57
    const int bk = blockIdx.x & 31;        // 0..31
    const int n0 = bn << 6, k0 = bk << 6;
    const int c = threadIdx.x & 63, q = threadIdx.x >> 6;
#pragma unroll
    for (int i = 0; i < 16; ++i) {
        const int r = (q << 4) + i;
        float v = 0.f;
        if (bn < 9)       v = wavgk1[(size_t)(k0 + r) * 576 + n0 + c];
        else if (bn < 57) v = RKV[(size_t)(k0 + r) * 3072 + (n0 + c - 576)];
        tile[r][c] = v;
    }
    __syncthreads();
#pragma unroll
    for (int i = 0; i < 16; ++i) {
        const int rw = (q << 4) + i;
        BT1[(size_t)(n0 + rw) * 2048 + k0 + c] = f2bf(tile[c][rw]);
    }
}

// W2T[n][c] = blockdiag src[c][n]; 64x64 tiles, both sides coalesced.
__global__ __launch_bounds__(256) void k_prep_w2t(const float* __restrict__ w2, const float* __restrict__ a2,
                                                  const float* __restrict__ g2, const float* __restrict__ v2,
                                                  const float* __restrict__ k2, u16* __restrict__ W2T) {
    __shared__ float tile[64][65];
    const int bx = blockIdx.x;
    const int bn = bx / 9, bc = bx - bn * 9;
    const int n0 = bn << 6, c0 = bc << 6;
    const int cc = threadIdx.x & 63, q = threadIdx.x >> 6;
#pragma unroll
    for (int i = 0; i < 16; ++i) {
        const int r = (q << 4) + i;        // c-offset within tile
        const int c = c0 + r;
        const int n = n0 + cc;
        float v = 0.f;
        if (n0 < 2048)      { if (c < 96)              v = w2[(size_t)c * 2048 + n]; }
        else if (n0 < 4096) { if (c >= 96 && c < 192)  v = a2[(size_t)(c - 96) * 2048 + (n - 2048)]; }
        else if (n0 < 6144) { if (c >= 192 && c < 448) v = g2[(size_t)(c - 192) * 2048 + (n - 4096)]; }
        else if (n0 < 6656) { if (c >= 448 && c < 512) v = v2[(size_t)(c - 448) * 512 + (n - 6144)]; }
        else                { if (c >= 512)            v = k2[(size_t)(c - 512) * 512 + (n - 6656)]; }
        tile[r][cc] = v;
    }
    __syncthreads();
#pragma unroll
    for (int i = 0; i < 16; ++i) {
        const int rw = (q << 4) + i;       // n-offset within tile
        W2T[(size_t)(n0 + rw) * 576 + c0 + cc] = f2bf(tile[cc][rw]);
    }
}

// OT[n][k] = O[k][n], 2048x2048, 64x64 tiles
__global__ __launch_bounds__(256) void k_prep_ot(const float* __restrict__ O, u16* __restrict__ OT) {
    __shared__ float tile[64][65];
    const int bn = blockIdx.x >> 5, bk = blockIdx.x & 31;
    const int n0 = bn << 6, k0 = bk << 6;
    const int c = threadIdx.x & 63, q = threadIdx.x >> 6;
#pragma unroll
    for (int i = 0; i < 16; ++i) {
        const int r = (q << 4) + i;
        tile[r][c] = O[(size_t)(k0 + r) * 2048 + n0 + c];
    }
    __syncthreads();
#pragma unroll
    for (int i = 0; i < 16; ++i) {
        const int rw = (q << 4) + i;
        OT[(size_t)(n0 + rw) * 2048 + k0 + c] = f2bf(tile[c][rw]);
    }
}

// ---------- rmsnorm(x_in, ln1) -> bf16 ----------
__global__ __launch_bounds__(256) void k_rms1(const float* __restrict__ X,
                                              const float* __restrict__ ln1,
                                              u16* __restrict__ XB) {
    const int t = blockIdx.x, tid = threadIdx.x;
    const float* row = X + ((size_t)t << 11);
    float4 v0 = *(const float4*)(row + tid * 8);
    float4 v1 = *(const float4*)(row + tid * 8 + 4);
    float ss = v0.x*v0.x + v0.y*v0.y + v0.z*v0.z + v0.w*v0.w
             + v1.x*v1.x + v1.y*v1.y + v1.z*v1.z + v1.w*v1.w;
    ss = wsum(ss);
    __shared__ float red[4];
    if ((tid & 63) == 0) red[tid >> 6] = ss;
    __syncthreads();
    float scale = rsqrtf((red[0] + red[1] + red[2] + red[3]) * (1.f / 2048.f) + 1e-6f);
    float4 w0_ = *(const float4*)(ln1 + tid * 8);
    float4 w1_ = *(const float4*)(ln1 + tid * 8 + 4);
    u16* o = XB + ((size_t)t << 11) + tid * 8;
    o[0] = f2bf(v0.x * scale * w0_.x); o[1] = f2bf(v0.y * scale * w0_.y);
    o[2] = f2bf(v0.z * scale * w0_.z); o[3] = f2bf(v0.w * scale * w0_.w);
    o[4] = f2bf(v1.x * scale * w1_.x); o[5] = f2bf(v1.y * scale * w1_.y);
    o[6] = f2bf(v1.z * scale * w1_.z); o[7] = f2bf(v1.w * scale * w1_.w);
}

// ---------- generic bf16 MFMA GEMM with LDS chunk swizzle (f32 C) ----------
__global__ __launch_bounds__(256) void k_gemm(const u16* __restrict__ A,
                                              const u16* __restrict__ Bt,
                                              float* __restrict__ C,
                                              int M, int N, int K) {
    __shared__ __align__(16) u16 tA[4096];  // [128 rows][32 k]
    __shared__ __align__(16) u16 tB[4096];
    const int tid = threadIdx.x;
    const int w = tid >> 6, l = tid & 63;
    const int bm = blockIdx.x << 7, bn = blockIdx.y << 7;
    const int wm = (w >> 1) << 6, wn = (w & 1) << 6;
    const int lrow = l >> 2;        // 0..15 (staged row within 16-row group)
    const int lk = (((l & 3) ^ ((l >> 3) & 3)) << 3);   // pre-swizzled global chunk
    f32x4 acc[4][4] = {};
    const size_t rA0 = (size_t)(bm + (w << 4) + lrow) * K;
    const size_t rA1 = (size_t)(bm + ((w + 4) << 4) + lrow) * K;
    const size_t rB0 = (size_t)(bn + (w << 4) + lrow) * K;
    const size_t rB1 = (size_t)(bn + ((w + 4) << 4) + lrow) * K;
    const int frow = l & 15;
    const int koff = (((l >> 4) ^ ((l >> 1) & 3)) << 3);  // swizzled read chunk
    for (int kt = 0; kt < K; kt += 32) {
        gload_lds16(A + rA0 + kt + lk, &tA[w << 9]);
        gload_lds16(A + rA1 + kt + lk, &tA[2048 + (w << 9)]);
        gload_lds16(Bt + rB0 + kt + lk, &tB[w << 9]);
        gload_lds16(Bt + rB1 + kt + lk, &tB[2048 + (w << 9)]);
        __syncthreads();
        bf16x8 av[4], bv[4];
#pragma unroll
        for (int i = 0; i < 4; ++i) {
            av[i] = *(const bf16x8*)&tA[((wm + (i << 4) + frow) << 5) + koff];
            bv[i] = *(const bf16x8*)&tB[((wn + (i << 4) + frow) << 5) + koff];
        }
#pragma unroll
        for (int i = 0; i < 4; ++i)
#pragma unroll
            for (int j = 0; j < 4; ++j)
                acc[i][j] = __builtin_amdgcn_mfma_f32_16x16x32_bf16(av[i], bv[j], acc[i][j], 0, 0, 0);
        __syncthreads();
    }
    const int crow = bm + wm + ((l >> 4) << 2);
    const int ccol = bn + wn + (l & 15);
#pragma unroll
    for (int i = 0; i < 4; ++i)
#pragma unroll
        for (int j = 0; j < 4; ++j)
#pragma unroll
            for (int jj = 0; jj < 4; ++jj)
                C[(size_t)(crow + (i << 4) + jj) * N + ccol + (j << 4)] = acc[i][j][jj];
}

// ---------- same GEMM, bf16 C output (for Y1) ----------
__global__ __launch_bounds__(256) void k_gemmb(const u16* __restrict__ A,
                                               const u16* __restrict__ Bt,
                                               u16* __restrict__ C,
                                               int M, int N, int K) {
    __shared__ __align__(16) u16 tA[4096];
    __shared__ __align__(16) u16 tB[4096];
    const int tid = threadIdx.x;
    const int w = tid >> 6, l = tid & 63;
    const int bm = blockIdx.x << 7, bn = blockIdx.y << 7;
    const int wm = (w >> 1) << 6, wn = (w & 1) << 6;
    const int lrow = l >> 2;
    const int lk = (((l & 3) ^ ((l >> 3) & 3)) << 3);
    f32x4 acc[4][4] = {};
    const size_t rA0 = (size_t)(bm + (w << 4) + lrow) * K;
    const size_t rA1 = (size_t)(bm + ((w + 4) << 4) + lrow) * K;
    const size_t rB0 = (size_t)(bn + (w << 4) + lrow) * K;
    const size_t rB1 = (size_t)(bn + ((w + 4) << 4) + lrow) * K;
    const int frow = l & 15;
    const int koff = (((l >> 4) ^ ((l >> 1) & 3)) << 3);
    for (int kt = 0; kt < K; kt += 32) {
        gload_lds16(A + rA0 + kt + lk, &tA[w << 9]);
        gload_lds16(A + rA1 + kt + lk, &tA[2048 + (w << 9)]);
        gload_lds16(Bt + rB0 + kt + lk, &tB[w << 9]);
        gload_lds16(Bt + rB1 + kt + lk, &tB[2048 + (w << 9)]);
        __syncthreads();
        bf16x8 av[4], bv[4];
#pragma unroll
        for (int i = 0; i < 4; ++i) {
            av[i] = *(const bf16x8*)&tA[((wm + (i << 4) + frow) << 5) + koff];
            bv[i] = *(const bf16x8*)&tB[((wn + (i << 4) + frow) << 5) + koff];
        }
#pragma unroll
        for (int i = 0; i < 4; ++i)
#pragma unroll
            for (int j = 0; j < 4; ++j)
                acc[i][j] = __builtin_amdgcn_mfma_f32_16x16x32_bf16(av[i], bv[j], acc[i][j], 0, 0, 0);
        __syncthreads();
    }
    const int crow = bm + wm + ((l >> 4) << 2);
    const int ccol = bn + wn + (l & 15);
#pragma unroll
    for (int i = 0; i < 4; ++i)
#pragma unroll
        for (int j = 0; j < 4; ++j)
#pragma unroll
            for (int jj = 0; jj < 4; ++jj)
                C[(size_t)(crow + (i << 4) + jj) * N + ccol + (j << 4)] = f2bf(acc[i][j][jj]);
}

// ---------- GEMM2 specialization: block-diagonal W2T, per-segment true K ----------
__global__ __launch_bounds__(256) void k_gemm2(const u16* __restrict__ A,
                                               const u16* __restrict__ Bt,
                                               float* __restrict__ C) {
    __shared__ __align__(16) u16 tA[4096];
    __shared__ __align__(16) u16 tB[4096];
    const int tid = threadIdx.x;
    const int w = tid >> 6, l = tid & 63;
    const int by = blockIdx.y;
    int c0, K;
    if (by < 16)      { c0 = 0;   K = 96; }
    else if (by < 32) { c0 = 96;  K = 96; }
    else if (by < 48) { c0 = 192; K = 256; }
    else if (by < 52) { c0 = 448; K = 64; }
    else              { c0 = 512; K = 64; }
    const int n0 = by << 7;
    const int bm = blockIdx.x << 7;
    const int wm = (w >> 1) << 6, wn = (w & 1) << 6;
    const int lrow = l >> 2;
    const int lk = (((l & 3) ^ ((l >> 3) & 3)) << 3);
    f32x4 acc[4][4] = {};
    const size_t rA0 = (size_t)(bm + (w << 4) + lrow) * 576 + c0;
    const size_t rA1 = (size_t)(bm + ((w + 4) << 4) + lrow) * 576 + c0;
    const size_t rB0 = (size_t)(n0 + (w << 4) + lrow) * 576 + c0;
    const size_t rB1 = (size_t)(n0 + ((w + 4) << 4) + lrow) * 576 + c0;
    const int frow = l & 15;
    const int koff = (((l >> 4) ^ ((l >> 1) & 3)) << 3);
    for (int kt = 0; kt < K; kt += 32) {
        gload_lds16(A + rA0 + kt + lk, &tA[w << 9]);
        gload_lds16(A + rA1 + kt + lk, &tA[2048 + (w << 9)]);
        gload_lds16(Bt + rB0 + kt + lk, &tB[w << 9]);
        gload_lds16(Bt + rB1 + kt + lk, &tB[2048 + (w << 9)]);
        __syncthreads();
        bf16x8 av[4], bv[4];
#pragma unroll
        for (int i = 0; i < 4; ++i) {
            av[i] = *(const bf16x8*)&tA[((wm + (i << 4) + frow) << 5) + koff];
            bv[i] = *(const bf16x8*)&tB[((wn + (i << 4) + frow) << 5) + koff];
        }
#pragma unroll
        for (int i = 0; i < 4; ++i)
#pragma unroll
            for (int j = 0; j < 4; ++j)
                acc[i][j] = __builtin_amdgcn_mfma_f32_16x16x32_bf16(av[i], bv[j], acc[i][j], 0, 0, 0);
        __syncthreads();
    }
    const int crow = bm + wm + ((l >> 4) << 2);
    const int ccol = n0 + wn + (l & 15);
#pragma unroll
    for (int i = 0; i < 4; ++i)
#pragma unroll
        for (int j = 0; j < 4; ++j)
#pragma unroll
            for (int jj = 0; jj < 4; ++jj)
                C[(size_t)(crow + (i << 4) + jj) * N2 + ccol + (j << 4)] = acc[i][j][jj];
}

// ---------- Y1(bf16) -> X2 (bf16): [tanh(xw) | xa | sigmoid(xg) | xv | xk] ----------
__global__ __launch_bounds__(256) void k_prep_x2(const u16* __restrict__ Y1, u16* __restrict__ X2) {
    int idx = blockIdx.x * 256 + threadIdx.x;   // t*576 + c
    int t = idx / 576, c = idx - t * 576;
    const u16* y1 = Y1 + (size_t)t * N1;
    float v;
    if (c < 96)       v = tanhf(bf2f(y1[c]));
    else if (c < 192) v = bf2f(y1[c]);
    else if (c < 448) v = sigm(bf2f(y1[c + 64]));
    else if (c < 512) v = bf2f(y1[c - 256]);
    else              v = bf2f(y1[c]);
    X2[idx] = f2bf(v);
}

// ---------- per-token recurrence prep (+ packed coeffs + head-dot) ----------
__global__ __launch_bounds__(256) void k_prep_rec(
    const u16* __restrict__ Y1, const float* __restrict__ Y2,
    const float* __restrict__ v_first, const float* __restrict__ k_first,
    const float* __restrict__ cosb, const float* __restrict__ sinb,
    const float* __restrict__ w0, const float* __restrict__ a0,
    const float* __restrict__ v0b, const float* __restrict__ k0b,
    const float* __restrict__ R_bias, const float* __restrict__ K_bias,
    const float* __restrict__ V_bias, const float* __restrict__ ln_r,
    const float* __restrict__ ln_k, const float* __restrict__ r_k,
    float* __restrict__ DEC, float* __restrict__ VV,
    u32* __restrict__ PAB, u32* __restrict__ PKR, float* __restrict__ DOT) {
    const int t = blockIdx.x, tid = threadIdx.x;
    const int ww = tid >> 6, lane = tid & 63;
    const u16* y1 = Y1 + (size_t)t * N1;
    const float* y2 = Y2 + (size_t)t * N2;
    const float cs = cosb[t * 64 + lane];
    const float sn = sinb[t * 64 + lane];
    const float sign = lane < 32 ? -1.f : 1.f;
    const size_t tb = (size_t)t << 11;
    __shared__ float kkv[512], vkv[512];
    float rsave[8];
    // r: per-head rmsnorm + rope
#pragma unroll
    for (int i = 0; i < 8; ++i) {
        int h = ww * 8 + i, c = h * 64 + lane;
        float rr = bf2f(y1[576 + c]) + R_bias[c];
        float ssq = wsum(rr * rr);
        float rn = ln_r[lane] * rr * rsqrtf(ssq * (1.f / 64.f) + 1e-6f);
        float rot = sign * __shfl(rn, lane ^ 32, 64);
        rsave[i] = rn * cs + rot * sn;
    }
    // k,v kv-heads: rmsnorm+rope+mix
#pragma unroll
    for (int i = 0; i < 2; ++i) {
        int j = ww * 2 + i, c = j * 64 + lane;
        float kr = bf2f(y1[2624 + c]) + K_bias[c];
        float ssq = wsum(kr * kr);
        float kn = ln_k[lane] * kr * rsqrtf(ssq * (1.f / 64.f) + 1e-6f);
        float rot = sign * __shfl(kn, lane ^ 32, 64);
        float krope = kn * cs + rot * sn;
        float ksig = sigm(y2[6656 + c] + k0b[c]);
        kkv[c] = krope + (k_first[(size_t)t * 512 + c] - krope) * ksig;
        float vr = bf2f(y1[3136 + c]) + V_bias[c];
        float vsig = sigm(y2[6144 + c] + v0b[c]);
        vkv[c] = vr + (v_first[(size_t)t * 512 + c] - vr) * vsig;
    }
    __syncthreads();
    // per-head final recurrence operands
#pragma unroll
    for (int i = 0; i < 8; ++i) {
        int h = ww * 8 + i, c = h * 64 + lane;
        int ckv = (h >> 2) * 64 + lane;
        float kb = kkv[ckv], vb = vkv[ckv];
        float a_ = sigm(y2[2048 + c] + a0[c]);
        float wr = y2[c] + w0[c];
        float z = -wr;
        float sp = fmaxf(z, 0.f) + log1pf(expf(-fabsf(z)));
        float w_log = -sp - 0.5f;
        float ssq = wsum(kb * kb);
        float kk = kb / fmaxf(sqrtf(ssq), 1e-12f);
        const float kr2 = kb * (1.f - w_log + a_);
        const float rrv = rsave[i];
        DEC[tb + c] = expf(-expf(w_log));
        VV[tb + c] = vb;
        PAB[tb + c] = (u32)f2bf(-kk) | ((u32)f2bf(kk * a_) << 16);
        PKR[tb + c] = (u32)f2bf(kr2) | ((u32)f2bf(rrv) << 16);
        const float dsum = wsum(rrv * kr2 * r_k[c]);
        if (lane == 0) DOT[((size_t)t << 5) + h] = dsum;
    }
}

// ---------- sequential recurrence: homogeneous-b128, 2 groups in flight (r24 best) ----------
__global__ __launch_bounds__(256, 1) void k_recv17(
    const float* __restrict__ DECp, const u32* __restrict__ PABp,
    const u32* __restrict__ PKRp, const float* __restrict__ VVp,
    const float* __restrict__ S0, float* __restrict__ OO) {
    __shared__ __align__(16) float cbuf[2][4][32][64];   // 64 KB
    const int tid = threadIdx.x;
    const int wl = tid >> 6;           // wave 0..3
    const int lane = tid & 63;
    const int vl = lane >> 4;          // DPP row 0..3
    const int kq = lane & 15;          // k-quad 0..15
    const int quarter = blockIdx.x & 3;
    const int ch = blockIdx.x >> 2;          // chain 0..63 (b*32+h)
    const int vcol = (quarter << 4) + (wl << 2) + vl;   // this row's v-column
    const size_t cb = ((size_t)(ch >> 5) * 1024 * 2048) + ((size_t)(ch & 31) << 6);

    const float* s0 = S0 + ((size_t)ch << 12);
    float L0 = s0[((kq << 2) + 0) * 64 + vcol];
    float L1 = s0[((kq << 2) + 1) * 64 + vcol];
    float L2 = s0[((kq << 2) + 2) * 64 + vcol];
    float L3 = s0[((kq << 2) + 3) * 64 + vcol];

    const int trow = (wl << 2) + vl;   // 0..15; rows trow and trow+16 staged

#define STG(B, T0)                                                             \
    {                                                                          \
        const size_t g0 = cb + (size_t)((T0) + trow) * 2048 + (kq << 2);       \
        const size_t g1 = cb + (size_t)((T0) + 16 + trow) * 2048 + (kq << 2);  \
        float* lb = &cbuf[B][0][0][0] + (wl << 8);                             \
        gload_lds16(DECp + g0, lb);                                            \
        gload_lds16(DECp + g1, lb + 1024);                                     \
        gload_lds16(PABp + g0, lb + 2048);                                     \
        gload_lds16(PABp + g1, lb + 3072);                                     \
        gload_lds16(PKRp + g0, lb + 4096);                                     \
        gload_lds16(PKRp + g1, lb + 5120);                                     \
        gload_lds16(VVp + g0, lb + 6144);                                      \
        gload_lds16(VVp + g1, lb + 7168);                                      \
    }

    const u32 base0 = (u32)(size_t)(void*)&cbuf[0][0][0][0];
    const u32 aA0 = base0 + (kq << 4);             // coefficient chunk for lane
    const u32 aV0 = base0 + 24576 + (vcol << 2);   // V broadcast slot

    float4 cDa0, cDa1, cDb0, cDb1;
    uint4 cPAa0, cPAa1, cPAb0, cPAb1, cPKa0, cPKa1, cPKb0, cPKb1;
    float cV[32];

#define LD2(S_, G)                                                             \
    cD##S_##0 = ds_read128<(G) * 512>(aAb);                                    \
    cD##S_##1 = ds_read128<(G) * 512 + 256>(aAb);                              \
    cPA##S_##0 = ds_read128u<8192 + (G) * 512>(aAb);                           \
    cPA##S_##1 = ds_read128u<8192 + (G) * 512 + 256>(aAb);                     \
    cPK##S_##0 = ds_read128u<16384 + (G) * 512>(aAb);                          \
    cPK##S_##1 = ds_read128u<16384 + (G) * 512 + 256>(aAb);

#define VRD(J) cV[J] = ds_read32<(J) * 256>(aVb);
#define VRD8(J) VRD(J) VRD((J)+1) VRD((J)+2) VRD((J)+3) VRD((J)+4) VRD((J)+5) VRD((J)+6) VRD((J)+7)

#define WAIT6 asm volatile("s_waitcnt lgkmcnt(6)" ::: "memory");               \
    __builtin_amdgcn_sched_barrier(0);
#define WAIT0 asm volatile("s_waitcnt lgkmcnt(0)" ::: "memory");               \
    __builtin_amdgcn_sched_barrier(0);

#define UNP_LO(u) __uint_as_float((u) << 16)
#define UNP_HI(u) __uint_as_float((u) & 0xffff0000u)

#define STEP1(D4, pa, pk, Vsj, T)                                              \
    {                                                                          \
        const float Ax = UNP_LO(pa.x), Ay = UNP_LO(pa.y),                      \
                    Az = UNP_LO(pa.z), Aw = UNP_LO(pa.w);                      \
        const float Bx = UNP_HI(pa.x), By = UNP_HI(pa.y),                      \
                    Bz = UNP_HI(pa.z), Bw = UNP_HI(pa.w);                      \
        const float Kx = UNP_LO(pk.x), Ky = UNP_LO(pk.y),                      \
                    Kz = UNP_LO(pk.z), Kw = UNP_LO(pk.w);                      \
        const float Rx = UNP_HI(pk.x), Ry = UNP_HI(pk.y),                      \
                    Rz = UNP_HI(pk.z), Rw = UNP_HI(pk.w);                      \
        float sp = fmaf(L1, Ay, L0 * Ax) + fmaf(L3, Aw, L2 * Az);              \
        const float sa = rowsum16(sp);                                         \
        L0 = fmaf(Bx, sa, fmaf(Kx, Vsj, L0 * D4.x));                           \
        L1 = fmaf(By, sa, fmaf(Ky, Vsj, L1 * D4.y));                           \
        L2 = fmaf(Bz, sa, fmaf(Kz, Vsj, L2 * D4.z));                           \
        L3 = fmaf(Bw, sa, fmaf(Kw, Vsj, L3 * D4.w));                           \
        float op = fmaf(L1, Ry, L0 * Rx) + fmaf(L3, Rw, L2 * Rz);              \
        const float o = rowsum16(op);                                          \
        if (kq == 0) OO[cb + ((size_t)(T) << 11) + vcol] = o;                  \
    }

#define STEP2(S_, G)                                                           \
    STEP1(cD##S_##0, cPA##S_##0, cPK##S_##0, cV[2 * (G)], tbase + 2 * (G));    \
    STEP1(cD##S_##1, cPA##S_##1, cPK##S_##1, cV[2 * (G) + 1], tbase + 2 * (G) + 1);

#define PAIR(G)                                                                \
    LD2(b, (G) + 1) WAIT6 STEP2(a, G) LD2(a, (G) + 2) WAIT6 STEP2(b, (G) + 1)

    STG(0, 0);
    __syncthreads();

    for (int c = 0; c < 32; ++c) {
        const int b = c & 1;
        if (c < 31) STG(b ^ 1, (c + 1) << 5);      // async prefetch next chunk (vmcnt)
        const u32 aAb = aA0 + b * 32768;
        const u32 aVb = aV0 + b * 32768;
        const int tbase = c << 5;
        VRD8(0) VRD8(8) VRD8(16) VRD8(24)          // all 32 V values (b32 burst)
        WAIT0                                      // V in regs; lgkm queue empty
        LD2(a, 0)
        PAIR(0) PAIR(2) PAIR(4) PAIR(6) PAIR(8) PAIR(10) PAIR(12)
        LD2(b, 15) WAIT6 STEP2(a, 14) WAIT0 STEP2(b, 15)
        __syncthreads();   // drains staging vmcnt (1/32 steps); flips buffers
    }
#undef PAIR
#undef STEP2
#undef STEP1
#undef UNP_LO
#undef UNP_HI
#undef WAIT0
#undef WAIT6
#undef VRD8
#undef VRD
#undef LD2
#undef STG
}

// ---------- gate: pure elementwise (dot precomputed in prep_rec) ----------
__global__ __launch_bounds__(256) void k_gate(
    const float* __restrict__ OOp, const float* __restrict__ VVp,
    const float* __restrict__ DOT, const float* __restrict__ Y2,
    u16* __restrict__ XG) {
    const int t = blockIdx.x, tid = threadIdx.x;
    const size_t tb = (size_t)t << 11;
    const int c0 = tid << 3;
    const float dot = DOT[((size_t)t << 5) + (tid >> 3)];
    float4 o0 = *(const float4*)(OOp + tb + c0);
    float4 o1 = *(const float4*)(OOp + tb + c0 + 4);
    float4 v0 = *(const float4*)(VVp + tb + c0);
    float4 v1 = *(const float4*)(VVp + tb + c0 + 4);
    const float* g = Y2 + (size_t)t * N2 + 4096 + c0;
    float4 g0 = *(const float4*)(g);
    float4 g1 = *(const float4*)(g + 4);
    const float x0 = fmaf(o0.x, 0.125f, dot * v0.x) * g0.x;
    const float x1 = fmaf(o0.y, 0.125f, dot * v0.y) * g0.y;
    const float x2 = fmaf(o0.z, 0.125f, dot * v0.z) * g0.z;
    const float x3 = fmaf(o0.w, 0.125f, dot * v0.w) * g0.w;
    const float x4 = fmaf(o1.x, 0.125f, dot * v1.x) * g1.x;
    const float x5 = fmaf(o1.y, 0.125f, dot * v1.y) * g1.y;
    const float x6 = fmaf(o1.z, 0.125f, dot * v1.z) * g1.z;
    const float x7 = fmaf(o1.w, 0.125f, dot * v1.w) * g1.w;
    uint4 pk;
    pk.x = (u32)f2bf(x0) | ((u32)f2bf(x1) << 16);
    pk.y = (u32)f2bf(x2) | ((u32)f2bf(x3) << 16);
    pk.z = (u32)f2bf(x4) | ((u32)f2bf(x5) << 16);
    pk.w = (u32)f2bf(x6) | ((u32)f2bf(x7) << 16);
    *(uint4*)(XG + tb + c0) = pk;
}

// ---------- final residual + rmsnorm ----------
__global__ __launch_bounds__(256) void k_final(const float* __restrict__ x_in,
                                               const float* __restrict__ OUTR,
                                               const float* __restrict__ ln2,
                                               float* __restrict__ out) {
    const int t = blockIdx.x, tid = threadIdx.x;
    const float* xr = x_in + ((size_t)t << 11);
    const float* orow = OUTR + ((size_t)t << 11);
    float4 a0 = *(const float4*)(xr + tid * 8);
    float4 a1 = *(const float4*)(xr + tid * 8 + 4);
    float4 b0 = *(const float4*)(orow + tid * 8);
    float4 b1 = *(const float4*)(orow + tid * 8 + 4);
    float v[8] = {a0.x + b0.x, a0.y + b0.y, a0.z + b0.z, a0.w + b0.w,
                  a1.x + b1.x, a1.y + b1.y, a1.z + b1.z, a1.w + b1.w};
    float ss = 0.f;
#pragma unroll
    for (int i = 0; i < 8; ++i) ss = fmaf(v[i], v[i], ss);
    ss = wsum(ss);
    __shared__ float red[4];
    if ((tid & 63) == 0) red[tid >> 6] = ss;
    __syncthreads();
    float scale = rsqrtf((red[0] + red[1] + red[2] + red[3]) * (1.f / 2048.f) + 1e-6f);
    float* o = out + ((size_t)t << 11) + tid * 8;
#pragma unroll
    for (int i = 0; i < 8; ++i) o[i] = ln2[tid * 8 + i] * v[i] * scale;
}

extern "C" void kernel_launch(void* const* d_in, const int* in_sizes, int n_in,
                              void* d_out, int out_size, void* d_ws, size_t ws_size,
                              hipStream_t stream) {
    const float* x_in    = (const float*)d_in[0];
    const float* v_first = (const float*)d_in[1];
    const float* k_first = (const float*)d_in[2];
    const float* state   = (const float*)d_in[3];
    const float* cosb    = (const float*)d_in[4];
    const float* sinb    = (const float*)d_in[5];
    const float* wavgk1  = (const float*)d_in[6];
    const float* w0      = (const float*)d_in[7];
    const float* w2      = (const float*)d_in[8];
    const float* a0      = (const float*)d_in[9];
    const float* a2      = (const float*)d_in[10];
    const float* v0      = (const float*)d_in[11];
    const float* v2      = (const float*)d_in[12];
    const float* g2      = (const float*)d_in[13];
    const float* k0      = (const float*)d_in[14];
    const float* k2      = (const float*)d_in[15];
    const float* r_k     = (const float*)d_in[16];
    const float* RKV     = (const float*)d_in[17];
    const float* O       = (const float*)d_in[18];
    const float* R_bias  = (const float*)d_in[19];
    const float* K_bias  = (const float*)d_in[20];
    const float* V_bias  = (const float*)d_in[21];
    const float* ln_r    = (const float*)d_in[22];
    const float* ln_k    = (const float*)d_in[23];
    const float* ln1     = (const float*)d_in[24];
    const float* ln2     = (const float*)d_in[25];

    if (ws_size < WS_NEED) return;  // need 247.2 MB (fits 256 MiB)

    char* ws = (char*)d_ws;
    u16*   BT1  = (u16*)(ws + OFF_BT1);
    u16*   W2T  = (u16*)(ws + OFF_W2T);
    u16*   OT   = (u16*)(ws + OFF_OT);
    u16*   XB   = (u16*)(ws + OFF_XB);
    u16*   Y1   = (u16*)(ws + OFF_Y1);
    u16*   X2   = (u16*)(ws + OFF_X2);
    float* Y2   = (float*)(ws + OFF_Y2);
    float* DEC  = (float*)(ws + OFF_DEC);
    float* VV   = (float*)(ws + OFF_VV);
    u32*   PAB  = (u32*)(ws + OFF_PAB);
    u32*   PKR  = (u32*)(ws + OFF_PKR);
    float* DOT  = (float*)(ws + OFF_DOT);
    float* OO   = (float*)(ws + OFF_OO);
    u16*   XG   = (u16*)(ws + OFF_XG);
    float* OUTR = (float*)(ws + OFF_OUTR);

    // P0: BT1 + XB (region C)
    k_prep_bt1<<<1856, 256, 0, stream>>>(wavgk1, RKV, BT1);
    k_rms1<<<2048, 256, 0, stream>>>(x_in, ln1, XB);
    // P1: GEMM1 -> Y1 (bf16, region A)
    k_gemmb<<<dim3(16, 29), 256, 0, stream>>>(XB, BT1, Y1, 2048, N1, 2048);
    // P2: W2T + X2 overwrite BT1/XB (dead); GEMM2 (block-diagonal) -> Y2 (region B)
    k_prep_w2t<<<1008, 256, 0, stream>>>(w2, a2, g2, v2, k2, W2T);
    k_prep_x2<<<4608, 256, 0, stream>>>(Y1, X2);
    k_gemm2<<<dim3(16, 56), 256, 0, stream>>>(X2, W2T, Y2);
    // P3: recurrence operands + head-dot; Y1 dead after this
    k_prep_rec<<<2048, 256, 0, stream>>>(Y1, Y2, v_first, k_first, cosb, sinb,
                                         w0, a0, v0, k0, R_bias, K_bias, V_bias,
                                         ln_r, ln_k, r_k, DEC, VV, PAB, PKR, DOT);
    // P4: OT overwrites W2T/X2 (dead); recurrence -> OO (in old Y1 space)
    k_prep_ot<<<1024, 256, 0, stream>>>(O, OT);
    k_recv17<<<256, 256, 0, stream>>>(DEC, PAB, PKR, VV, state, OO);
    // P5: gate (elementwise) -> XG; Y2 dead after this
    k_gate<<<2048, 256, 0, stream>>>(OO, VV, DOT, Y2, XG);
    // P6: GEMM3 -> OUTR (in old Y2 space); final norm
    k_gemm<<<dim3(16, 16), 256, 0, stream>>>(XG, OT, OUTR, 2048, 2048, 2048);
    k_final<<<2048, 256, 0, stream>>>(x_in, OUTR, ln2, (float*)d_out);
}

// Round 27
// 342.798 us; speedup vs baseline: 1.2158x; 1.0534x over previous
//
#include <hip/hip_runtime.h>

typedef unsigned short u16;
typedef unsigned int u32;

using f32x4 = __attribute__((ext_vector_type(4))) float;
using bf16x8 = __attribute__((ext_vector_type(8))) __bf16;

// ---------- constants ----------
#define HN 2048
#define KVD 512
#define TOKENS 2048          // B*T
#define N1 3712              // GEMM1 N (3648 padded to 29*128)
#define K2W 576              // GEMM2 K
#define N2 7168              // GEMM2 N: w(2048) a(2048) g(2048) v(512) k(512)

// ---------- workspace layout (bytes) — lifetime-aliased ----------
#define OFF_Y1   0ull                    // bf16 [2048][3712] (dead after prep_rec)
#define OFF_OO   0ull                    // f32 [2048][2048] (after Y1 dead)
#define OFF_XG   16777216ull
#define OFF_Y2   30408704ull             // f32 [2048][7168]
#define OFF_OUTR 30408704ull             // after Y2 dead
#define OFF_BT1  89128960ull
#define OFF_XB   104333312ull
#define OFF_W2T  89128960ull
#define OFF_X2   97386496ull
#define OFF_OT   89128960ull
#define OFF_DEC  129499136ull
#define OFF_VV   163053568ull
#define OFF_PAB  213385216ull            // u32 [2048][2048]: bf16(A) | bf16(B)<<16
#define OFF_PKR  230162432ull            // u32 [2048][2048]: bf16(K) | bf16(R)<<16
#define OFF_DOT  246939648ull            // f32 [2048][32] = 256KB
#define WS_NEED  247201792ull

// ---------- helpers ----------
__device__ __forceinline__ u16 f2bf(float f) {
    u32 u = __float_as_uint(f);
    u32 r = u + 0x7fffu + ((u >> 16) & 1u);
    return (u16)(r >> 16);
}
__device__ __forceinline__ float bf2f(u16 b) {
    return __uint_as_float(((u32)b) << 16);
}
__device__ __forceinline__ float sigm(float x) { return 1.f / (1.f + expf(-x)); }
__device__ __forceinline__ float wsum(float v) {
#pragma unroll
    for (int m = 32; m > 0; m >>= 1) v += __shfl_xor(v, m, 64);
    return v;
}
// sum across each 16-lane DPP row via row_ror 1,2,4,8; result in all lanes of the row
__device__ __forceinline__ float rowsum16(float v) {
    float t;
    t = __uint_as_float(__builtin_amdgcn_update_dpp(0, __float_as_uint(v), 0x121, 0xf, 0xf, true));
    v += t;
    t = __uint_as_float(__builtin_amdgcn_update_dpp(0, __float_as_uint(v), 0x122, 0xf, 0xf, true));
    v += t;
    t = __uint_as_float(__builtin_amdgcn_update_dpp(0, __float_as_uint(v), 0x124, 0xf, 0xf, true));
    v += t;
    t = __uint_as_float(__builtin_amdgcn_update_dpp(0, __float_as_uint(v), 0x128, 0xf, 0xf, true));
    v += t;
    return v;
}

typedef __attribute__((address_space(1))) const void glob_t;
typedef __attribute__((address_space(3))) void lds_t;
__device__ __forceinline__ void gload_lds16(const void* g, void* l) {
    __builtin_amdgcn_global_load_lds((glob_t*)g, (lds_t*)l, 16, 0, 0);
}

// inline-asm LDS readers with literal offset (burst-issued, order preserved)
template<int OFF>
__device__ __forceinline__ float4 ds_read128(u32 a) {
    float4 r;
    asm volatile("ds_read_b128 %0, %1 offset:%2" : "=v"(r) : "v"(a), "i"(OFF));
    return r;
}
template<int OFF>
__device__ __forceinline__ uint4 ds_read128u(u32 a) {
    uint4 r;
    asm volatile("ds_read_b128 %0, %1 offset:%2" : "=v"(r) : "v"(a), "i"(OFF));
    return r;
}
template<int OFF>
__device__ __forceinline__ float ds_read32(u32 a) {
    float r;
    asm volatile("ds_read_b32 %0, %1 offset:%2" : "=v"(r) : "v"(a), "i"(OFF));
    return r;
}

// ---------- weight prep: tiled transposes (coalesced read AND write) ----------
__global__ __launch_bounds__(256) void k_prep_bt1(const float* __restrict__ wavgk1,
                                                  const float* __restrict__ RKV,
                                                  u16* __restrict__ BT1) {
    __shared__ float tile[64][65];
    const int bn = blockIdx.x >> 5;        // 0..57
    const int bk = blockIdx.x & 31;        // 0..31
    const int n0 = bn << 6, k0 = bk << 6;
    const int c = threadIdx.x & 63, q = threadIdx.x >> 6;
#pragma unroll
    for (int i = 0; i < 16; ++i) {
        const int r = (q << 4) + i;
        float v = 0.f;
        if (bn < 9)       v = wavgk1[(size_t)(k0 + r) * 576 + n0 + c];
        else if (bn < 57) v = RKV[(size_t)(k0 + r) * 3072 + (n0 + c - 576)];
        tile[r][c] = v;
    }
    __syncthreads();
#pragma unroll
    for (int i = 0; i < 16; ++i) {
        const int rw = (q << 4) + i;
        BT1[(size_t)(n0 + rw) * 2048 + k0 + c] = f2bf(tile[c][rw]);
    }
}

// W2T[n][c] = blockdiag src[c][n]; 64x64 tiles, both sides coalesced.
__global__ __launch_bounds__(256) void k_prep_w2t(const float* __restrict__ w2, const float* __restrict__ a2,
                                                  const float* __restrict__ g2, const float* __restrict__ v2,
                                                  const float* __restrict__ k2, u16* __restrict__ W2T) {
    __shared__ float tile[64][65];
    const int bx = blockIdx.x;
    const int bn = bx / 9, bc = bx - bn * 9;
    const int n0 = bn << 6, c0 = bc << 6;
    const int cc = threadIdx.x & 63, q = threadIdx.x >> 6;
#pragma unroll
    for (int i = 0; i < 16; ++i) {
        const int r = (q << 4) + i;        // c-offset within tile
        const int c = c0 + r;
        const int n = n0 + cc;
        float v = 0.f;
        if (n0 < 2048)      { if (c < 96)              v = w2[(size_t)c * 2048 + n]; }
        else if (n0 < 4096) { if (c >= 96 && c < 192)  v = a2[(size_t)(c - 96) * 2048 + (n - 2048)]; }
        else if (n0 < 6144) { if (c >= 192 && c < 448) v = g2[(size_t)(c - 192) * 2048 + (n - 4096)]; }
        else if (n0 < 6656) { if (c >= 448 && c < 512) v = v2[(size_t)(c - 448) * 512 + (n - 6144)]; }
        else                { if (c >= 512)            v = k2[(size_t)(c - 512) * 512 + (n - 6656)]; }
        tile[r][cc] = v;
    }
    __syncthreads();
#pragma unroll
    for (int i = 0; i < 16; ++i) {
        const int rw = (q << 4) + i;       // n-offset within tile
        W2T[(size_t)(n0 + rw) * 576 + c0 + cc] = f2bf(tile[cc][rw]);
    }
}

// OT[n][k] = O[k][n], 2048x2048, 64x64 tiles
__global__ __launch_bounds__(256) void k_prep_ot(const float* __restrict__ O, u16* __restrict__ OT) {
    __shared__ float tile[64][65];
    const int bn = blockIdx.x >> 5, bk = blockIdx.x & 31;
    const int n0 = bn << 6, k0 = bk << 6;
    const int c = threadIdx.x & 63, q = threadIdx.x >> 6;
#pragma unroll
    for (int i = 0; i < 16; ++i) {
        const int r = (q << 4) + i;
        tile[r][c] = O[(size_t)(k0 + r) * 2048 + n0 + c];
    }
    __syncthreads();
#pragma unroll
    for (int i = 0; i < 16; ++i) {
        const int rw = (q << 4) + i;
        OT[(size_t)(n0 + rw) * 2048 + k0 + c] = f2bf(tile[c][rw]);
    }
}

// ---------- rmsnorm(x_in, ln1) -> bf16 ----------
__global__ __launch_bounds__(256) void k_rms1(const float* __restrict__ X,
                                              const float* __restrict__ ln1,
                                              u16* __restrict__ XB) {
    const int t = blockIdx.x, tid = threadIdx.x;
    const float* row = X + ((size_t)t << 11);
    float4 v0 = *(const float4*)(row + tid * 8);
    float4 v1 = *(const float4*)(row + tid * 8 + 4);
    float ss = v0.x*v0.x + v0.y*v0.y + v0.z*v0.z + v0.w*v0.w
             + v1.x*v1.x + v1.y*v1.y + v1.z*v1.z + v1.w*v1.w;
    ss = wsum(ss);
    __shared__ float red[4];
    if ((tid & 63) == 0) red[tid >> 6] = ss;
    __syncthreads();
    float scale = rsqrtf((red[0] + red[1] + red[2] + red[3]) * (1.f / 2048.f) + 1e-6f);
    float4 w0_ = *(const float4*)(ln1 + tid * 8);
    float4 w1_ = *(const float4*)(ln1 + tid * 8 + 4);
    u16* o = XB + ((size_t)t << 11) + tid * 8;
    o[0] = f2bf(v0.x * scale * w0_.x); o[1] = f2bf(v0.y * scale * w0_.y);
    o[2] = f2bf(v0.z * scale * w0_.z); o[3] = f2bf(v0.w * scale * w0_.w);
    o[4] = f2bf(v1.x * scale * w1_.x); o[5] = f2bf(v1.y * scale * w1_.y);
    o[6] = f2bf(v1.z * scale * w1_.z); o[7] = f2bf(v1.w * scale * w1_.w);
}

// ---------- BK=64 bf16 MFMA GEMM, f32 C (half the barriers of BK=32) ----------
// Tile [128 rows][64 k] u16 = 16KB/matrix. Row = 8 chunks of 16B; chunk swizzle
// key = row&7 on BOTH sides: staging pre-swizzles the GLOBAL chunk
// (lk = ((l&7)^((l>>3)&7))<<3; staged row rt = 32rr+8w+(l>>3), rt&7=(l>>3)&7),
// reads XOR the logical chunk (s*4+(l>>4)) with frow&7 = l&7. Uniform 8-lane
// per chunk -> conflict-free minimum cycles.
__global__ __launch_bounds__(256) void k_gemm(const u16* __restrict__ A,
                                              const u16* __restrict__ Bt,
                                              float* __restrict__ C,
                                              int M, int N, int K) {
    __shared__ __align__(16) u16 tA[8192];
    __shared__ __align__(16) u16 tB[8192];
    const int tid = threadIdx.x;
    const int w = tid >> 6, l = tid & 63;
    const int bm = blockIdx.x << 7, bn = blockIdx.y << 7;
    const int wm = (w >> 1) << 6, wn = (w & 1) << 6;
    const int srow = (w << 3) + (l >> 3);                 // row within 32-row round
    const int lk = (((l & 7) ^ ((l >> 3) & 7)) << 3);     // pre-swizzled global chunk
    const int frow = l & 15;
    f32x4 acc[4][4] = {};
    for (int kt = 0; kt < K; kt += 64) {
#pragma unroll
        for (int rr = 0; rr < 4; ++rr) {
            gload_lds16(A + (size_t)(bm + (rr << 5) + srow) * K + kt + lk,
                        &tA[(rr << 11) + (w << 9)]);
            gload_lds16(Bt + (size_t)(bn + (rr << 5) + srow) * K + kt + lk,
                        &tB[(rr << 11) + (w << 9)]);
        }
        __syncthreads();
#pragma unroll
        for (int s = 0; s < 2; ++s) {
            const int koff = ((((s << 2) + (l >> 4)) ^ (l & 7)) << 3);
            bf16x8 av[4], bv[4];
#pragma unroll
            for (int i = 0; i < 4; ++i) {
                av[i] = *(const bf16x8*)&tA[((wm + (i << 4) + frow) << 6) + koff];
                bv[i] = *(const bf16x8*)&tB[((wn + (i << 4) + frow) << 6) + koff];
            }
#pragma unroll
            for (int i = 0; i < 4; ++i)
#pragma unroll
                for (int j = 0; j < 4; ++j)
                    acc[i][j] = __builtin_amdgcn_mfma_f32_16x16x32_bf16(av[i], bv[j], acc[i][j], 0, 0, 0);
        }
        __syncthreads();
    }
    const int crow = bm + wm + ((l >> 4) << 2);
    const int ccol = bn + wn + (l & 15);
#pragma unroll
    for (int i = 0; i < 4; ++i)
#pragma unroll
        for (int j = 0; j < 4; ++j)
#pragma unroll
            for (int jj = 0; jj < 4; ++jj)
                C[(size_t)(crow + (i << 4) + jj) * N + ccol + (j << 4)] = acc[i][j][jj];
}

// ---------- same BK=64 GEMM, bf16 C output (for Y1) ----------
__global__ __launch_bounds__(256) void k_gemmb(const u16* __restrict__ A,
                                               const u16* __restrict__ Bt,
                                               u16* __restrict__ C,
                                               int M, int N, int K) {
    __shared__ __align__(16) u16 tA[8192];
    __shared__ __align__(16) u16 tB[8192];
    const int tid = threadIdx.x;
    const int w = tid >> 6, l = tid & 63;
    const int bm = blockIdx.x << 7, bn = blockIdx.y << 7;
    const int wm = (w >> 1) << 6, wn = (w & 1) << 6;
    const int srow = (w << 3) + (l >> 3);
    const int lk = (((l & 7) ^ ((l >> 3) & 7)) << 3);
    const int frow = l & 15;
    f32x4 acc[4][4] = {};
    for (int kt = 0; kt < K; kt += 64) {
#pragma unroll
        for (int rr = 0; rr < 4; ++rr) {
            gload_lds16(A + (size_t)(bm + (rr << 5) + srow) * K + kt + lk,
                        &tA[(rr << 11) + (w << 9)]);
            gload_lds16(Bt + (size_t)(bn + (rr << 5) + srow) * K + kt + lk,
                        &tB[(rr << 11) + (w << 9)]);
        }
        __syncthreads();
#pragma unroll
        for (int s = 0; s < 2; ++s) {
            const int koff = ((((s << 2) + (l >> 4)) ^ (l & 7)) << 3);
            bf16x8 av[4], bv[4];
#pragma unroll
            for (int i = 0; i < 4; ++i) {
                av[i] = *(const bf16x8*)&tA[((wm + (i << 4) + frow) << 6) + koff];
                bv[i] = *(const bf16x8*)&tB[((wn + (i << 4) + frow) << 6) + koff];
            }
#pragma unroll
            for (int i = 0; i < 4; ++i)
#pragma unroll
                for (int j = 0; j < 4; ++j)
                    acc[i][j] = __builtin_amdgcn_mfma_f32_16x16x32_bf16(av[i], bv[j], acc[i][j], 0, 0, 0);
        }
        __syncthreads();
    }
    const int crow = bm + wm + ((l >> 4) << 2);
    const int ccol = bn + wn + (l & 15);
#pragma unroll
    for (int i = 0; i < 4; ++i)
#pragma unroll
        for (int j = 0; j < 4; ++j)
#pragma unroll
            for (int jj = 0; jj < 4; ++jj)
                C[(size_t)(crow + (i << 4) + jj) * N + ccol + (j << 4)] = f2bf(acc[i][j][jj]);
}

// ---------- GEMM2: block-diagonal W2T, per-segment true K (BK=32, proven) ----------
__global__ __launch_bounds__(256) void k_gemm2(const u16* __restrict__ A,
                                               const u16* __restrict__ Bt,
                                               float* __restrict__ C) {
    __shared__ __align__(16) u16 tA[4096];
    __shared__ __align__(16) u16 tB[4096];
    const int tid = threadIdx.x;
    const int w = tid >> 6, l = tid & 63;
    const int by = blockIdx.y;
    int c0, K;
    if (by < 16)      { c0 = 0;   K = 96; }
    else if (by < 32) { c0 = 96;  K = 96; }
    else if (by < 48) { c0 = 192; K = 256; }
    else if (by < 52) { c0 = 448; K = 64; }
    else              { c0 = 512; K = 64; }
    const int n0 = by << 7;
    const int bm = blockIdx.x << 7;
    const int wm = (w >> 1) << 6, wn = (w & 1) << 6;
    const int lrow = l >> 2;
    const int lk = (((l & 3) ^ ((l >> 3) & 3)) << 3);
    f32x4 acc[4][4] = {};
    const size_t rA0 = (size_t)(bm + (w << 4) + lrow) * 576 + c0;
    const size_t rA1 = (size_t)(bm + ((w + 4) << 4) + lrow) * 576 + c0;
    const size_t rB0 = (size_t)(n0 + (w << 4) + lrow) * 576 + c0;
    const size_t rB1 = (size_t)(n0 + ((w + 4) << 4) + lrow) * 576 + c0;
    const int frow = l & 15;
    const int koff = (((l >> 4) ^ ((l >> 1) & 3)) << 3);
    for (int kt = 0; kt < K; kt += 32) {
        gload_lds16(A + rA0 + kt + lk, &tA[w << 9]);
        gload_lds16(A + rA1 + kt + lk, &tA[2048 + (w << 9)]);
        gload_lds16(Bt + rB0 + kt + lk, &tB[w << 9]);
        gload_lds16(Bt + rB1 + kt + lk, &tB[2048 + (w << 9)]);
        __syncthreads();
        bf16x8 av[4], bv[4];
#pragma unroll
        for (int i = 0; i < 4; ++i) {
            av[i] = *(const bf16x8*)&tA[((wm + (i << 4) + frow) << 5) + koff];
            bv[i] = *(const bf16x8*)&tB[((wn + (i << 4) + frow) << 5) + koff];
        }
#pragma unroll
        for (int i = 0; i < 4; ++i)
#pragma unroll
            for (int j = 0; j < 4; ++j)
                acc[i][j] = __builtin_amdgcn_mfma_f32_16x16x32_bf16(av[i], bv[j], acc[i][j], 0, 0, 0);
        __syncthreads();
    }
    const int crow = bm + wm + ((l >> 4) << 2);
    const int ccol = n0 + wn + (l & 15);
#pragma unroll
    for (int i = 0; i < 4; ++i)
#pragma unroll
        for (int j = 0; j < 4; ++j)
#pragma unroll
            for (int jj = 0; jj < 4; ++jj)
                C[(size_t)(crow + (i << 4) + jj) * N2 + ccol + (j << 4)] = acc[i][j][jj];
}

// ---------- Y1(bf16) -> X2 (bf16): [tanh(xw) | xa | sigmoid(xg) | xv | xk] ----------
__global__ __launch_bounds__(256) void k_prep_x2(const u16* __restrict__ Y1, u16* __restrict__ X2) {
    int idx = blockIdx.x * 256 + threadIdx.x;   // t*576 + c
    int t = idx / 576, c = idx - t * 576;
    const u16* y1 = Y1 + (size_t)t * N1;
    float v;
    if (c < 96)       v = tanhf(bf2f(y1[c]));
    else if (c < 192) v = bf2f(y1[c]);
    else if (c < 448) v = sigm(bf2f(y1[c + 64]));
    else if (c < 512) v = bf2f(y1[c - 256]);
    else              v = bf2f(y1[c]);
    X2[idx] = f2bf(v);
}

// ---------- per-token recurrence prep (+ packed coeffs + head-dot) ----------
__global__ __launch_bounds__(256) void k_prep_rec(
    const u16* __restrict__ Y1, const float* __restrict__ Y2,
    const float* __restrict__ v_first, const float* __restrict__ k_first,
    const float* __restrict__ cosb, const float* __restrict__ sinb,
    const float* __restrict__ w0, const float* __restrict__ a0,
    const float* __restrict__ v0b, const float* __restrict__ k0b,
    const float* __restrict__ R_bias, const float* __restrict__ K_bias,
    const float* __restrict__ V_bias, const float* __restrict__ ln_r,
    const float* __restrict__ ln_k, const float* __restrict__ r_k,
    float* __restrict__ DEC, float* __restrict__ VV,
    u32* __restrict__ PAB, u32* __restrict__ PKR, float* __restrict__ DOT) {
    const int t = blockIdx.x, tid = threadIdx.x;
    const int ww = tid >> 6, lane = tid & 63;
    const u16* y1 = Y1 + (size_t)t * N1;
    const float* y2 = Y2 + (size_t)t * N2;
    const float cs = cosb[t * 64 + lane];
    const float sn = sinb[t * 64 + lane];
    const float sign = lane < 32 ? -1.f : 1.f;
    const size_t tb = (size_t)t << 11;
    __shared__ float kkv[512], vkv[512];
    float rsave[8];
    // r: per-head rmsnorm + rope
#pragma unroll
    for (int i = 0; i < 8; ++i) {
        int h = ww * 8 + i, c = h * 64 + lane;
        float rr = bf2f(y1[576 + c]) + R_bias[c];
        float ssq = wsum(rr * rr);
        float rn = ln_r[lane] * rr * rsqrtf(ssq * (1.f / 64.f) + 1e-6f);
        float rot = sign * __shfl(rn, lane ^ 32, 64);
        rsave[i] = rn * cs + rot * sn;
    }
    // k,v kv-heads: rmsnorm+rope+mix
#pragma unroll
    for (int i = 0; i < 2; ++i) {
        int j = ww * 2 + i, c = j * 64 + lane;
        float kr = bf2f(y1[2624 + c]) + K_bias[c];
        float ssq = wsum(kr * kr);
        float kn = ln_k[lane] * kr * rsqrtf(ssq * (1.f / 64.f) + 1e-6f);
        float rot = sign * __shfl(kn, lane ^ 32, 64);
        float krope = kn * cs + rot * sn;
        float ksig = sigm(y2[6656 + c] + k0b[c]);
        kkv[c] = krope + (k_first[(size_t)t * 512 + c] - krope) * ksig;
        float vr = bf2f(y1[3136 + c]) + V_bias[c];
        float vsig = sigm(y2[6144 + c] + v0b[c]);
        vkv[c] = vr + (v_first[(size_t)t * 512 + c] - vr) * vsig;
    }
    __syncthreads();
    // per-head final recurrence operands
#pragma unroll
    for (int i = 0; i < 8; ++i) {
        int h = ww * 8 + i, c = h * 64 + lane;
        int ckv = (h >> 2) * 64 + lane;
        float kb = kkv[ckv], vb = vkv[ckv];
        float a_ = sigm(y2[2048 + c] + a0[c]);
        float wr = y2[c] + w0[c];
        float z = -wr;
        float sp = fmaxf(z, 0.f) + log1pf(expf(-fabsf(z)));
        float w_log = -sp - 0.5f;
        float ssq = wsum(kb * kb);
        float kk = kb / fmaxf(sqrtf(ssq), 1e-12f);
        const float kr2 = kb * (1.f - w_log + a_);
        const float rrv = rsave[i];
        DEC[tb + c] = expf(-expf(w_log));
        VV[tb + c] = vb;
        PAB[tb + c] = (u32)f2bf(-kk) | ((u32)f2bf(kk * a_) << 16);
        PKR[tb + c] = (u32)f2bf(kr2) | ((u32)f2bf(rrv) << 16);
        const float dsum = wsum(rrv * kr2 * r_k[c]);
        if (lane == 0) DOT[((size_t)t << 5) + h] = dsum;
    }
}

// ---------- sequential recurrence: homogeneous-b128, 2 groups in flight (r24 best) ----------
__global__ __launch_bounds__(256, 1) void k_recv17(
    const float* __restrict__ DECp, const u32* __restrict__ PABp,
    const u32* __restrict__ PKRp, const float* __restrict__ VVp,
    const float* __restrict__ S0, float* __restrict__ OO) {
    __shared__ __align__(16) float cbuf[2][4][32][64];   // 64 KB
    const int tid = threadIdx.x;
    const int wl = tid >> 6;           // wave 0..3
    const int lane = tid & 63;
    const int vl = lane >> 4;          // DPP row 0..3
    const int kq = lane & 15;          // k-quad 0..15
    const int quarter = blockIdx.x & 3;
    const int ch = blockIdx.x >> 2;          // chain 0..63 (b*32+h)
    const int vcol = (quarter << 4) + (wl << 2) + vl;   // this row's v-column
    const size_t cb = ((size_t)(ch >> 5) * 1024 * 2048) + ((size_t)(ch & 31) << 6);

    const float* s0 = S0 + ((size_t)ch << 12);
    float L0 = s0[((kq << 2) + 0) * 64 + vcol];
    float L1 = s0[((kq << 2) + 1) * 64 + vcol];
    float L2 = s0[((kq << 2) + 2) * 64 + vcol];
    float L3 = s0[((kq << 2) + 3) * 64 + vcol];

    const int trow = (wl << 2) + vl;   // 0..15; rows trow and trow+16 staged

#define STG(B, T0)                                                             \
    {                                                                          \
        const size_t g0 = cb + (size_t)((T0) + trow) * 2048 + (kq << 2);       \
        const size_t g1 = cb + (size_t)((T0) + 16 + trow) * 2048 + (kq << 2);  \
        float* lb = &cbuf[B][0][0][0] + (wl << 8);                             \
        gload_lds16(DECp + g0, lb);                                            \
        gload_lds16(DECp + g1, lb + 1024);                                     \
        gload_lds16(PABp + g0, lb + 2048);                                     \
        gload_lds16(PABp + g1, lb + 3072);                                     \
        gload_lds16(PKRp + g0, lb + 4096);                                     \
        gload_lds16(PKRp + g1, lb + 5120);                                     \
        gload_lds16(VVp + g0, lb + 6144);                                      \
        gload_lds16(VVp + g1, lb + 7168);                                      \
    }

    const u32 base0 = (u32)(size_t)(void*)&cbuf[0][0][0][0];
    const u32 aA0 = base0 + (kq << 4);             // coefficient chunk for lane
    const u32 aV0 = base0 + 24576 + (vcol << 2);   // V broadcast slot

    float4 cDa0, cDa1, cDb0, cDb1;
    uint4 cPAa0, cPAa1, cPAb0, cPAb1, cPKa0, cPKa1, cPKb0, cPKb1;
    float cV[32];

#define LD2(S_, G)                                                             \
    cD##S_##0 = ds_read128<(G) * 512>(aAb);                                    \
    cD##S_##1 = ds_read128<(G) * 512 + 256>(aAb);                              \
    cPA##S_##0 = ds_read128u<8192 + (G) * 512>(aAb);                           \
    cPA##S_##1 = ds_read128u<8192 + (G) * 512 + 256>(aAb);                     \
    cPK##S_##0 = ds_read128u<16384 + (G) * 512>(aAb);                          \
    cPK##S_##1 = ds_read128u<16384 + (G) * 512 + 256>(aAb);

#define VRD(J) cV[J] = ds_read32<(J) * 256>(aVb);
#define VRD8(J) VRD(J) VRD((J)+1) VRD((J)+2) VRD((J)+3) VRD((J)+4) VRD((J)+5) VRD((J)+6) VRD((J)+7)

#define WAIT6 asm volatile("s_waitcnt lgkmcnt(6)" ::: "memory");               \
    __builtin_amdgcn_sched_barrier(0);
#define WAIT0 asm volatile("s_waitcnt lgkmcnt(0)" ::: "memory");               \
    __builtin_amdgcn_sched_barrier(0);

#define UNP_LO(u) __uint_as_float((u) << 16)
#define UNP_HI(u) __uint_as_float((u) & 0xffff0000u)

#define STEP1(D4, pa, pk, Vsj, T)                                              \
    {                                                                          \
        const float Ax = UNP_LO(pa.x), Ay = UNP_LO(pa.y),                      \
                    Az = UNP_LO(pa.z), Aw = UNP_LO(pa.w);                      \
        const float Bx = UNP_HI(pa.x), By = UNP_HI(pa.y),                      \
                    Bz = UNP_HI(pa.z), Bw = UNP_HI(pa.w);                      \
        const float Kx = UNP_LO(pk.x), Ky = UNP_LO(pk.y),                      \
                    Kz = UNP_LO(pk.z), Kw = UNP_LO(pk.w);                      \
        const float Rx = UNP_HI(pk.x), Ry = UNP_HI(pk.y),                      \
                    Rz = UNP_HI(pk.z), Rw = UNP_HI(pk.w);                      \
        float sp = fmaf(L1, Ay, L0 * Ax) + fmaf(L3, Aw, L2 * Az);              \
        const float sa = rowsum16(sp);                                         \
        L0 = fmaf(Bx, sa, fmaf(Kx, Vsj, L0 * D4.x));                           \
        L1 = fmaf(By, sa, fmaf(Ky, Vsj, L1 * D4.y));                           \
        L2 = fmaf(Bz, sa, fmaf(Kz, Vsj, L2 * D4.z));                           \
        L3 = fmaf(Bw, sa, fmaf(Kw, Vsj, L3 * D4.w));                           \
        float op = fmaf(L1, Ry, L0 * Rx) + fmaf(L3, Rw, L2 * Rz);              \
        const float o = rowsum16(op);                                          \
        if (kq == 0) OO[cb + ((size_t)(T) << 11) + vcol] = o;                  \
    }

#define STEP2(S_, G)                                                           \
    STEP1(cD##S_##0, cPA##S_##0, cPK##S_##0, cV[2 * (G)], tbase + 2 * (G));    \
    STEP1(cD##S_##1, cPA##S_##1, cPK##S_##1, cV[2 * (G) + 1], tbase + 2 * (G) + 1);

#define PAIR(G)                                                                \
    LD2(b, (G) + 1) WAIT6 STEP2(a, G) LD2(a, (G) + 2) WAIT6 STEP2(b, (G) + 1)

    STG(0, 0);
    __syncthreads();

    for (int c = 0; c < 32; ++c) {
        const int b = c & 1;
        if (c < 31) STG(b ^ 1, (c + 1) << 5);      // async prefetch next chunk (vmcnt)
        const u32 aAb = aA0 + b * 32768;
        const u32 aVb = aV0 + b * 32768;
        const int tbase = c << 5;
        VRD8(0) VRD8(8) VRD8(16) VRD8(24)          // all 32 V values (b32 burst)
        WAIT0                                      // V in regs; lgkm queue empty
        LD2(a, 0)
        PAIR(0) PAIR(2) PAIR(4) PAIR(6) PAIR(8) PAIR(10) PAIR(12)
        LD2(b, 15) WAIT6 STEP2(a, 14) WAIT0 STEP2(b, 15)
        __syncthreads();   // drains staging vmcnt (1/32 steps); flips buffers
    }
#undef PAIR
#undef STEP2
#undef STEP1
#undef UNP_LO
#undef UNP_HI
#undef WAIT0
#undef WAIT6
#undef VRD8
#undef VRD
#undef LD2
#undef STG
}

// ---------- gate: pure elementwise (dot precomputed in prep_rec) ----------
__global__ __launch_bounds__(256) void k_gate(
    const float* __restrict__ OOp, const float* __restrict__ VVp,
    const float* __restrict__ DOT, const float* __restrict__ Y2,
    u16* __restrict__ XG) {
    const int t = blockIdx.x, tid = threadIdx.x;
    const size_t tb = (size_t)t << 11;
    const int c0 = tid << 3;
    const float dot = DOT[((size_t)t << 5) + (tid >> 3)];
    float4 o0 = *(const float4*)(OOp + tb + c0);
    float4 o1 = *(const float4*)(OOp + tb + c0 + 4);
    float4 v0 = *(const float4*)(VVp + tb + c0);
    float4 v1 = *(const float4*)(VVp + tb + c0 + 4);
    const float* g = Y2 + (size_t)t * N2 + 4096 + c0;
    float4 g0 = *(const float4*)(g);
    float4 g1 = *(const float4*)(g + 4);
    const float x0 = fmaf(o0.x, 0.125f, dot * v0.x) * g0.x;
    const float x1 = fmaf(o0.y, 0.125f, dot * v0.y) * g0.y;
    const float x2 = fmaf(o0.z, 0.125f, dot * v0.z) * g0.z;
    const float x3 = fmaf(o0.w, 0.125f, dot * v0.w) * g0.w;
    const float x4 = fmaf(o1.x, 0.125f, dot * v1.x) * g1.x;
    const float x5 = fmaf(o1.y, 0.125f, dot * v1.y) * g1.y;
    const float x6 = fmaf(o1.z, 0.125f, dot * v1.z) * g1.z;
    const float x7 = fmaf(o1.w, 0.125f, dot * v1.w) * g1.w;
    uint4 pk;
    pk.x = (u32)f2bf(x0) | ((u32)f2bf(x1) << 16);
    pk.y = (u32)f2bf(x2) | ((u32)f2bf(x3) << 16);
    pk.z = (u32)f2bf(x4) | ((u32)f2bf(x5) << 16);
    pk.w = (u32)f2bf(x6) | ((u32)f2bf(x7) << 16);
    *(uint4*)(XG + tb + c0) = pk;
}

// ---------- final residual + rmsnorm ----------
__global__ __launch_bounds__(256) void k_final(const float* __restrict__ x_in,
                                               const float* __restrict__ OUTR,
                                               const float* __restrict__ ln2,
                                               float* __restrict__ out) {
    const int t = blockIdx.x, tid = threadIdx.x;
    const float* xr = x_in + ((size_t)t << 11);
    const float* orow = OUTR + ((size_t)t << 11);
    float4 a0 = *(const float4*)(xr + tid * 8);
    float4 a1 = *(const float4*)(xr + tid * 8 + 4);
    float4 b0 = *(const float4*)(orow + tid * 8);
    float4 b1 = *(const float4*)(orow + tid * 8 + 4);
    float v[8] = {a0.x + b0.x, a0.y + b0.y, a0.z + b0.z, a0.w + b0.w,
                  a1.x + b1.x, a1.y + b1.y, a1.z + b1.z, a1.w + b1.w};
    float ss = 0.f;
#pragma unroll
    for (int i = 0; i < 8; ++i) ss = fmaf(v[i], v[i], ss);
    ss = wsum(ss);
    __shared__ float red[4];
    if ((tid & 63) == 0) red[tid >> 6] = ss;
    __syncthreads();
    float scale = rsqrtf((red[0] + red[1] + red[2] + red[3]) * (1.f / 2048.f) + 1e-6f);
    float* o = out + ((size_t)t << 11) + tid * 8;
#pragma unroll
    for (int i = 0; i < 8; ++i) o[i] = ln2[tid * 8 + i] * v[i] * scale;
}

extern "C" void kernel_launch(void* const* d_in, const int* in_sizes, int n_in,
                              void* d_out, int out_size, void* d_ws, size_t ws_size,
                              hipStream_t stream) {
    const float* x_in    = (const float*)d_in[0];
    const float* v_first = (const float*)d_in[1];
    const float* k_first = (const float*)d_in[2];
    const float* state   = (const float*)d_in[3];
    const float* cosb    = (const float*)d_in[4];
    const float* sinb    = (const float*)d_in[5];
    const float* wavgk1  = (const float*)d_in[6];
    const float* w0      = (const float*)d_in[7];
    const float* w2      = (const float*)d_in[8];
    const float* a0      = (const float*)d_in[9];
    const float* a2      = (const float*)d_in[10];
    const float* v0      = (const float*)d_in[11];
    const float* v2      = (const float*)d_in[12];
    const float* g2      = (const float*)d_in[13];
    const float* k0      = (const float*)d_in[14];
    const float* k2      = (const float*)d_in[15];
    const float* r_k     = (const float*)d_in[16];
    const float* RKV     = (const float*)d_in[17];
    const float* O       = (const float*)d_in[18];
    const float* R_bias  = (const float*)d_in[19];
    const float* K_bias  = (const float*)d_in[20];
    const float* V_bias  = (const float*)d_in[21];
    const float* ln_r    = (const float*)d_in[22];
    const float* ln_k    = (const float*)d_in[23];
    const float* ln1     = (const float*)d_in[24];
    const float* ln2     = (const float*)d_in[25];

    if (ws_size < WS_NEED) return;  // need 247.2 MB (fits 256 MiB)

    char* ws = (char*)d_ws;
    u16*   BT1  = (u16*)(ws + OFF_BT1);
    u16*   W2T  = (u16*)(ws + OFF_W2T);
    u16*   OT   = (u16*)(ws + OFF_OT);
    u16*   XB   = (u16*)(ws + OFF_XB);
    u16*   Y1   = (u16*)(ws + OFF_Y1);
    u16*   X2   = (u16*)(ws + OFF_X2);
    float* Y2   = (float*)(ws + OFF_Y2);
    float* DEC  = (float*)(ws + OFF_DEC);
    float* VV   = (float*)(ws + OFF_VV);
    u32*   PAB  = (u32*)(ws + OFF_PAB);
    u32*   PKR  = (u32*)(ws + OFF_PKR);
    float* DOT  = (float*)(ws + OFF_DOT);
    float* OO   = (float*)(ws + OFF_OO);
    u16*   XG   = (u16*)(ws + OFF_XG);
    float* OUTR = (float*)(ws + OFF_OUTR);

    // P0: BT1 + XB (region C)
    k_prep_bt1<<<1856, 256, 0, stream>>>(wavgk1, RKV, BT1);
    k_rms1<<<2048, 256, 0, stream>>>(x_in, ln1, XB);
    // P1: GEMM1 -> Y1 (bf16, region A), BK=64
    k_gemmb<<<dim3(16, 29), 256, 0, stream>>>(XB, BT1, Y1, 2048, N1, 2048);
    // P2: W2T + X2 overwrite BT1/XB (dead); GEMM2 (block-diagonal) -> Y2 (region B)
    k_prep_w2t<<<1008, 256, 0, stream>>>(w2, a2, g2, v2, k2, W2T);
    k_prep_x2<<<4608, 256, 0, stream>>>(Y1, X2);
    k_gemm2<<<dim3(16, 56), 256, 0, stream>>>(X2, W2T, Y2);
    // P3: recurrence operands + head-dot; Y1 dead after this
    k_prep_rec<<<2048, 256, 0, stream>>>(Y1, Y2, v_first, k_first, cosb, sinb,
                                         w0, a0, v0, k0, R_bias, K_bias, V_bias,
                                         ln_r, ln_k, r_k, DEC, VV, PAB, PKR, DOT);
    // P4: OT overwrites W2T/X2 (dead); recurrence -> OO (in old Y1 space)
    k_prep_ot<<<1024, 256, 0, stream>>>(O, OT);
    k_recv17<<<256, 256, 0, stream>>>(DEC, PAB, PKR, VV, state, OO);
    // P5: gate (elementwise) -> XG; Y2 dead after this
    k_gate<<<2048, 256, 0, stream>>>(OO, VV, DOT, Y2, XG);
    // P6: GEMM3 -> OUTR (in old Y2 space), BK=64; final norm
    k_gemm<<<dim3(16, 16), 256, 0, stream>>>(XG, OT, OUTR, 2048, 2048, 2048);
    k_final<<<2048, 256, 0, stream>>>(x_in, OUTR, ln2, (float*)d_out);
}

// Round 28
// 342.040 us; speedup vs baseline: 1.2185x; 1.0022x over previous
//
#include <hip/hip_runtime.h>

typedef unsigned short u16;
typedef unsigned int u32;

using f32x4 = __attribute__((ext_vector_type(4))) float;
using bf16x8 = __attribute__((ext_vector_type(8))) __bf16;

// ---------- constants ----------
#define HN 2048
#define KVD 512
#define TOKENS 2048          // B*T
#define N1 3712              // GEMM1 N (3648 padded to 29*128)
#define K2W 576              // GEMM2 K
#define N2 7168              // GEMM2 N: w(2048) a(2048) g(2048) v(512) k(512)

// ---------- workspace layout (bytes) — lifetime-aliased ----------
#define OFF_Y1   0ull                    // bf16 [2048][3712] (dead after prep_rec)
#define OFF_OO   0ull                    // bf16 [2048][2048] (after Y1 dead)
#define OFF_XG   16777216ull
#define OFF_Y2   30408704ull             // bf16 [2048][7168] = 29.4MB
#define OFF_OUTR 60817408ull             // f32 [2048][2048] (after Y2 dead; separate to be safe)
#define OFF_BT1  89128960ull
#define OFF_XB   104333312ull
#define OFF_W2T  89128960ull
#define OFF_X2   97386496ull
#define OFF_OT   89128960ull
#define OFF_DEC  129499136ull
#define OFF_VV   163053568ull
#define OFF_PAB  213385216ull            // u32 [2048][2048]: bf16(A) | bf16(B)<<16
#define OFF_PKR  230162432ull            // u32 [2048][2048]: bf16(K) | bf16(R)<<16
#define OFF_DOT  246939648ull            // f32 [2048][32] = 256KB
#define WS_NEED  247201792ull

// ---------- helpers ----------
__device__ __forceinline__ u16 f2bf(float f) {
    u32 u = __float_as_uint(f);
    u32 r = u + 0x7fffu + ((u >> 16) & 1u);
    return (u16)(r >> 16);
}
__device__ __forceinline__ float bf2f(u16 b) {
    return __uint_as_float(((u32)b) << 16);
}
__device__ __forceinline__ float sigm(float x) { return 1.f / (1.f + expf(-x)); }
__device__ __forceinline__ float wsum(float v) {
#pragma unroll
    for (int m = 32; m > 0; m >>= 1) v += __shfl_xor(v, m, 64);
    return v;
}
// sum across each 16-lane DPP row via row_ror 1,2,4,8; result in all lanes of the row
__device__ __forceinline__ float rowsum16(float v) {
    float t;
    t = __uint_as_float(__builtin_amdgcn_update_dpp(0, __float_as_uint(v), 0x121, 0xf, 0xf, true));
    v += t;
    t = __uint_as_float(__builtin_amdgcn_update_dpp(0, __float_as_uint(v), 0x122, 0xf, 0xf, true));
    v += t;
    t = __uint_as_float(__builtin_amdgcn_update_dpp(0, __float_as_uint(v), 0x124, 0xf, 0xf, true));
    v += t;
    t = __uint_as_float(__builtin_amdgcn_update_dpp(0, __float_as_uint(v), 0x128, 0xf, 0xf, true));
    v += t;
    return v;
}

typedef __attribute__((address_space(1))) const void glob_t;
typedef __attribute__((address_space(3))) void lds_t;
__device__ __forceinline__ void gload_lds16(const void* g, void* l) {
    __builtin_amdgcn_global_load_lds((glob_t*)g, (lds_t*)l, 16, 0, 0);
}

// inline-asm LDS readers with literal offset (burst-issued, order preserved)
template<int OFF>
__device__ __forceinline__ float4 ds_read128(u32 a) {
    float4 r;
    asm volatile("ds_read_b128 %0, %1 offset:%2" : "=v"(r) : "v"(a), "i"(OFF));
    return r;
}
template<int OFF>
__device__ __forceinline__ uint4 ds_read128u(u32 a) {
    uint4 r;
    asm volatile("ds_read_b128 %0, %1 offset:%2" : "=v"(r) : "v"(a), "i"(OFF));
    return r;
}
template<int OFF>
__device__ __forceinline__ float ds_read32(u32 a) {
    float r;
    asm volatile("ds_read_b32 %0, %1 offset:%2" : "=v"(r) : "v"(a), "i"(OFF));
    return r;
}

// ---------- weight prep: tiled transposes (coalesced read AND write) ----------
__global__ __launch_bounds__(256) void k_prep_bt1(const float* __restrict__ wavgk1,
                                                  const float* __restrict__ RKV,
                                                  u16* __restrict__ BT1) {
    __shared__ float tile[64][65];
    const int bn = blockIdx.x >> 5;        // 0..57
    const int bk = blockIdx.x & 31;        // 0..31
    const int n0 = bn << 6, k0 = bk << 6;
    const int c = threadIdx.x & 63, q = threadIdx.x >> 6;
#pragma unroll
    for (int i = 0; i < 16; ++i) {
        const int r = (q << 4) + i;
        float v = 0.f;
        if (bn < 9)       v = wavgk1[(size_t)(k0 + r) * 576 + n0 + c];
        else if (bn < 57) v = RKV[(size_t)(k0 + r) * 3072 + (n0 + c - 576)];
        tile[r][c] = v;
    }
    __syncthreads();
#pragma unroll
    for (int i = 0; i < 16; ++i) {
        const int rw = (q << 4) + i;
        BT1[(size_t)(n0 + rw) * 2048 + k0 + c] = f2bf(tile[c][rw]);
    }
}

// W2T[n][c] = blockdiag src[c][n]; 64x64 tiles, both sides coalesced.
__global__ __launch_bounds__(256) void k_prep_w2t(const float* __restrict__ w2, const float* __restrict__ a2,
                                                  const float* __restrict__ g2, const float* __restrict__ v2,
                                                  const float* __restrict__ k2, u16* __restrict__ W2T) {
    __shared__ float tile[64][65];
    const int bx = blockIdx.x;
    const int bn = bx / 9, bc = bx - bn * 9;
    const int n0 = bn << 6, c0 = bc << 6;
    const int cc = threadIdx.x & 63, q = threadIdx.x >> 6;
#pragma unroll
    for (int i = 0; i < 16; ++i) {
        const int r = (q << 4) + i;        // c-offset within tile
        const int c = c0 + r;
        const int n = n0 + cc;
        float v = 0.f;
        if (n0 < 2048)      { if (c < 96)              v = w2[(size_t)c * 2048 + n]; }
        else if (n0 < 4096) { if (c >= 96 && c < 192)  v = a2[(size_t)(c - 96) * 2048 + (n - 2048)]; }
        else if (n0 < 6144) { if (c >= 192 && c < 448) v = g2[(size_t)(c - 192) * 2048 + (n - 4096)]; }
        else if (n0 < 6656) { if (c >= 448 && c < 512) v = v2[(size_t)(c - 448) * 512 + (n - 6144)]; }
        else                { if (c >= 512)            v = k2[(size_t)(c - 512) * 512 + (n - 6656)]; }
        tile[r][cc] = v;
    }
    __syncthreads();
#pragma unroll
    for (int i = 0; i < 16; ++i) {
        const int rw = (q << 4) + i;       // n-offset within tile
        W2T[(size_t)(n0 + rw) * 576 + c0 + cc] = f2bf(tile[cc][rw]);
    }
}

// OT[n][k] = O[k][n], 2048x2048, 64x64 tiles
__global__ __launch_bounds__(256) void k_prep_ot(const float* __restrict__ O, u16* __restrict__ OT) {
    __shared__ float tile[64][65];
    const int bn = blockIdx.x >> 5, bk = blockIdx.x & 31;
    const int n0 = bn << 6, k0 = bk << 6;
    const int c = threadIdx.x & 63, q = threadIdx.x >> 6;
#pragma unroll
    for (int i = 0; i < 16; ++i) {
        const int r = (q << 4) + i;
        tile[r][c] = O[(size_t)(k0 + r) * 2048 + n0 + c];
    }
    __syncthreads();
#pragma unroll
    for (int i = 0; i < 16; ++i) {
        const int rw = (q << 4) + i;
        OT[(size_t)(n0 + rw) * 2048 + k0 + c] = f2bf(tile[c][rw]);
    }
}

// ---------- rmsnorm(x_in, ln1) -> bf16 ----------
__global__ __launch_bounds__(256) void k_rms1(const float* __restrict__ X,
                                              const float* __restrict__ ln1,
                                              u16* __restrict__ XB) {
    const int t = blockIdx.x, tid = threadIdx.x;
    const float* row = X + ((size_t)t << 11);
    float4 v0 = *(const float4*)(row + tid * 8);
    float4 v1 = *(const float4*)(row + tid * 8 + 4);
    float ss = v0.x*v0.x + v0.y*v0.y + v0.z*v0.z + v0.w*v0.w
             + v1.x*v1.x + v1.y*v1.y + v1.z*v1.z + v1.w*v1.w;
    ss = wsum(ss);
    __shared__ float red[4];
    if ((tid & 63) == 0) red[tid >> 6] = ss;
    __syncthreads();
    float scale = rsqrtf((red[0] + red[1] + red[2] + red[3]) * (1.f / 2048.f) + 1e-6f);
    float4 w0_ = *(const float4*)(ln1 + tid * 8);
    float4 w1_ = *(const float4*)(ln1 + tid * 8 + 4);
    u16* o = XB + ((size_t)t << 11) + tid * 8;
    o[0] = f2bf(v0.x * scale * w0_.x); o[1] = f2bf(v0.y * scale * w0_.y);
    o[2] = f2bf(v0.z * scale * w0_.z); o[3] = f2bf(v0.w * scale * w0_.w);
    o[4] = f2bf(v1.x * scale * w1_.x); o[5] = f2bf(v1.y * scale * w1_.y);
    o[6] = f2bf(v1.z * scale * w1_.z); o[7] = f2bf(v1.w * scale * w1_.w);
}

// ---------- BK=64 bf16 MFMA GEMM, f32 C ----------
__global__ __launch_bounds__(256) void k_gemm(const u16* __restrict__ A,
                                              const u16* __restrict__ Bt,
                                              float* __restrict__ C,
                                              int M, int N, int K) {
    __shared__ __align__(16) u16 tA[8192];
    __shared__ __align__(16) u16 tB[8192];
    const int tid = threadIdx.x;
    const int w = tid >> 6, l = tid & 63;
    const int bm = blockIdx.x << 7, bn = blockIdx.y << 7;
    const int wm = (w >> 1) << 6, wn = (w & 1) << 6;
    const int srow = (w << 3) + (l >> 3);                 // row within 32-row round
    const int lk = (((l & 7) ^ ((l >> 3) & 7)) << 3);     // pre-swizzled global chunk
    const int frow = l & 15;
    f32x4 acc[4][4] = {};
    for (int kt = 0; kt < K; kt += 64) {
#pragma unroll
        for (int rr = 0; rr < 4; ++rr) {
            gload_lds16(A + (size_t)(bm + (rr << 5) + srow) * K + kt + lk,
                        &tA[(rr << 11) + (w << 9)]);
            gload_lds16(Bt + (size_t)(bn + (rr << 5) + srow) * K + kt + lk,
                        &tB[(rr << 11) + (w << 9)]);
        }
        __syncthreads();
#pragma unroll
        for (int s = 0; s < 2; ++s) {
            const int koff = ((((s << 2) + (l >> 4)) ^ (l & 7)) << 3);
            bf16x8 av[4], bv[4];
#pragma unroll
            for (int i = 0; i < 4; ++i) {
                av[i] = *(const bf16x8*)&tA[((wm + (i << 4) + frow) << 6) + koff];
                bv[i] = *(const bf16x8*)&tB[((wn + (i << 4) + frow) << 6) + koff];
            }
#pragma unroll
            for (int i = 0; i < 4; ++i)
#pragma unroll
                for (int j = 0; j < 4; ++j)
                    acc[i][j] = __builtin_amdgcn_mfma_f32_16x16x32_bf16(av[i], bv[j], acc[i][j], 0, 0, 0);
        }
        __syncthreads();
    }
    const int crow = bm + wm + ((l >> 4) << 2);
    const int ccol = bn + wn + (l & 15);
#pragma unroll
    for (int i = 0; i < 4; ++i)
#pragma unroll
        for (int j = 0; j < 4; ++j)
#pragma unroll
            for (int jj = 0; jj < 4; ++jj)
                C[(size_t)(crow + (i << 4) + jj) * N + ccol + (j << 4)] = acc[i][j][jj];
}

// ---------- same BK=64 GEMM, bf16 C output (for Y1) ----------
__global__ __launch_bounds__(256) void k_gemmb(const u16* __restrict__ A,
                                               const u16* __restrict__ Bt,
                                               u16* __restrict__ C,
                                               int M, int N, int K) {
    __shared__ __align__(16) u16 tA[8192];
    __shared__ __align__(16) u16 tB[8192];
    const int tid = threadIdx.x;
    const int w = tid >> 6, l = tid & 63;
    const int bm = blockIdx.x << 7, bn = blockIdx.y << 7;
    const int wm = (w >> 1) << 6, wn = (w & 1) << 6;
    const int srow = (w << 3) + (l >> 3);
    const int lk = (((l & 7) ^ ((l >> 3) & 7)) << 3);
    const int frow = l & 15;
    f32x4 acc[4][4] = {};
    for (int kt = 0; kt < K; kt += 64) {
#pragma unroll
        for (int rr = 0; rr < 4; ++rr) {
            gload_lds16(A + (size_t)(bm + (rr << 5) + srow) * K + kt + lk,
                        &tA[(rr << 11) + (w << 9)]);
            gload_lds16(Bt + (size_t)(bn + (rr << 5) + srow) * K + kt + lk,
                        &tB[(rr << 11) + (w << 9)]);
        }
        __syncthreads();
#pragma unroll
        for (int s = 0; s < 2; ++s) {
            const int koff = ((((s << 2) + (l >> 4)) ^ (l & 7)) << 3);
            bf16x8 av[4], bv[4];
#pragma unroll
            for (int i = 0; i < 4; ++i) {
                av[i] = *(const bf16x8*)&tA[((wm + (i << 4) + frow) << 6) + koff];
                bv[i] = *(const bf16x8*)&tB[((wn + (i << 4) + frow) << 6) + koff];
            }
#pragma unroll
            for (int i = 0; i < 4; ++i)
#pragma unroll
                for (int j = 0; j < 4; ++j)
                    acc[i][j] = __builtin_amdgcn_mfma_f32_16x16x32_bf16(av[i], bv[j], acc[i][j], 0, 0, 0);
        }
        __syncthreads();
    }
    const int crow = bm + wm + ((l >> 4) << 2);
    const int ccol = bn + wn + (l & 15);
#pragma unroll
    for (int i = 0; i < 4; ++i)
#pragma unroll
        for (int j = 0; j < 4; ++j)
#pragma unroll
            for (int jj = 0; jj < 4; ++jj)
                C[(size_t)(crow + (i << 4) + jj) * N + ccol + (j << 4)] = f2bf(acc[i][j][jj]);
}

// ---------- GEMM2: block-diagonal W2T, per-segment true K (BK=32), bf16 C ----------
__global__ __launch_bounds__(256) void k_gemm2(const u16* __restrict__ A,
                                               const u16* __restrict__ Bt,
                                               u16* __restrict__ C) {
    __shared__ __align__(16) u16 tA[4096];
    __shared__ __align__(16) u16 tB[4096];
    const int tid = threadIdx.x;
    const int w = tid >> 6, l = tid & 63;
    const int by = blockIdx.y;
    int c0, K;
    if (by < 16)      { c0 = 0;   K = 96; }
    else if (by < 32) { c0 = 96;  K = 96; }
    else if (by < 48) { c0 = 192; K = 256; }
    else if (by < 52) { c0 = 448; K = 64; }
    else              { c0 = 512; K = 64; }
    const int n0 = by << 7;
    const int bm = blockIdx.x << 7;
    const int wm = (w >> 1) << 6, wn = (w & 1) << 6;
    const int lrow = l >> 2;
    const int lk = (((l & 3) ^ ((l >> 3) & 3)) << 3);
    f32x4 acc[4][4] = {};
    const size_t rA0 = (size_t)(bm + (w << 4) + lrow) * 576 + c0;
    const size_t rA1 = (size_t)(bm + ((w + 4) << 4) + lrow) * 576 + c0;
    const size_t rB0 = (size_t)(n0 + (w << 4) + lrow) * 576 + c0;
    const size_t rB1 = (size_t)(n0 + ((w + 4) << 4) + lrow) * 576 + c0;
    const int frow = l & 15;
    const int koff = (((l >> 4) ^ ((l >> 1) & 3)) << 3);
    for (int kt = 0; kt < K; kt += 32) {
        gload_lds16(A + rA0 + kt + lk, &tA[w << 9]);
        gload_lds16(A + rA1 + kt + lk, &tA[2048 + (w << 9)]);
        gload_lds16(Bt + rB0 + kt + lk, &tB[w << 9]);
        gload_lds16(Bt + rB1 + kt + lk, &tB[2048 + (w << 9)]);
        __syncthreads();
        bf16x8 av[4], bv[4];
#pragma unroll
        for (int i = 0; i < 4; ++i) {
            av[i] = *(const bf16x8*)&tA[((wm + (i << 4) + frow) << 5) + koff];
            bv[i] = *(const bf16x8*)&tB[((wn + (i << 4) + frow) << 5) + koff];
        }
#pragma unroll
        for (int i = 0; i < 4; ++i)
#pragma unroll
            for (int j = 0; j < 4; ++j)
                acc[i][j] = __builtin_amdgcn_mfma_f32_16x16x32_bf16(av[i], bv[j], acc[i][j], 0, 0, 0);
        __syncthreads();
    }
    const int crow = bm + wm + ((l >> 4) << 2);
    const int ccol = n0 + wn + (l & 15);
#pragma unroll
    for (int i = 0; i < 4; ++i)
#pragma unroll
        for (int j = 0; j < 4; ++j)
#pragma unroll
            for (int jj = 0; jj < 4; ++jj)
                C[(size_t)(crow + (i << 4) + jj) * N2 + ccol + (j << 4)] = f2bf(acc[i][j][jj]);
}

// ---------- Y1(bf16) -> X2 (bf16): [tanh(xw) | xa | sigmoid(xg) | xv | xk] ----------
__global__ __launch_bounds__(256) void k_prep_x2(const u16* __restrict__ Y1, u16* __restrict__ X2) {
    int idx = blockIdx.x * 256 + threadIdx.x;   // t*576 + c
    int t = idx / 576, c = idx - t * 576;
    const u16* y1 = Y1 + (size_t)t * N1;
    float v;
    if (c < 96)       v = tanhf(bf2f(y1[c]));
    else if (c < 192) v = bf2f(y1[c]);
    else if (c < 448) v = sigm(bf2f(y1[c + 64]));
    else if (c < 512) v = bf2f(y1[c - 256]);
    else              v = bf2f(y1[c]);
    X2[idx] = f2bf(v);
}

// ---------- per-token recurrence prep (+ packed coeffs + head-dot); Y2 bf16 ----------
__global__ __launch_bounds__(256) void k_prep_rec(
    const u16* __restrict__ Y1, const u16* __restrict__ Y2b,
    const float* __restrict__ v_first, const float* __restrict__ k_first,
    const float* __restrict__ cosb, const float* __restrict__ sinb,
    const float* __restrict__ w0, const float* __restrict__ a0,
    const float* __restrict__ v0b, const float* __restrict__ k0b,
    const float* __restrict__ R_bias, const float* __restrict__ K_bias,
    const float* __restrict__ V_bias, const float* __restrict__ ln_r,
    const float* __restrict__ ln_k, const float* __restrict__ r_k,
    float* __restrict__ DEC, float* __restrict__ VV,
    u32* __restrict__ PAB, u32* __restrict__ PKR, float* __restrict__ DOT) {
    const int t = blockIdx.x, tid = threadIdx.x;
    const int ww = tid >> 6, lane = tid & 63;
    const u16* y1 = Y1 + (size_t)t * N1;
    const u16* y2 = Y2b + (size_t)t * N2;
    const float cs = cosb[t * 64 + lane];
    const float sn = sinb[t * 64 + lane];
    const float sign = lane < 32 ? -1.f : 1.f;
    const size_t tb = (size_t)t << 11;
    __shared__ float kkv[512], vkv[512];
    float rsave[8];
    // r: per-head rmsnorm + rope
#pragma unroll
    for (int i = 0; i < 8; ++i) {
        int h = ww * 8 + i, c = h * 64 + lane;
        float rr = bf2f(y1[576 + c]) + R_bias[c];
        float ssq = wsum(rr * rr);
        float rn = ln_r[lane] * rr * rsqrtf(ssq * (1.f / 64.f) + 1e-6f);
        float rot = sign * __shfl(rn, lane ^ 32, 64);
        rsave[i] = rn * cs + rot * sn;
    }
    // k,v kv-heads: rmsnorm+rope+mix
#pragma unroll
    for (int i = 0; i < 2; ++i) {
        int j = ww * 2 + i, c = j * 64 + lane;
        float kr = bf2f(y1[2624 + c]) + K_bias[c];
        float ssq = wsum(kr * kr);
        float kn = ln_k[lane] * kr * rsqrtf(ssq * (1.f / 64.f) + 1e-6f);
        float rot = sign * __shfl(kn, lane ^ 32, 64);
        float krope = kn * cs + rot * sn;
        float ksig = sigm(bf2f(y2[6656 + c]) + k0b[c]);
        kkv[c] = krope + (k_first[(size_t)t * 512 + c] - krope) * ksig;
        float vr = bf2f(y1[3136 + c]) + V_bias[c];
        float vsig = sigm(bf2f(y2[6144 + c]) + v0b[c]);
        vkv[c] = vr + (v_first[(size_t)t * 512 + c] - vr) * vsig;
    }
    __syncthreads();
    // per-head final recurrence operands
#pragma unroll
    for (int i = 0; i < 8; ++i) {
        int h = ww * 8 + i, c = h * 64 + lane;
        int ckv = (h >> 2) * 64 + lane;
        float kb = kkv[ckv], vb = vkv[ckv];
        float a_ = sigm(bf2f(y2[2048 + c]) + a0[c]);
        float wr = bf2f(y2[c]) + w0[c];
        float z = -wr;
        float sp = fmaxf(z, 0.f) + log1pf(expf(-fabsf(z)));
        float w_log = -sp - 0.5f;
        float ssq = wsum(kb * kb);
        float kk = kb / fmaxf(sqrtf(ssq), 1e-12f);
        const float kr2 = kb * (1.f - w_log + a_);
        const float rrv = rsave[i];
        DEC[tb + c] = expf(-expf(w_log));
        VV[tb + c] = vb;
        PAB[tb + c] = (u32)f2bf(-kk) | ((u32)f2bf(kk * a_) << 16);
        PKR[tb + c] = (u32)f2bf(kr2) | ((u32)f2bf(rrv) << 16);
        const float dsum = wsum(rrv * kr2 * r_k[c]);
        if (lane == 0) DOT[((size_t)t << 5) + h] = dsum;
    }
}

// ---------- sequential recurrence: homogeneous-b128, 2 groups in flight; OO bf16 ----------
__global__ __launch_bounds__(256, 1) void k_recv17(
    const float* __restrict__ DECp, const u32* __restrict__ PABp,
    const u32* __restrict__ PKRp, const float* __restrict__ VVp,
    const float* __restrict__ S0, u16* __restrict__ OO) {
    __shared__ __align__(16) float cbuf[2][4][32][64];   // 64 KB
    const int tid = threadIdx.x;
    const int wl = tid >> 6;           // wave 0..3
    const int lane = tid & 63;
    const int vl = lane >> 4;          // DPP row 0..3
    const int kq = lane & 15;          // k-quad 0..15
    const int quarter = blockIdx.x & 3;
    const int ch = blockIdx.x >> 2;          // chain 0..63 (b*32+h)
    const int vcol = (quarter << 4) + (wl << 2) + vl;   // this row's v-column
    const size_t cb = ((size_t)(ch >> 5) * 1024 * 2048) + ((size_t)(ch & 31) << 6);

    const float* s0 = S0 + ((size_t)ch << 12);
    float L0 = s0[((kq << 2) + 0) * 64 + vcol];
    float L1 = s0[((kq << 2) + 1) * 64 + vcol];
    float L2 = s0[((kq << 2) + 2) * 64 + vcol];
    float L3 = s0[((kq << 2) + 3) * 64 + vcol];

    const int trow = (wl << 2) + vl;   // 0..15; rows trow and trow+16 staged

#define STG(B, T0)                                                             \
    {                                                                          \
        const size_t g0 = cb + (size_t)((T0) + trow) * 2048 + (kq << 2);       \
        const size_t g1 = cb + (size_t)((T0) + 16 + trow) * 2048 + (kq << 2);  \
        float* lb = &cbuf[B][0][0][0] + (wl << 8);                             \
        gload_lds16(DECp + g0, lb);                                            \
        gload_lds16(DECp + g1, lb + 1024);                                     \
        gload_lds16(PABp + g0, lb + 2048);                                     \
        gload_lds16(PABp + g1, lb + 3072);                                     \
        gload_lds16(PKRp + g0, lb + 4096);                                     \
        gload_lds16(PKRp + g1, lb + 5120);                                     \
        gload_lds16(VVp + g0, lb + 6144);                                      \
        gload_lds16(VVp + g1, lb + 7168);                                      \
    }

    const u32 base0 = (u32)(size_t)(void*)&cbuf[0][0][0][0];
    const u32 aA0 = base0 + (kq << 4);             // coefficient chunk for lane
    const u32 aV0 = base0 + 24576 + (vcol << 2);   // V broadcast slot

    float4 cDa0, cDa1, cDb0, cDb1;
    uint4 cPAa0, cPAa1, cPAb0, cPAb1, cPKa0, cPKa1, cPKb0, cPKb1;
    float cV[32];

#define LD2(S_, G)                                                             \
    cD##S_##0 = ds_read128<(G) * 512>(aAb);                                    \
    cD##S_##1 = ds_read128<(G) * 512 + 256>(aAb);                              \
    cPA##S_##0 = ds_read128u<8192 + (G) * 512>(aAb);                           \
    cPA##S_##1 = ds_read128u<8192 + (G) * 512 + 256>(aAb);                     \
    cPK##S_##0 = ds_read128u<16384 + (G) * 512>(aAb);                          \
    cPK##S_##1 = ds_read128u<16384 + (G) * 512 + 256>(aAb);

#define VRD(J) cV[J] = ds_read32<(J) * 256>(aVb);
#define VRD8(J) VRD(J) VRD((J)+1) VRD((J)+2) VRD((J)+3) VRD((J)+4) VRD((J)+5) VRD((J)+6) VRD((J)+7)

#define WAIT6 asm volatile("s_waitcnt lgkmcnt(6)" ::: "memory");               \
    __builtin_amdgcn_sched_barrier(0);
#define WAIT0 asm volatile("s_waitcnt lgkmcnt(0)" ::: "memory");               \
    __builtin_amdgcn_sched_barrier(0);

#define UNP_LO(u) __uint_as_float((u) << 16)
#define UNP_HI(u) __uint_as_float((u) & 0xffff0000u)

#define STEP1(D4, pa, pk, Vsj, T)                                              \
    {                                                                          \
        const float Ax = UNP_LO(pa.x), Ay = UNP_LO(pa.y),                      \
                    Az = UNP_LO(pa.z), Aw = UNP_LO(pa.w);                      \
        const float Bx = UNP_HI(pa.x), By = UNP_HI(pa.y),                      \
                    Bz = UNP_HI(pa.z), Bw = UNP_HI(pa.w);                      \
        const float Kx = UNP_LO(pk.x), Ky = UNP_LO(pk.y),                      \
                    Kz = UNP_LO(pk.z), Kw = UNP_LO(pk.w);                      \
        const float Rx = UNP_HI(pk.x), Ry = UNP_HI(pk.y),                      \
                    Rz = UNP_HI(pk.z), Rw = UNP_HI(pk.w);                      \
        float sp = fmaf(L1, Ay, L0 * Ax) + fmaf(L3, Aw, L2 * Az);              \
        const float sa = rowsum16(sp);                                         \
        L0 = fmaf(Bx, sa, fmaf(Kx, Vsj, L0 * D4.x));                           \
        L1 = fmaf(By, sa, fmaf(Ky, Vsj, L1 * D4.y));                           \
        L2 = fmaf(Bz, sa, fmaf(Kz, Vsj, L2 * D4.z));                           \
        L3 = fmaf(Bw, sa, fmaf(Kw, Vsj, L3 * D4.w));                           \
        float op = fmaf(L1, Ry, L0 * Rx) + fmaf(L3, Rw, L2 * Rz);              \
        const float o = rowsum16(op);                                          \
        if (kq == 0) OO[cb + ((size_t)(T) << 11) + vcol] = f2bf(o);            \
    }

#define STEP2(S_, G)                                                           \
    STEP1(cD##S_##0, cPA##S_##0, cPK##S_##0, cV[2 * (G)], tbase + 2 * (G));    \
    STEP1(cD##S_##1, cPA##S_##1, cPK##S_##1, cV[2 * (G) + 1], tbase + 2 * (G) + 1);

#define PAIR(G)                                                                \
    LD2(b, (G) + 1) WAIT6 STEP2(a, G) LD2(a, (G) + 2) WAIT6 STEP2(b, (G) + 1)

    STG(0, 0);
    __syncthreads();

    for (int c = 0; c < 32; ++c) {
        const int b = c & 1;
        if (c < 31) STG(b ^ 1, (c + 1) << 5);      // async prefetch next chunk (vmcnt)
        const u32 aAb = aA0 + b * 32768;
        const u32 aVb = aV0 + b * 32768;
        const int tbase = c << 5;
        VRD8(0) VRD8(8) VRD8(16) VRD8(24)          // all 32 V values (b32 burst)
        WAIT0                                      // V in regs; lgkm queue empty
        LD2(a, 0)
        PAIR(0) PAIR(2) PAIR(4) PAIR(6) PAIR(8) PAIR(10) PAIR(12)
        LD2(b, 15) WAIT6 STEP2(a, 14) WAIT0 STEP2(b, 15)
        __syncthreads();   // drains staging vmcnt (1/32 steps); flips buffers
    }
#undef PAIR
#undef STEP2
#undef STEP1
#undef UNP_LO
#undef UNP_HI
#undef WAIT0
#undef WAIT6
#undef VRD8
#undef VRD
#undef LD2
#undef STG
}

// ---------- gate: pure elementwise (dot precomputed; OO & Y2 bf16) ----------
__global__ __launch_bounds__(256) void k_gate(
    const u16* __restrict__ OOp, const float* __restrict__ VVp,
    const float* __restrict__ DOT, const u16* __restrict__ Y2b,
    u16* __restrict__ XG) {
    const int t = blockIdx.x, tid = threadIdx.x;
    const size_t tb = (size_t)t << 11;
    const int c0 = tid << 3;
    const float dot = DOT[((size_t)t << 5) + (tid >> 3)];
    uint4 ou = *(const uint4*)(OOp + tb + c0);     // 8 bf16
    float4 v0 = *(const float4*)(VVp + tb + c0);
    float4 v1 = *(const float4*)(VVp + tb + c0 + 4);
    uint4 gu = *(const uint4*)(Y2b + (size_t)t * N2 + 4096 + c0);   // 8 bf16
    const float o0 = __uint_as_float(ou.x << 16),  o1 = __uint_as_float(ou.x & 0xffff0000u);
    const float o2 = __uint_as_float(ou.y << 16),  o3 = __uint_as_float(ou.y & 0xffff0000u);
    const float o4 = __uint_as_float(ou.z << 16),  o5 = __uint_as_float(ou.z & 0xffff0000u);
    const float o6 = __uint_as_float(ou.w << 16),  o7 = __uint_as_float(ou.w & 0xffff0000u);
    const float g0 = __uint_as_float(gu.x << 16),  g1 = __uint_as_float(gu.x & 0xffff0000u);
    const float g2 = __uint_as_float(gu.y << 16),  g3 = __uint_as_float(gu.y & 0xffff0000u);
    const float g4 = __uint_as_float(gu.z << 16),  g5 = __uint_as_float(gu.z & 0xffff0000u);
    const float g6 = __uint_as_float(gu.w << 16),  g7 = __uint_as_float(gu.w & 0xffff0000u);
    const float x0 = fmaf(o0, 0.125f, dot * v0.x) * g0;
    const float x1 = fmaf(o1, 0.125f, dot * v0.y) * g1;
    const float x2 = fmaf(o2, 0.125f, dot * v0.z) * g2;
    const float x3 = fmaf(o3, 0.125f, dot * v0.w) * g3;
    const float x4 = fmaf(o4, 0.125f, dot * v1.x) * g4;
    const float x5 = fmaf(o5, 0.125f, dot * v1.y) * g5;
    const float x6 = fmaf(o6, 0.125f, dot * v1.z) * g6;
    const float x7 = fmaf(o7, 0.125f, dot * v1.w) * g7;
    uint4 pk;
    pk.x = (u32)f2bf(x0) | ((u32)f2bf(x1) << 16);
    pk.y = (u32)f2bf(x2) | ((u32)f2bf(x3) << 16);
    pk.z = (u32)f2bf(x4) | ((u32)f2bf(x5) << 16);
    pk.w = (u32)f2bf(x6) | ((u32)f2bf(x7) << 16);
    *(uint4*)(XG + tb + c0) = pk;
}

// ---------- final residual + rmsnorm ----------
__global__ __launch_bounds__(256) void k_final(const float* __restrict__ x_in,
                                               const float* __restrict__ OUTR,
                                               const float* __restrict__ ln2,
                                               float* __restrict__ out) {
    const int t = blockIdx.x, tid = threadIdx.x;
    const float* xr = x_in + ((size_t)t << 11);
    const float* orow = OUTR + ((size_t)t << 11);
    float4 a0 = *(const float4*)(xr + tid * 8);
    float4 a1 = *(const float4*)(xr + tid * 8 + 4);
    float4 b0 = *(const float4*)(orow + tid * 8);
    float4 b1 = *(const float4*)(orow + tid * 8 + 4);
    float v[8] = {a0.x + b0.x, a0.y + b0.y, a0.z + b0.z, a0.w + b0.w,
                  a1.x + b1.x, a1.y + b1.y, a1.z + b1.z, a1.w + b1.w};
    float ss = 0.f;
#pragma unroll
    for (int i = 0; i < 8; ++i) ss = fmaf(v[i], v[i], ss);
    ss = wsum(ss);
    __shared__ float red[4];
    if ((tid & 63) == 0) red[tid >> 6] = ss;
    __syncthreads();
    float scale = rsqrtf((red[0] + red[1] + red[2] + red[3]) * (1.f / 2048.f) + 1e-6f);
    float* o = out + ((size_t)t << 11) + tid * 8;
#pragma unroll
    for (int i = 0; i < 8; ++i) o[i] = ln2[tid * 8 + i] * v[i] * scale;
}

extern "C" void kernel_launch(void* const* d_in, const int* in_sizes, int n_in,
                              void* d_out, int out_size, void* d_ws, size_t ws_size,
                              hipStream_t stream) {
    const float* x_in    = (const float*)d_in[0];
    const float* v_first = (const float*)d_in[1];
    const float* k_first = (const float*)d_in[2];
    const float* state   = (const float*)d_in[3];
    const float* cosb    = (const float*)d_in[4];
    const float* sinb    = (const float*)d_in[5];
    const float* wavgk1  = (const float*)d_in[6];
    const float* w0      = (const float*)d_in[7];
    const float* w2      = (const float*)d_in[8];
    const float* a0      = (const float*)d_in[9];
    const float* a2      = (const float*)d_in[10];
    const float* v0      = (const float*)d_in[11];
    const float* v2      = (const float*)d_in[12];
    const float* g2      = (const float*)d_in[13];
    const float* k0      = (const float*)d_in[14];
    const float* k2      = (const float*)d_in[15];
    const float* r_k     = (const float*)d_in[16];
    const float* RKV     = (const float*)d_in[17];
    const float* O       = (const float*)d_in[18];
    const float* R_bias  = (const float*)d_in[19];
    const float* K_bias  = (const float*)d_in[20];
    const float* V_bias  = (const float*)d_in[21];
    const float* ln_r    = (const float*)d_in[22];
    const float* ln_k    = (const float*)d_in[23];
    const float* ln1     = (const float*)d_in[24];
    const float* ln2     = (const float*)d_in[25];

    if (ws_size < WS_NEED) return;  // need 247.2 MB (fits 256 MiB)

    char* ws = (char*)d_ws;
    u16*   BT1  = (u16*)(ws + OFF_BT1);
    u16*   W2T  = (u16*)(ws + OFF_W2T);
    u16*   OT   = (u16*)(ws + OFF_OT);
    u16*   XB   = (u16*)(ws + OFF_XB);
    u16*   Y1   = (u16*)(ws + OFF_Y1);
    u16*   X2   = (u16*)(ws + OFF_X2);
    u16*   Y2b  = (u16*)(ws + OFF_Y2);
    float* DEC  = (float*)(ws + OFF_DEC);
    float* VV   = (float*)(ws + OFF_VV);
    u32*   PAB  = (u32*)(ws + OFF_PAB);
    u32*   PKR  = (u32*)(ws + OFF_PKR);
    float* DOT  = (float*)(ws + OFF_DOT);
    u16*   OO   = (u16*)(ws + OFF_OO);
    u16*   XG   = (u16*)(ws + OFF_XG);
    float* OUTR = (float*)(ws + OFF_OUTR);

    // P0: BT1 + XB (region C)
    k_prep_bt1<<<1856, 256, 0, stream>>>(wavgk1, RKV, BT1);
    k_rms1<<<2048, 256, 0, stream>>>(x_in, ln1, XB);
    // P1: GEMM1 -> Y1 (bf16, region A), BK=64
    k_gemmb<<<dim3(16, 29), 256, 0, stream>>>(XB, BT1, Y1, 2048, N1, 2048);
    // P2: W2T + X2 overwrite BT1/XB (dead); GEMM2 (block-diagonal) -> Y2 bf16
    k_prep_w2t<<<1008, 256, 0, stream>>>(w2, a2, g2, v2, k2, W2T);
    k_prep_x2<<<4608, 256, 0, stream>>>(Y1, X2);
    k_gemm2<<<dim3(16, 56), 256, 0, stream>>>(X2, W2T, Y2b);
    // P3: recurrence operands + head-dot; Y1 dead after this
    k_prep_rec<<<2048, 256, 0, stream>>>(Y1, Y2b, v_first, k_first, cosb, sinb,
                                         w0, a0, v0, k0, R_bias, K_bias, V_bias,
                                         ln_r, ln_k, r_k, DEC, VV, PAB, PKR, DOT);
    // P4: OT overwrites W2T/X2 (dead); recurrence -> OO bf16 (in old Y1 space)
    k_prep_ot<<<1024, 256, 0, stream>>>(O, OT);
    k_recv17<<<256, 256, 0, stream>>>(DEC, PAB, PKR, VV, state, OO);
    // P5: gate (elementwise) -> XG; Y2 dead after this
    k_gate<<<2048, 256, 0, stream>>>(OO, VV, DOT, Y2b, XG);
    // P6: GEMM3 -> OUTR (f32), BK=64; final norm
    k_gemm<<<dim3(16, 16), 256, 0, stream>>>(XG, OT, OUTR, 2048, 2048, 2048);
    k_final<<<2048, 256, 0, stream>>>(x_in, OUTR, ln2, (float*)d_out);
}

// Round 29
// 339.658 us; speedup vs baseline: 1.2270x; 1.0070x over previous
//
#include <hip/hip_runtime.h>

typedef unsigned short u16;
typedef unsigned int u32;

using f32x4 = __attribute__((ext_vector_type(4))) float;
using bf16x8 = __attribute__((ext_vector_type(8))) __bf16;

// ---------- constants ----------
#define HN 2048
#define KVD 512
#define TOKENS 2048          // B*T
#define N1 3712              // GEMM1 N (3648 padded to 29*128)
#define K2W 576              // GEMM2 K
#define N2 7168              // GEMM2 N: w(2048) a(2048) g(2048) v(512) k(512)

// ---------- workspace layout (bytes) — lifetime-aliased ----------
// P0 writes: BT1, W2T, OT, XB. P1: Y1(+X2 fused). P2: Y2. P3: DEC/VV/PAB/PKR/DOT.
// P4: OO (over dead Y1). P5: XG (over dead W2T). P6: OUTR (own region).
#define OFF_Y1   0ull                    // bf16 [2048][3712] (dead after prep_rec)
#define OFF_OO   0ull                    // f32 [2048][2048] (after Y1 dead)
#define OFF_XG   16777216ull             // bf16 [2048][2048]; W2T lives here until P5
#define OFF_W2T  16777216ull             // bf16 [7168][576] = 8.26MB (dead after gemm2)
#define OFF_X2   25165824ull             // bf16 [2048][576] = 2.36MB
#define OFF_Y2   30408704ull             // bf16 [2048][7168] = 29.4MB
#define OFF_OUTR 60817408ull             // f32 [2048][2048]
#define OFF_OT   77594624ull             // bf16 [2048][2048] = 8.4MB (written P0, read P6)
#define OFF_BT1  89128960ull             // bf16 [3712][2048] = 15.2MB (dead after gemm1)
#define OFF_XB   104333312ull            // bf16 [2048][2048]
#define OFF_DEC  129499136ull
#define OFF_VV   163053568ull
#define OFF_PAB  213385216ull            // u32 [2048][2048]: bf16(A) | bf16(B)<<16
#define OFF_PKR  230162432ull            // u32 [2048][2048]: bf16(K) | bf16(R)<<16
#define OFF_DOT  246939648ull            // f32 [2048][32] = 256KB
#define WS_NEED  247201792ull

// ---------- helpers ----------
__device__ __forceinline__ u16 f2bf(float f) {
    u32 u = __float_as_uint(f);
    u32 r = u + 0x7fffu + ((u >> 16) & 1u);
    return (u16)(r >> 16);
}
__device__ __forceinline__ float bf2f(u16 b) {
    return __uint_as_float(((u32)b) << 16);
}
__device__ __forceinline__ float sigm(float x) { return 1.f / (1.f + expf(-x)); }
__device__ __forceinline__ float wsum(float v) {
#pragma unroll
    for (int m = 32; m > 0; m >>= 1) v += __shfl_xor(v, m, 64);
    return v;
}
// sum across each 16-lane DPP row via row_ror 1,2,4,8; result in all lanes of the row
__device__ __forceinline__ float rowsum16(float v) {
    float t;
    t = __uint_as_float(__builtin_amdgcn_update_dpp(0, __float_as_uint(v), 0x121, 0xf, 0xf, true));
    v += t;
    t = __uint_as_float(__builtin_amdgcn_update_dpp(0, __float_as_uint(v), 0x122, 0xf, 0xf, true));
    v += t;
    t = __uint_as_float(__builtin_amdgcn_update_dpp(0, __float_as_uint(v), 0x124, 0xf, 0xf, true));
    v += t;
    t = __uint_as_float(__builtin_amdgcn_update_dpp(0, __float_as_uint(v), 0x128, 0xf, 0xf, true));
    v += t;
    return v;
}

typedef __attribute__((address_space(1))) const void glob_t;
typedef __attribute__((address_space(3))) void lds_t;
__device__ __forceinline__ void gload_lds16(const void* g, void* l) {
    __builtin_amdgcn_global_load_lds((glob_t*)g, (lds_t*)l, 16, 0, 0);
}

// inline-asm LDS readers with literal offset (burst-issued, order preserved)
template<int OFF>
__device__ __forceinline__ float4 ds_read128(u32 a) {
    float4 r;
    asm volatile("ds_read_b128 %0, %1 offset:%2" : "=v"(r) : "v"(a), "i"(OFF));
    return r;
}
template<int OFF>
__device__ __forceinline__ uint4 ds_read128u(u32 a) {
    uint4 r;
    asm volatile("ds_read_b128 %0, %1 offset:%2" : "=v"(r) : "v"(a), "i"(OFF));
    return r;
}
template<int OFF>
__device__ __forceinline__ float ds_read32(u32 a) {
    float r;
    asm volatile("ds_read_b32 %0, %1 offset:%2" : "=v"(r) : "v"(a), "i"(OFF));
    return r;
}

// ---------- merged P0 prep: 4 independent kernels in one launch ----------
// blocks [0,1856): BT1 transpose; [1856,2864): W2T; [2864,3888): OT; [3888,5936): rms1
__global__ __launch_bounds__(256) void k_prep0(
    const float* __restrict__ wavgk1, const float* __restrict__ RKV,
    const float* __restrict__ w2, const float* __restrict__ a2,
    const float* __restrict__ g2, const float* __restrict__ v2,
    const float* __restrict__ k2, const float* __restrict__ O,
    const float* __restrict__ X, const float* __restrict__ ln1,
    u16* __restrict__ BT1, u16* __restrict__ W2T,
    u16* __restrict__ OT, u16* __restrict__ XB) {
    __shared__ float tile[64][65];
    const int bx = blockIdx.x;
    const int tid = threadIdx.x;
    if (bx < 1856) {                       // ---- BT1[n][k] = src[k][n]
        const int bn = bx >> 5, bk = bx & 31;
        const int n0 = bn << 6, k0 = bk << 6;
        const int c = tid & 63, q = tid >> 6;
#pragma unroll
        for (int i = 0; i < 16; ++i) {
            const int r = (q << 4) + i;
            float v = 0.f;
            if (bn < 9)       v = wavgk1[(size_t)(k0 + r) * 576 + n0 + c];
            else if (bn < 57) v = RKV[(size_t)(k0 + r) * 3072 + (n0 + c - 576)];
            tile[r][c] = v;
        }
        __syncthreads();
#pragma unroll
        for (int i = 0; i < 16; ++i) {
            const int rw = (q << 4) + i;
            BT1[(size_t)(n0 + rw) * 2048 + k0 + c] = f2bf(tile[c][rw]);
        }
    } else if (bx < 2864) {                // ---- W2T[n][c] = blockdiag src[c][n]
        const int b = bx - 1856;
        const int bn = b / 9, bc = b - bn * 9;
        const int n0 = bn << 6, c0 = bc << 6;
        const int cc = tid & 63, q = tid >> 6;
#pragma unroll
        for (int i = 0; i < 16; ++i) {
            const int r = (q << 4) + i;
            const int c = c0 + r;
            const int n = n0 + cc;
            float v = 0.f;
            if (n0 < 2048)      { if (c < 96)              v = w2[(size_t)c * 2048 + n]; }
            else if (n0 < 4096) { if (c >= 96 && c < 192)  v = a2[(size_t)(c - 96) * 2048 + (n - 2048)]; }
            else if (n0 < 6144) { if (c >= 192 && c < 448) v = g2[(size_t)(c - 192) * 2048 + (n - 4096)]; }
            else if (n0 < 6656) { if (c >= 448 && c < 512) v = v2[(size_t)(c - 448) * 512 + (n - 6144)]; }
            else                { if (c >= 512)            v = k2[(size_t)(c - 512) * 512 + (n - 6656)]; }
            tile[r][cc] = v;
        }
        __syncthreads();
#pragma unroll
        for (int i = 0; i < 16; ++i) {
            const int rw = (q << 4) + i;
            W2T[(size_t)(n0 + rw) * 576 + c0 + cc] = f2bf(tile[cc][rw]);
        }
    } else if (bx < 3888) {                // ---- OT[n][k] = O[k][n]
        const int b = bx - 2864;
        const int bn = b >> 5, bk = b & 31;
        const int n0 = bn << 6, k0 = bk << 6;
        const int c = tid & 63, q = tid >> 6;
#pragma unroll
        for (int i = 0; i < 16; ++i) {
            const int r = (q << 4) + i;
            tile[r][c] = O[(size_t)(k0 + r) * 2048 + n0 + c];
        }
        __syncthreads();
#pragma unroll
        for (int i = 0; i < 16; ++i) {
            const int rw = (q << 4) + i;
            OT[(size_t)(n0 + rw) * 2048 + k0 + c] = f2bf(tile[c][rw]);
        }
    } else {                               // ---- rmsnorm(x_in, ln1) -> XB bf16
        const int t = bx - 3888;
        const float* row = X + ((size_t)t << 11);
        float4 v0 = *(const float4*)(row + tid * 8);
        float4 v1 = *(const float4*)(row + tid * 8 + 4);
        float ss = v0.x*v0.x + v0.y*v0.y + v0.z*v0.z + v0.w*v0.w
                 + v1.x*v1.x + v1.y*v1.y + v1.z*v1.z + v1.w*v1.w;
        ss = wsum(ss);
        if ((tid & 63) == 0) tile[0][tid >> 6] = ss;
        __syncthreads();
        float scale = rsqrtf((tile[0][0] + tile[0][1] + tile[0][2] + tile[0][3]) * (1.f / 2048.f) + 1e-6f);
        float4 w0_ = *(const float4*)(ln1 + tid * 8);
        float4 w1_ = *(const float4*)(ln1 + tid * 8 + 4);
        u16* o = XB + ((size_t)t << 11) + tid * 8;
        o[0] = f2bf(v0.x * scale * w0_.x); o[1] = f2bf(v0.y * scale * w0_.y);
        o[2] = f2bf(v0.z * scale * w0_.z); o[3] = f2bf(v0.w * scale * w0_.w);
        o[4] = f2bf(v1.x * scale * w1_.x); o[5] = f2bf(v1.y * scale * w1_.y);
        o[6] = f2bf(v1.z * scale * w1_.z); o[7] = f2bf(v1.w * scale * w1_.w);
    }
}

// ---------- BK=64 bf16 MFMA GEMM, f32 C ----------
__global__ __launch_bounds__(256) void k_gemm(const u16* __restrict__ A,
                                              const u16* __restrict__ Bt,
                                              float* __restrict__ C,
                                              int M, int N, int K) {
    __shared__ __align__(16) u16 tA[8192];
    __shared__ __align__(16) u16 tB[8192];
    const int tid = threadIdx.x;
    const int w = tid >> 6, l = tid & 63;
    const int bm = blockIdx.x << 7, bn = blockIdx.y << 7;
    const int wm = (w >> 1) << 6, wn = (w & 1) << 6;
    const int srow = (w << 3) + (l >> 3);                 // row within 32-row round
    const int lk = (((l & 7) ^ ((l >> 3) & 7)) << 3);     // pre-swizzled global chunk
    const int frow = l & 15;
    f32x4 acc[4][4] = {};
    for (int kt = 0; kt < K; kt += 64) {
#pragma unroll
        for (int rr = 0; rr < 4; ++rr) {
            gload_lds16(A + (size_t)(bm + (rr << 5) + srow) * K + kt + lk,
                        &tA[(rr << 11) + (w << 9)]);
            gload_lds16(Bt + (size_t)(bn + (rr << 5) + srow) * K + kt + lk,
                        &tB[(rr << 11) + (w << 9)]);
        }
        __syncthreads();
#pragma unroll
        for (int s = 0; s < 2; ++s) {
            const int koff = ((((s << 2) + (l >> 4)) ^ (l & 7)) << 3);
            bf16x8 av[4], bv[4];
#pragma unroll
            for (int i = 0; i < 4; ++i) {
                av[i] = *(const bf16x8*)&tA[((wm + (i << 4) + frow) << 6) + koff];
                bv[i] = *(const bf16x8*)&tB[((wn + (i << 4) + frow) << 6) + koff];
            }
#pragma unroll
            for (int i = 0; i < 4; ++i)
#pragma unroll
                for (int j = 0; j < 4; ++j)
                    acc[i][j] = __builtin_amdgcn_mfma_f32_16x16x32_bf16(av[i], bv[j], acc[i][j], 0, 0, 0);
        }
        __syncthreads();
    }
    const int crow = bm + wm + ((l >> 4) << 2);
    const int ccol = bn + wn + (l & 15);
#pragma unroll
    for (int i = 0; i < 4; ++i)
#pragma unroll
        for (int j = 0; j < 4; ++j)
#pragma unroll
            for (int jj = 0; jj < 4; ++jj)
                C[(size_t)(crow + (i << 4) + jj) * N + ccol + (j << 4)] = acc[i][j][jj];
}

// ---------- BK=64 GEMM, bf16 C + fused X2 epilogue (for Y1) ----------
// Y1 col c<576 also produces X2: c<96 -> tanh @c; 96..192 -> id @c;
// 192..256 -> id @c+256; 256..512 -> sigm @c-64; 512..576 -> id @c.
__global__ __launch_bounds__(256) void k_gemmb(const u16* __restrict__ A,
                                               const u16* __restrict__ Bt,
                                               u16* __restrict__ C,
                                               u16* __restrict__ X2,
                                               int M, int N, int K) {
    __shared__ __align__(16) u16 tA[8192];
    __shared__ __align__(16) u16 tB[8192];
    const int tid = threadIdx.x;
    const int w = tid >> 6, l = tid & 63;
    const int bm = blockIdx.x << 7, bn = blockIdx.y << 7;
    const int wm = (w >> 1) << 6, wn = (w & 1) << 6;
    const int srow = (w << 3) + (l >> 3);
    const int lk = (((l & 7) ^ ((l >> 3) & 7)) << 3);
    const int frow = l & 15;
    f32x4 acc[4][4] = {};
    for (int kt = 0; kt < K; kt += 64) {
#pragma unroll
        for (int rr = 0; rr < 4; ++rr) {
            gload_lds16(A + (size_t)(bm + (rr << 5) + srow) * K + kt + lk,
                        &tA[(rr << 11) + (w << 9)]);
            gload_lds16(Bt + (size_t)(bn + (rr << 5) + srow) * K + kt + lk,
                        &tB[(rr << 11) + (w << 9)]);
        }
        __syncthreads();
#pragma unroll
        for (int s = 0; s < 2; ++s) {
            const int koff = ((((s << 2) + (l >> 4)) ^ (l & 7)) << 3);
            bf16x8 av[4], bv[4];
#pragma unroll
            for (int i = 0; i < 4; ++i) {
                av[i] = *(const bf16x8*)&tA[((wm + (i << 4) + frow) << 6) + koff];
                bv[i] = *(const bf16x8*)&tB[((wn + (i << 4) + frow) << 6) + koff];
            }
#pragma unroll
            for (int i = 0; i < 4; ++i)
#pragma unroll
                for (int j = 0; j < 4; ++j)
                    acc[i][j] = __builtin_amdgcn_mfma_f32_16x16x32_bf16(av[i], bv[j], acc[i][j], 0, 0, 0);
        }
        __syncthreads();
    }
    const int crow = bm + wm + ((l >> 4) << 2);
    const int ccol = bn + wn + (l & 15);
#pragma unroll
    for (int i = 0; i < 4; ++i)
#pragma unroll
        for (int j = 0; j < 4; ++j) {
            const int c = ccol + (j << 4);
#pragma unroll
            for (int jj = 0; jj < 4; ++jj) {
                const int t = crow + (i << 4) + jj;
                const float y = acc[i][j][jj];
                C[(size_t)t * N + c] = f2bf(y);
                if (c < 576) {
                    float v; int xc;
                    if (c < 96)       { v = tanhf(y); xc = c; }
                    else if (c < 192) { v = y;        xc = c; }
                    else if (c < 256) { v = y;        xc = c + 256; }
                    else if (c < 512) { v = sigm(y);  xc = c - 64; }
                    else              { v = y;        xc = c; }
                    X2[(size_t)t * 576 + xc] = f2bf(v);
                }
            }
        }
}

// ---------- GEMM2: block-diagonal W2T, per-segment true K (BK=32), bf16 C ----------
__global__ __launch_bounds__(256) void k_gemm2(const u16* __restrict__ A,
                                               const u16* __restrict__ Bt,
                                               u16* __restrict__ C) {
    __shared__ __align__(16) u16 tA[4096];
    __shared__ __align__(16) u16 tB[4096];
    const int tid = threadIdx.x;
    const int w = tid >> 6, l = tid & 63;
    const int by = blockIdx.y;
    int c0, K;
    if (by < 16)      { c0 = 0;   K = 96; }
    else if (by < 32) { c0 = 96;  K = 96; }
    else if (by < 48) { c0 = 192; K = 256; }
    else if (by < 52) { c0 = 448; K = 64; }
    else              { c0 = 512; K = 64; }
    const int n0 = by << 7;
    const int bm = blockIdx.x << 7;
    const int wm = (w >> 1) << 6, wn = (w & 1) << 6;
    const int lrow = l >> 2;
    const int lk = (((l & 3) ^ ((l >> 3) & 3)) << 3);
    f32x4 acc[4][4] = {};
    const size_t rA0 = (size_t)(bm + (w << 4) + lrow) * 576 + c0;
    const size_t rA1 = (size_t)(bm + ((w + 4) << 4) + lrow) * 576 + c0;
    const size_t rB0 = (size_t)(n0 + (w << 4) + lrow) * 576 + c0;
    const size_t rB1 = (size_t)(n0 + ((w + 4) << 4) + lrow) * 576 + c0;
    const int frow = l & 15;
    const int koff = (((l >> 4) ^ ((l >> 1) & 3)) << 3);
    for (int kt = 0; kt < K; kt += 32) {
        gload_lds16(A + rA0 + kt + lk, &tA[w << 9]);
        gload_lds16(A + rA1 + kt + lk, &tA[2048 + (w << 9)]);
        gload_lds16(Bt + rB0 + kt + lk, &tB[w << 9]);
        gload_lds16(Bt + rB1 + kt + lk, &tB[2048 + (w << 9)]);
        __syncthreads();
        bf16x8 av[4], bv[4];
#pragma unroll
        for (int i = 0; i < 4; ++i) {
            av[i] = *(const bf16x8*)&tA[((wm + (i << 4) + frow) << 5) + koff];
            bv[i] = *(const bf16x8*)&tB[((wn + (i << 4) + frow) << 5) + koff];
        }
#pragma unroll
        for (int i = 0; i < 4; ++i)
#pragma unroll
            for (int j = 0; j < 4; ++j)
                acc[i][j] = __builtin_amdgcn_mfma_f32_16x16x32_bf16(av[i], bv[j], acc[i][j], 0, 0, 0);
        __syncthreads();
    }
    const int crow = bm + wm + ((l >> 4) << 2);
    const int ccol = n0 + wn + (l & 15);
#pragma unroll
    for (int i = 0; i < 4; ++i)
#pragma unroll
        for (int j = 0; j < 4; ++j)
#pragma unroll
            for (int jj = 0; jj < 4; ++jj)
                C[(size_t)(crow + (i << 4) + jj) * N2 + ccol + (j << 4)] = f2bf(acc[i][j][jj]);
}

// ---------- per-token recurrence prep (+ packed coeffs + head-dot); Y2 bf16 ----------
__global__ __launch_bounds__(256) void k_prep_rec(
    const u16* __restrict__ Y1, const u16* __restrict__ Y2b,
    const float* __restrict__ v_first, const float* __restrict__ k_first,
    const float* __restrict__ cosb, const float* __restrict__ sinb,
    const float* __restrict__ w0, const float* __restrict__ a0,
    const float* __restrict__ v0b, const float* __restrict__ k0b,
    const float* __restrict__ R_bias, const float* __restrict__ K_bias,
    const float* __restrict__ V_bias, const float* __restrict__ ln_r,
    const float* __restrict__ ln_k, const float* __restrict__ r_k,
    float* __restrict__ DEC, float* __restrict__ VV,
    u32* __restrict__ PAB, u32* __restrict__ PKR, float* __restrict__ DOT) {
    const int t = blockIdx.x, tid = threadIdx.x;
    const int ww = tid >> 6, lane = tid & 63;
    const u16* y1 = Y1 + (size_t)t * N1;
    const u16* y2 = Y2b + (size_t)t * N2;
    const float cs = cosb[t * 64 + lane];
    const float sn = sinb[t * 64 + lane];
    const float sign = lane < 32 ? -1.f : 1.f;
    const size_t tb = (size_t)t << 11;
    __shared__ float kkv[512], vkv[512];
    float rsave[8];
    // r: per-head rmsnorm + rope
#pragma unroll
    for (int i = 0; i < 8; ++i) {
        int h = ww * 8 + i, c = h * 64 + lane;
        float rr = bf2f(y1[576 + c]) + R_bias[c];
        float ssq = wsum(rr * rr);
        float rn = ln_r[lane] * rr * rsqrtf(ssq * (1.f / 64.f) + 1e-6f);
        float rot = sign * __shfl(rn, lane ^ 32, 64);
        rsave[i] = rn * cs + rot * sn;
    }
    // k,v kv-heads: rmsnorm+rope+mix
#pragma unroll
    for (int i = 0; i < 2; ++i) {
        int j = ww * 2 + i, c = j * 64 + lane;
        float kr = bf2f(y1[2624 + c]) + K_bias[c];
        float ssq = wsum(kr * kr);
        float kn = ln_k[lane] * kr * rsqrtf(ssq * (1.f / 64.f) + 1e-6f);
        float rot = sign * __shfl(kn, lane ^ 32, 64);
        float krope = kn * cs + rot * sn;
        float ksig = sigm(bf2f(y2[6656 + c]) + k0b[c]);
        kkv[c] = krope + (k_first[(size_t)t * 512 + c] - krope) * ksig;
        float vr = bf2f(y1[3136 + c]) + V_bias[c];
        float vsig = sigm(bf2f(y2[6144 + c]) + v0b[c]);
        vkv[c] = vr + (v_first[(size_t)t * 512 + c] - vr) * vsig;
    }
    __syncthreads();
    // per-head final recurrence operands
#pragma unroll
    for (int i = 0; i < 8; ++i) {
        int h = ww * 8 + i, c = h * 64 + lane;
        int ckv = (h >> 2) * 64 + lane;
        float kb = kkv[ckv], vb = vkv[ckv];
        float a_ = sigm(bf2f(y2[2048 + c]) + a0[c]);
        float wr = bf2f(y2[c]) + w0[c];
        float z = -wr;
        float sp = fmaxf(z, 0.f) + log1pf(expf(-fabsf(z)));
        float w_log = -sp - 0.5f;
        float ssq = wsum(kb * kb);
        float kk = kb / fmaxf(sqrtf(ssq), 1e-12f);
        const float kr2 = kb * (1.f - w_log + a_);
        const float rrv = rsave[i];
        DEC[tb + c] = expf(-expf(w_log));
        VV[tb + c] = vb;
        PAB[tb + c] = (u32)f2bf(-kk) | ((u32)f2bf(kk * a_) << 16);
        PKR[tb + c] = (u32)f2bf(kr2) | ((u32)f2bf(rrv) << 16);
        const float dsum = wsum(rrv * kr2 * r_k[c]);
        if (lane == 0) DOT[((size_t)t << 5) + h] = dsum;
    }
}

// ---------- sequential recurrence: homogeneous-b128, 2 groups in flight; OO f32 ----------
// (r28's bf16 OO store regressed recv +4us — f2bf + scattered 2B stores in the
//  serial chain. Reverted to the r27-proven f32 store.)
__global__ __launch_bounds__(256, 1) void k_recv17(
    const float* __restrict__ DECp, const u32* __restrict__ PABp,
    const u32* __restrict__ PKRp, const float* __restrict__ VVp,
    const float* __restrict__ S0, float* __restrict__ OO) {
    __shared__ __align__(16) float cbuf[2][4][32][64];   // 64 KB
    const int tid = threadIdx.x;
    const int wl = tid >> 6;           // wave 0..3
    const int lane = tid & 63;
    const int vl = lane >> 4;          // DPP row 0..3
    const int kq = lane & 15;          // k-quad 0..15
    const int quarter = blockIdx.x & 3;
    const int ch = blockIdx.x >> 2;          // chain 0..63 (b*32+h)
    const int vcol = (quarter << 4) + (wl << 2) + vl;   // this row's v-column
    const size_t cb = ((size_t)(ch >> 5) * 1024 * 2048) + ((size_t)(ch & 31) << 6);

    const float* s0 = S0 + ((size_t)ch << 12);
    float L0 = s0[((kq << 2) + 0) * 64 + vcol];
    float L1 = s0[((kq << 2) + 1) * 64 + vcol];
    float L2 = s0[((kq << 2) + 2) * 64 + vcol];
    float L3 = s0[((kq << 2) + 3) * 64 + vcol];

    const int trow = (wl << 2) + vl;   // 0..15; rows trow and trow+16 staged

#define STG(B, T0)                                                             \
    {                                                                          \
        const size_t g0 = cb + (size_t)((T0) + trow) * 2048 + (kq << 2);       \
        const size_t g1 = cb + (size_t)((T0) + 16 + trow) * 2048 + (kq << 2);  \
        float* lb = &cbuf[B][0][0][0] + (wl << 8);                             \
        gload_lds16(DECp + g0, lb);                                            \
        gload_lds16(DECp + g1, lb + 1024);                                     \
        gload_lds16(PABp + g0, lb + 2048);                                     \
        gload_lds16(PABp + g1, lb + 3072);                                     \
        gload_lds16(PKRp + g0, lb + 4096);                                     \
        gload_lds16(PKRp + g1, lb + 5120);                                     \
        gload_lds16(VVp + g0, lb + 6144);                                      \
        gload_lds16(VVp + g1, lb + 7168);                                      \
    }

    const u32 base0 = (u32)(size_t)(void*)&cbuf[0][0][0][0];
    const u32 aA0 = base0 + (kq << 4);             // coefficient chunk for lane
    const u32 aV0 = base0 + 24576 + (vcol << 2);   // V broadcast slot

    float4 cDa0, cDa1, cDb0, cDb1;
    uint4 cPAa0, cPAa1, cPAb0, cPAb1, cPKa0, cPKa1, cPKb0, cPKb1;
    float cV[32];

#define LD2(S_, G)                                                             \
    cD##S_##0 = ds_read128<(G) * 512>(aAb);                                    \
    cD##S_##1 = ds_read128<(G) * 512 + 256>(aAb);                              \
    cPA##S_##0 = ds_read128u<8192 + (G) * 512>(aAb);                           \
    cPA##S_##1 = ds_read128u<8192 + (G) * 512 + 256>(aAb);                     \
    cPK##S_##0 = ds_read128u<16384 + (G) * 512>(aAb);                          \
    cPK##S_##1 = ds_read128u<16384 + (G) * 512 + 256>(aAb);

#define VRD(J) cV[J] = ds_read32<(J) * 256>(aVb);
#define VRD8(J) VRD(J) VRD((J)+1) VRD((J)+2) VRD((J)+3) VRD((J)+4) VRD((J)+5) VRD((J)+6) VRD((J)+7)

#define WAIT6 asm volatile("s_waitcnt lgkmcnt(6)" ::: "memory");               \
    __builtin_amdgcn_sched_barrier(0);
#define WAIT0 asm volatile("s_waitcnt lgkmcnt(0)" ::: "memory");               \
    __builtin_amdgcn_sched_barrier(0);

#define UNP_LO(u) __uint_as_float((u) << 16)
#define UNP_HI(u) __uint_as_float((u) & 0xffff0000u)

#define STEP1(D4, pa, pk, Vsj, T)                                              \
    {                                                                          \
        const float Ax = UNP_LO(pa.x), Ay = UNP_LO(pa.y),                      \
                    Az = UNP_LO(pa.z), Aw = UNP_LO(pa.w);                      \
        const float Bx = UNP_HI(pa.x), By = UNP_HI(pa.y),                      \
                    Bz = UNP_HI(pa.z), Bw = UNP_HI(pa.w);                      \
        const float Kx = UNP_LO(pk.x), Ky = UNP_LO(pk.y),                      \
                    Kz = UNP_LO(pk.z), Kw = UNP_LO(pk.w);                      \
        const float Rx = UNP_HI(pk.x), Ry = UNP_HI(pk.y),                      \
                    Rz = UNP_HI(pk.z), Rw = UNP_HI(pk.w);                      \
        float sp = fmaf(L1, Ay, L0 * Ax) + fmaf(L3, Aw, L2 * Az);              \
        const float sa = rowsum16(sp);                                         \
        L0 = fmaf(Bx, sa, fmaf(Kx, Vsj, L0 * D4.x));                           \
        L1 = fmaf(By, sa, fmaf(Ky, Vsj, L1 * D4.y));                           \
        L2 = fmaf(Bz, sa, fmaf(Kz, Vsj, L2 * D4.z));                           \
        L3 = fmaf(Bw, sa, fmaf(Kw, Vsj, L3 * D4.w));                           \
        float op = fmaf(L1, Ry, L0 * Rx) + fmaf(L3, Rw, L2 * Rz);              \
        const float o = rowsum16(op);                                          \
        if (kq == 0) OO[cb + ((size_t)(T) << 11) + vcol] = o;                  \
    }

#define STEP2(S_, G)                                                           \
    STEP1(cD##S_##0, cPA##S_##0, cPK##S_##0, cV[2 * (G)], tbase + 2 * (G));    \
    STEP1(cD##S_##1, cPA##S_##1, cPK##S_##1, cV[2 * (G) + 1], tbase + 2 * (G) + 1);

#define PAIR(G)                                                                \
    LD2(b, (G) + 1) WAIT6 STEP2(a, G) LD2(a, (G) + 2) WAIT6 STEP2(b, (G) + 1)

    STG(0, 0);
    __syncthreads();

    for (int c = 0; c < 32; ++c) {
        const int b = c & 1;
        if (c < 31) STG(b ^ 1, (c + 1) << 5);      // async prefetch next chunk (vmcnt)
        const u32 aAb = aA0 + b * 32768;
        const u32 aVb = aV0 + b * 32768;
        const int tbase = c << 5;
        VRD8(0) VRD8(8) VRD8(16) VRD8(24)          // all 32 V values (b32 burst)
        WAIT0                                      // V in regs; lgkm queue empty
        LD2(a, 0)
        PAIR(0) PAIR(2) PAIR(4) PAIR(6) PAIR(8) PAIR(10) PAIR(12)
        LD2(b, 15) WAIT6 STEP2(a, 14) WAIT0 STEP2(b, 15)
        __syncthreads();   // drains staging vmcnt (1/32 steps); flips buffers
    }
#undef PAIR
#undef STEP2
#undef STEP1
#undef UNP_LO
#undef UNP_HI
#undef WAIT0
#undef WAIT6
#undef VRD8
#undef VRD
#undef LD2
#undef STG
}

// ---------- gate: pure elementwise (dot precomputed; OO f32, Y2 bf16) ----------
__global__ __launch_bounds__(256) void k_gate(
    const float* __restrict__ OOp, const float* __restrict__ VVp,
    const float* __restrict__ DOT, const u16* __restrict__ Y2b,
    u16* __restrict__ XG) {
    const int t = blockIdx.x, tid = threadIdx.x;
    const size_t tb = (size_t)t << 11;
    const int c0 = tid << 3;
    const float dot = DOT[((size_t)t << 5) + (tid >> 3)];
    float4 o0 = *(const float4*)(OOp + tb + c0);
    float4 o1 = *(const float4*)(OOp + tb + c0 + 4);
    float4 v0 = *(const float4*)(VVp + tb + c0);
    float4 v1 = *(const float4*)(VVp + tb + c0 + 4);
    uint4 gu = *(const uint4*)(Y2b + (size_t)t * N2 + 4096 + c0);   // 8 bf16
    const float g0 = __uint_as_float(gu.x << 16),  g1 = __uint_as_float(gu.x & 0xffff0000u);
    const float g2 = __uint_as_float(gu.y << 16),  g3 = __uint_as_float(gu.y & 0xffff0000u);
    const float g4 = __uint_as_float(gu.z << 16),  g5 = __uint_as_float(gu.z & 0xffff0000u);
    const float g6 = __uint_as_float(gu.w << 16),  g7 = __uint_as_float(gu.w & 0xffff0000u);
    const float x0 = fmaf(o0.x, 0.125f, dot * v0.x) * g0;
    const float x1 = fmaf(o0.y, 0.125f, dot * v0.y) * g1;
    const float x2 = fmaf(o0.z, 0.125f, dot * v0.z) * g2;
    const float x3 = fmaf(o0.w, 0.125f, dot * v0.w) * g3;
    const float x4 = fmaf(o1.x, 0.125f, dot * v1.x) * g4;
    const float x5 = fmaf(o1.y, 0.125f, dot * v1.y) * g5;
    const float x6 = fmaf(o1.z, 0.125f, dot * v1.z) * g6;
    const float x7 = fmaf(o1.w, 0.125f, dot * v1.w) * g7;
    uint4 pk;
    pk.x = (u32)f2bf(x0) | ((u32)f2bf(x1) << 16);
    pk.y = (u32)f2bf(x2) | ((u32)f2bf(x3) << 16);
    pk.z = (u32)f2bf(x4) | ((u32)f2bf(x5) << 16);
    pk.w = (u32)f2bf(x6) | ((u32)f2bf(x7) << 16);
    *(uint4*)(XG + tb + c0) = pk;
}

// ---------- final residual + rmsnorm ----------
__global__ __launch_bounds__(256) void k_final(const float* __restrict__ x_in,
                                               const float* __restrict__ OUTR,
                                               const float* __restrict__ ln2,
                                               float* __restrict__ out) {
    const int t = blockIdx.x, tid = threadIdx.x;
    const float* xr = x_in + ((size_t)t << 11);
    const float* orow = OUTR + ((size_t)t << 11);
    float4 a0 = *(const float4*)(xr + tid * 8);
    float4 a1 = *(const float4*)(xr + tid * 8 + 4);
    float4 b0 = *(const float4*)(orow + tid * 8);
    float4 b1 = *(const float4*)(orow + tid * 8 + 4);
    float v[8] = {a0.x + b0.x, a0.y + b0.y, a0.z + b0.z, a0.w + b0.w,
                  a1.x + b1.x, a1.y + b1.y, a1.z + b1.z, a1.w + b1.w};
    float ss = 0.f;
#pragma unroll
    for (int i = 0; i < 8; ++i) ss = fmaf(v[i], v[i], ss);
    ss = wsum(ss);
    __shared__ float red[4];
    if ((tid & 63) == 0) red[tid >> 6] = ss;
    __syncthreads();
    float scale = rsqrtf((red[0] + red[1] + red[2] + red[3]) * (1.f / 2048.f) + 1e-6f);
    float* o = out + ((size_t)t << 11) + tid * 8;
#pragma unroll
    for (int i = 0; i < 8; ++i) o[i] = ln2[tid * 8 + i] * v[i] * scale;
}

extern "C" void kernel_launch(void* const* d_in, const int* in_sizes, int n_in,
                              void* d_out, int out_size, void* d_ws, size_t ws_size,
                              hipStream_t stream) {
    const float* x_in    = (const float*)d_in[0];
    const float* v_first = (const float*)d_in[1];
    const float* k_first = (const float*)d_in[2];
    const float* state   = (const float*)d_in[3];
    const float* cosb    = (const float*)d_in[4];
    const float* sinb    = (const float*)d_in[5];
    const float* wavgk1  = (const float*)d_in[6];
    const float* w0      = (const float*)d_in[7];
    const float* w2      = (const float*)d_in[8];
    const float* a0      = (const float*)d_in[9];
    const float* a2      = (const float*)d_in[10];
    const float* v0      = (const float*)d_in[11];
    const float* v2      = (const float*)d_in[12];
    const float* g2      = (const float*)d_in[13];
    const float* k0      = (const float*)d_in[14];
    const float* k2      = (const float*)d_in[15];
    const float* r_k     = (const float*)d_in[16];
    const float* RKV     = (const float*)d_in[17];
    const float* O       = (const float*)d_in[18];
    const float* R_bias  = (const float*)d_in[19];
    const float* K_bias  = (const float*)d_in[20];
    const float* V_bias  = (const float*)d_in[21];
    const float* ln_r    = (const float*)d_in[22];
    const float* ln_k    = (const float*)d_in[23];
    const float* ln1     = (const float*)d_in[24];
    const float* ln2     = (const float*)d_in[25];

    if (ws_size < WS_NEED) return;  // need 247.2 MB (fits 256 MiB)

    char* ws = (char*)d_ws;
    u16*   BT1  = (u16*)(ws + OFF_BT1);
    u16*   W2T  = (u16*)(ws + OFF_W2T);
    u16*   OT   = (u16*)(ws + OFF_OT);
    u16*   XB   = (u16*)(ws + OFF_XB);
    u16*   Y1   = (u16*)(ws + OFF_Y1);
    u16*   X2   = (u16*)(ws + OFF_X2);
    u16*   Y2b  = (u16*)(ws + OFF_Y2);
    float* DEC  = (float*)(ws + OFF_DEC);
    float* VV   = (float*)(ws + OFF_VV);
    u32*   PAB  = (u32*)(ws + OFF_PAB);
    u32*   PKR  = (u32*)(ws + OFF_PKR);
    float* DOT  = (float*)(ws + OFF_DOT);
    float* OO   = (float*)(ws + OFF_OO);
    u16*   XG   = (u16*)(ws + OFF_XG);
    float* OUTR = (float*)(ws + OFF_OUTR);

    // P0: ALL independent preps in one launch (BT1+W2T+OT+XB)
    k_prep0<<<5936, 256, 0, stream>>>(wavgk1, RKV, w2, a2, g2, v2, k2, O,
                                      x_in, ln1, BT1, W2T, OT, XB);
    // P1: GEMM1 -> Y1 bf16 + fused X2 epilogue, BK=64
    k_gemmb<<<dim3(16, 29), 256, 0, stream>>>(XB, BT1, Y1, X2, 2048, N1, 2048);
    // P2: GEMM2 (block-diagonal) -> Y2 bf16
    k_gemm2<<<dim3(16, 56), 256, 0, stream>>>(X2, W2T, Y2b);
    // P3: recurrence operands + head-dot; Y1 dead after this
    k_prep_rec<<<2048, 256, 0, stream>>>(Y1, Y2b, v_first, k_first, cosb, sinb,
                                         w0, a0, v0, k0, R_bias, K_bias, V_bias,
                                         ln_r, ln_k, r_k, DEC, VV, PAB, PKR, DOT);
    // P4: recurrence -> OO f32 (in old Y1 space)
    k_recv17<<<256, 256, 0, stream>>>(DEC, PAB, PKR, VV, state, OO);
    // P5: gate (elementwise) -> XG (over dead W2T); Y2 dead after this
    k_gate<<<2048, 256, 0, stream>>>(OO, VV, DOT, Y2b, XG);
    // P6: GEMM3 -> OUTR (f32), BK=64; final norm
    k_gemm<<<dim3(16, 16), 256, 0, stream>>>(XG, OT, OUTR, 2048, 2048, 2048);
    k_final<<<2048, 256, 0, stream>>>(x_in, OUTR, ln2, (float*)d_out);
}